// Round 4
// baseline (1513.470 us; speedup 1.0000x reference)
//
#include <hip/hip_runtime.h>
#include <hip/hip_bf16.h>

#define B_ 4
#define N_ 10000
#define NE_ 100000
#define D_ 128
#define S_ 64
#define H_ 4
#define T_ 128

typedef unsigned short u16;
typedef unsigned int u32;
typedef __attribute__((ext_vector_type(4))) float f4;
typedef __attribute__((ext_vector_type(8))) short s8;

#define DEVI static __device__ __forceinline__

DEVI float b2f(u16 u){ union{u32 i; float f;} v; v.i=((u32)u)<<16; return v.f; }
DEVI u16 f2b(float f){ union{float ff; u32 i;} v; v.ff=f; u32 i=v.i; return (u16)((i+0x7fffu+((i>>16)&1u))>>16); }
DEVI f4 mfma16(s8 a, s8 b, f4 c){ return __builtin_amdgcn_mfma_f32_16x16x32_bf16(a,b,c,0,0,0); }
DEVI float rsum16(float x){ x+=__shfl_xor(x,1); x+=__shfl_xor(x,2); x+=__shfl_xor(x,4); x+=__shfl_xor(x,8); return x; }
DEVI float silu_f(float v){ return v/(1.f+__expf(-v)); }
DEVI float nn(float v, float s){ return (v==v)? v : s; }

// load 8 consecutive f32, convert to 8 bf16 packed as an MFMA fragment
DEVI s8 ldw8f(const float* p){
  f4 a = *(const f4*)p;
  f4 c = *(const f4*)(p+4);
  union { u16 t[8]; s8 v; } u;
  #pragma unroll
  for (int i=0;i<4;i++){ u.t[i]=f2b(a[i]); u.t[4+i]=f2b(c[i]); }
  return u.v;
}
// load 8 consecutive f32, convert to 8 bf16 packed as uint4 (for LDS staging)
DEVI uint4 cvt8(const float* p){
  f4 a = *(const f4*)p;
  f4 c = *(const f4*)(p+4);
  union { u16 t[8]; uint4 v; } u;
  #pragma unroll
  for (int i=0;i<4;i++){ u.t[i]=f2b(a[i]); u.t[4+i]=f2b(c[i]); }
  return u.v;
}

// ---------------------------------------------------------------------------
// K1: edge MLP (f32 in, f32 E_out). X = [V_s|s_s|V_r|s_r|E] bf16 staged.
// ---------------------------------------------------------------------------
__global__ __launch_bounds__(256,2) void k_edge(
  const float* __restrict__ V, const float* __restrict__ E, const int* __restrict__ edges,
  const float* __restrict__ senc,
  const float* __restrict__ w1, const float* __restrict__ b1,
  const float* __restrict__ w2, const float* __restrict__ b2,
  const float* __restrict__ lng, const float* __restrict__ lnb,
  float* __restrict__ m0s, float* __restrict__ m1s,
  float* __restrict__ c0s, float* __restrict__ c1s,
  float* __restrict__ Eout)
{
  __shared__ u16 X[64][520];
  __shared__ int gi0[64], gi1[64];
  __shared__ float fvalid[64];
  const int tid = threadIdx.x;
  const int el = tid>>2, part = tid&3;
  const int ge = blockIdx.x*64 + el;
  const int b = ge / NE_;
  const int2 ed = *(const int2*)(edges + (size_t)ge*2);
  const int i0 = min(max(ed.x,0),N_-1), i1 = min(max(ed.y,0),N_-1);
  if (part==0){
    gi0[el] = b*N_ + i0; gi1[el] = b*N_ + i1;
    fvalid[el] = (ed.x>=0 && ed.y>=0) ? 1.f : 0.f;
  }
  {
    const float* Vb = V + (size_t)b*N_*D_;
    const float* Sb = senc + (size_t)b*N_*S_;
    const float* Ep = E + (size_t)ge*D_;
    #pragma unroll
    for (int j=0;j<16;j++){
      int u = part + 4*j;
      const float* p;
      if (u<16)      p = Vb + (size_t)i0*D_ + u*8;
      else if (u<24) p = Sb + (size_t)i0*S_ + (u-16)*8;
      else if (u<40) p = Vb + (size_t)i1*D_ + (u-24)*8;
      else if (u<48) p = Sb + (size_t)i1*S_ + (u-40)*8;
      else           p = Ep + (u-48)*8;
      *(uint4*)&X[el][u*8] = cvt8(p);
    }
  }
  __syncthreads();
  if (tid < 64){
    atomicAdd(&c0s[gi0[tid]], 1.f);
    atomicAdd(&c1s[gi1[tid]], 1.f);
  }
  const int lane = tid&63, w = tid>>6;
  const int l15 = lane&15, hi = lane>>4;
  const int rw = w*16;
  f4 acc[8];
  #pragma unroll
  for (int t=0;t<8;t++){ float bb=b1[l15+16*t]; acc[t]=(f4){bb,bb,bb,bb}; }
  for (int kk=0;kk<16;kk++){
    s8 a = *(const s8*)&X[rw+l15][kk*32 + hi*8];
    #pragma unroll
    for (int t=0;t<8;t++){
      s8 bf = ldw8f(w1 + (size_t)(t*16+l15)*512 + kk*32 + hi*8);
      acc[t] = mfma16(a, bf, acc[t]);
    }
  }
  __syncthreads();
  #pragma unroll
  for (int t=0;t<8;t++){
    #pragma unroll
    for (int r=0;r<4;r++) X[rw+hi*4+r][l15+16*t] = f2b(silu_f(acc[t][r]));
  }
  __syncthreads();
  f4 a2[8];
  #pragma unroll
  for (int t=0;t<8;t++){ float bb=b2[l15+16*t]; a2[t]=(f4){bb,bb,bb,bb}; }
  #pragma unroll
  for (int kk=0;kk<4;kk++){
    s8 a = *(const s8*)&X[rw+l15][kk*32 + hi*8];
    #pragma unroll
    for (int t=0;t<8;t++){
      s8 bf = ldw8f(w2 + (size_t)(t*16+l15)*128 + kk*32 + hi*8);
      a2[t] = mfma16(a, bf, a2[t]);
    }
  }
  __syncthreads();
  float gv[8], bev[8];
  #pragma unroll
  for (int t=0;t<8;t++){ gv[t]=lng[l15+16*t]; bev[t]=lnb[l15+16*t]; }
  #pragma unroll
  for (int r=0;r<4;r++){
    const int row = rw + hi*4 + r;
    float s=0.f, s2=0.f;
    #pragma unroll
    for (int t=0;t<8;t++){ float v=a2[t][r]; s+=v; s2+=v*v; }
    s = rsum16(s); s2 = rsum16(s2);
    const float mean = s*(1.f/128.f);
    const float rstd = rsqrtf(s2*(1.f/128.f) - mean*mean + 1e-5f);
    const float vm = fvalid[row];
    const int g0 = gi0[row], g1 = gi1[row];
    #pragma unroll
    for (int t=0;t<8;t++){
      const int col = l15 + 16*t;
      float ev = ((a2[t][r]-mean)*rstd*gv[t] + bev[t]) * vm;
      ev = nn(ev, 7e3f);   // sentinel: NaN born in k_edge
      if (col < 64) atomicAdd(m0s + (size_t)g0*64 + col, ev);
      else          atomicAdd(m1s + (size_t)g1*64 + (col-64), ev);
      X[row][384+col] = f2b(ev);     // e_emb (bf16) for the E_out add
    }
  }
  __syncthreads();
  // E_out = E(f32) + e_emb, coalesced f32 writes
  #pragma unroll
  for (int j=0;j<4;j++){
    int u = part + 4*j; int c0 = u*8;
    const float* ep = E + (size_t)ge*D_ + c0;
    f4 e0 = *(const f4*)ep, e1 = *(const f4*)(ep+4);
    f4 o0, o1v;
    #pragma unroll
    for (int i=0;i<4;i++){
      o0[i]  = e0[i] + b2f(X[el][384+c0+i]);
      o1v[i] = e1[i] + b2f(X[el][384+c0+4+i]);
    }
    *(f4*)(Eout + (size_t)ge*D_ + c0)   = o0;
    *(f4*)(Eout + (size_t)ge*D_ + c0+4) = o1v;
  }
}

// ---------------------------------------------------------------------------
// K2: node MLP + V1 = V+v_emb + W0 = LN(V1)   (f32 in, bf16 ws out)
// ---------------------------------------------------------------------------
__global__ __launch_bounds__(256,2) void k_node(
  const float* __restrict__ V, const float* __restrict__ senc,
  const float* __restrict__ m0s, const float* __restrict__ m1s,
  const float* __restrict__ c0s, const float* __restrict__ c1s,
  const float* __restrict__ w1, const float* __restrict__ b1,
  const float* __restrict__ w2, const float* __restrict__ b2,
  const float* __restrict__ lng, const float* __restrict__ lnb,
  const float* __restrict__ l1g, const float* __restrict__ l1b,
  u16* __restrict__ V1, u16* __restrict__ W0)
{
  __shared__ u16 X[64][328];
  const int tid=threadIdx.x, nl=tid>>2, part=tid&3;
  const int gn = blockIdx.x*64 + nl;
  const int b = gn / N_, n = gn - b*N_;
  {
    const float* Vp = V + ((size_t)b*N_ + n)*D_;
    const float* Sp = senc + ((size_t)b*N_ + n)*S_;
    #pragma unroll
    for (int j=0;j<6;j++){
      int u = part + 4*j;
      const float* p = (u<16)? Vp + u*8 : Sp + (u-16)*8;
      *(uint4*)&X[nl][u*8] = cvt8(p);
    }
    const float rc0 = 1.f/fmaxf(c0s[gn],1.f), rc1 = 1.f/fmaxf(c1s[gn],1.f);
    #pragma unroll
    for (int j=0;j<8;j++){
      int c = part*32 + j*4;
      const float* src = (c<64)? m0s + (size_t)gn*64 + c : m1s + (size_t)gn*64 + (c-64);
      float rr = (c<64)? rc0 : rc1;
      f4 mv = *(const f4*)src;
      u16 ov[4];
      #pragma unroll
      for (int i=0;i<4;i++) ov[i]=f2b(mv[i]*rr);
      uint2 pk; __builtin_memcpy(&pk, ov, 8);
      *(uint2*)&X[nl][192+c] = pk;
    }
  }
  __syncthreads();
  const int lane=tid&63, w=tid>>6, l15=lane&15, hi=lane>>4, rw=w*16;
  f4 acc[8];
  #pragma unroll
  for (int t=0;t<8;t++){ float bb=b1[l15+16*t]; acc[t]=(f4){bb,bb,bb,bb}; }
  for (int kk=0;kk<10;kk++){
    s8 a = *(const s8*)&X[rw+l15][kk*32+hi*8];
    #pragma unroll
    for (int t=0;t<8;t++){
      s8 bf = ldw8f(w1 + (size_t)(t*16+l15)*320 + kk*32 + hi*8);
      acc[t]=mfma16(a,bf,acc[t]);
    }
  }
  __syncthreads();
  #pragma unroll
  for (int t=0;t<8;t++){
    #pragma unroll
    for (int r=0;r<4;r++) X[rw+hi*4+r][192 + l15+16*t] = f2b(silu_f(acc[t][r]));
  }
  __syncthreads();
  f4 a2[8];
  #pragma unroll
  for (int t=0;t<8;t++){ float bb=b2[l15+16*t]; a2[t]=(f4){bb,bb,bb,bb}; }
  #pragma unroll
  for (int kk=0;kk<4;kk++){
    s8 a = *(const s8*)&X[rw+l15][192 + kk*32+hi*8];
    #pragma unroll
    for (int t=0;t<8;t++){
      s8 bf = ldw8f(w2 + (size_t)(t*16+l15)*128 + kk*32 + hi*8);
      a2[t]=mfma16(a,bf,a2[t]);
    }
  }
  __syncthreads();
  float gv[8],bev[8],g1v[8],b1v[8];
  #pragma unroll
  for (int t=0;t<8;t++){
    gv[t]=lng[l15+16*t]; bev[t]=lnb[l15+16*t];
    g1v[t]=l1g[l15+16*t]; b1v[t]=l1b[l15+16*t];
  }
  #pragma unroll
  for (int r=0;r<4;r++){
    const int row=rw+hi*4+r;
    float s=0.f,s2=0.f;
    #pragma unroll
    for (int t=0;t<8;t++){ float v=a2[t][r]; s+=v; s2+=v*v; }
    s=rsum16(s); s2=rsum16(s2);
    float mean=s*(1.f/128.f);
    float rstd=rsqrtf(s2*(1.f/128.f)-mean*mean+1e-5f);
    float tmp[8]; float sv=0.f, sv2=0.f;
    #pragma unroll
    for (int t=0;t<8;t++){
      float ve=(a2[t][r]-mean)*rstd*gv[t]+bev[t];
      float vv=b2f(X[row][l15+16*t])+ve;
      tmp[t]=vv; sv+=vv; sv2+=vv*vv;
    }
    sv=rsum16(sv); sv2=rsum16(sv2);
    float m2=sv*(1.f/128.f);
    float rs2=rsqrtf(sv2*(1.f/128.f)-m2*m2+1e-5f);
    #pragma unroll
    for (int t=0;t<8;t++){
      X[row][l15+16*t]=f2b(nn(tmp[t],5e3f));
      X[row][192+l15+16*t]=f2b(nn((tmp[t]-m2)*rs2*g1v[t]+b1v[t],5e3f));
    }
  }
  __syncthreads();
  #pragma unroll
  for (int j=0;j<4;j++){
    int u=part+4*j;
    *(uint4*)(V1 + (size_t)gn*D_ + u*8) = *(const uint4*)&X[nl][u*8];
    *(uint4*)(W0 + (size_t)gn*D_ + u*8) = *(const uint4*)&X[nl][192 + u*8];
  }
}

// ---------------------------------------------------------------------------
// K3q: qh1 = Q@wq1^T+bq1  -> (H,T,32)
// ---------------------------------------------------------------------------
__global__ __launch_bounds__(256) void k_qh1(
  const float* __restrict__ Q, const float* __restrict__ wqkv, const float* __restrict__ bqkv,
  u16* __restrict__ qh1)
{
  __shared__ u16 X[64][136];
  const int tid=threadIdx.x, nl=tid>>2, part=tid&3;
  const int q = blockIdx.x*64 + nl;
  #pragma unroll
  for (int j=0;j<4;j++){ int u=part+4*j; *(uint4*)&X[nl][u*8] = cvt8(Q + (size_t)q*D_ + u*8); }
  __syncthreads();
  const int lane=tid&63, w=tid>>6, l15=lane&15, hi=lane>>4, rw=w*16;
  f4 acc[8];
  #pragma unroll
  for (int t=0;t<8;t++){ float bb=bqkv[l15+16*t]; acc[t]=(f4){bb,bb,bb,bb}; }
  #pragma unroll
  for (int kk=0;kk<4;kk++){
    s8 a = *(const s8*)&X[rw+l15][kk*32+hi*8];
    #pragma unroll
    for (int t=0;t<8;t++){
      s8 bf = ldw8f(wqkv + (size_t)(t*16+l15)*D_ + kk*32+hi*8);
      acc[t]=mfma16(a,bf,acc[t]);
    }
  }
  __syncthreads();
  #pragma unroll
  for (int t=0;t<8;t++){
    #pragma unroll
    for (int r=0;r<4;r++) X[rw+hi*4+r][l15+16*t]=f2b(acc[t][r]);
  }
  __syncthreads();
  #pragma unroll
  for (int j=0;j<4;j++){
    int u=part+4*j, col0=u*8, h=col0>>5, d=col0&31;
    *(uint4*)(qh1 + ((size_t)h*T_ + q)*32 + d) = *(const uint4*)&X[nl][col0];
  }
}

// ---------------------------------------------------------------------------
// K3: kh1/vh1 = W0 @ [wk1;wv1]^T  -> (B,H,N,32) each
// ---------------------------------------------------------------------------
__global__ __launch_bounds__(256,2) void k_kv1(
  const u16* __restrict__ W0, const float* __restrict__ wqkv, const float* __restrict__ bqkv,
  u16* __restrict__ kh1, u16* __restrict__ vh1)
{
  __shared__ u16 X[64][264];
  const int tid=threadIdx.x, nl=tid>>2, part=tid&3;
  const int gn = blockIdx.x*64 + nl;
  const int b = gn / N_, n = gn - b*N_;
  #pragma unroll
  for (int j=0;j<4;j++){ int u=part+4*j; *(uint4*)&X[nl][u*8] = *(const uint4*)(W0 + (size_t)gn*D_ + u*8); }
  __syncthreads();
  const int lane=tid&63, w=tid>>6, l15=lane&15, hi=lane>>4, rw=w*16;
  f4 acc[16];
  #pragma unroll
  for (int t=0;t<16;t++){ float bb=bqkv[128 + l15+16*t]; acc[t]=(f4){bb,bb,bb,bb}; }
  #pragma unroll
  for (int kk=0;kk<4;kk++){
    s8 a = *(const s8*)&X[rw+l15][kk*32+hi*8];
    #pragma unroll
    for (int t=0;t<16;t++){
      s8 bf = ldw8f(wqkv + (size_t)(128 + t*16+l15)*D_ + kk*32+hi*8);
      acc[t]=mfma16(a,bf,acc[t]);
    }
  }
  __syncthreads();
  #pragma unroll
  for (int t=0;t<16;t++){
    #pragma unroll
    for (int r=0;r<4;r++) X[rw+hi*4+r][l15+16*t]=f2b(acc[t][r]);
  }
  __syncthreads();
  #pragma unroll
  for (int j=0;j<8;j++){
    int u=part+4*j, col0=u*8;
    u16* dst;
    if (col0<128){ int h=col0>>5, d=col0&31; dst = kh1 + ((size_t)(b*H_+h)*N_ + n)*32 + d; }
    else { int c2=col0-128; int h=c2>>5, d=c2&31; dst = vh1 + ((size_t)(b*H_+h)*N_ + n)*32 + d; }
    *(uint4*)dst = *(const uint4*)&X[nl][col0];
  }
}

// ---------------------------------------------------------------------------
// online-softmax wave-per-row attention core (hd=32), bf16 K/V in ws
// ---------------------------------------------------------------------------
DEVI float lo2f(u32 u){ union{u32 i; float f;} v; v.i=u<<16; return v.f; }
DEVI float hi2f(u32 u){ union{u32 i; float f;} v; v.i=u&0xffff0000u; return v.f; }

DEVI void mha_core(const float* qv, const u16* Kb, const u16* Vb, int nk,
                   int lane, float* outp)
{
  const float scale = 0.17677669529663687f;
  float m=-1e30f, ssum=0.f, o[32];
  #pragma unroll
  for (int i=0;i<32;i++) o[i]=0.f;
  for (int c0=0;c0<nk;c0+=64){
    int key=c0+lane, keyc = key<nk? key: nk-1;
    const uint4* kp=(const uint4*)(Kb+(size_t)keyc*32);
    float sa=0.f;
    #pragma unroll
    for (int i=0;i<4;i++){ uint4 u=kp[i];
      sa += qv[i*8+0]*lo2f(u.x)+qv[i*8+1]*hi2f(u.x)+qv[i*8+2]*lo2f(u.y)+qv[i*8+3]*hi2f(u.y)
          + qv[i*8+4]*lo2f(u.z)+qv[i*8+5]*hi2f(u.z)+qv[i*8+6]*lo2f(u.w)+qv[i*8+7]*hi2f(u.w);
    }
    float s=sa*scale;
    float mn=fmaxf(m,s);
    float corr=__expf(m-mn);
    float p=(key<nk)?__expf(s-mn):0.f;
    ssum=ssum*corr+p;
    const uint4* vp=(const uint4*)(Vb+(size_t)keyc*32);
    #pragma unroll
    for (int i=0;i<4;i++){ uint4 u=vp[i];
      o[i*8+0]=o[i*8+0]*corr+p*lo2f(u.x); o[i*8+1]=o[i*8+1]*corr+p*hi2f(u.x);
      o[i*8+2]=o[i*8+2]*corr+p*lo2f(u.y); o[i*8+3]=o[i*8+3]*corr+p*hi2f(u.y);
      o[i*8+4]=o[i*8+4]*corr+p*lo2f(u.z); o[i*8+5]=o[i*8+5]*corr+p*hi2f(u.z);
      o[i*8+6]=o[i*8+6]*corr+p*lo2f(u.w); o[i*8+7]=o[i*8+7]*corr+p*hi2f(u.w);
    }
    m=mn;
  }
  float M=m;
  #pragma unroll
  for (int d=32;d>=1;d>>=1) M=fmaxf(M,__shfl_xor(M,d));
  float sc=__expf(m-M);
  float sm=ssum*sc;
  #pragma unroll
  for (int d=32;d>=1;d>>=1) sm+=__shfl_xor(sm,d);
  float inv=1.f/sm;
  #pragma unroll
  for (int i=0;i<32;i++){
    float v=o[i]*sc;
    #pragma unroll
    for (int d=32;d>=1;d>>=1) v+=__shfl_xor(v,d);
    if (lane==0) outp[i]=v*inv;
  }
}

__global__ __launch_bounds__(256) void k_mha1(
  const u16* __restrict__ qh1, const u16* __restrict__ kh1, const u16* __restrict__ vh1,
  float* __restrict__ o1)
{
  const int blk=blockIdx.x, bh=blk>>5, b=bh>>2, h=bh&3;
  const int w=threadIdx.x>>6, lane=threadIdx.x&63;
  const int q=(blk&31)*4+w;
  float qv[32];
  const uint4* qp=(const uint4*)(qh1 + ((size_t)h*T_+q)*32);
  #pragma unroll
  for (int i=0;i<4;i++){ uint4 u=qp[i];
    qv[i*8+0]=lo2f(u.x); qv[i*8+1]=hi2f(u.x); qv[i*8+2]=lo2f(u.y); qv[i*8+3]=hi2f(u.y);
    qv[i*8+4]=lo2f(u.z); qv[i*8+5]=hi2f(u.z); qv[i*8+6]=lo2f(u.w); qv[i*8+7]=hi2f(u.w); }
  mha_core(qv, kh1+(size_t)bh*N_*32, vh1+(size_t)bh*N_*32, N_, lane,
           o1+((size_t)b*T_+q)*D_+h*32);
}

__global__ __launch_bounds__(256) void k_mha2(
  const u16* __restrict__ qh2, const u16* __restrict__ kh2, const u16* __restrict__ vh2,
  float* __restrict__ o2)
{
  const int blk=blockIdx.x, bh=blk>>5, b=bh>>2, h=bh&3;
  const int w=threadIdx.x>>6, lane=threadIdx.x&63;
  const int q=(blk&31)*4+w;
  float qv[32];
  const uint4* qp=(const uint4*)(qh2 + ((size_t)bh*T_+q)*32);
  #pragma unroll
  for (int i=0;i<4;i++){ uint4 u=qp[i];
    qv[i*8+0]=lo2f(u.x); qv[i*8+1]=hi2f(u.x); qv[i*8+2]=lo2f(u.y); qv[i*8+3]=hi2f(u.y);
    qv[i*8+4]=lo2f(u.z); qv[i*8+5]=hi2f(u.z); qv[i*8+6]=lo2f(u.w); qv[i*8+7]=hi2f(u.w); }
  mha_core(qv, kh2+(size_t)bh*T_*32, vh2+(size_t)bh*T_*32, T_, lane,
           o2+((size_t)b*T_+q)*D_+h*32);
}

// ---------------------------------------------------------------------------
// K5a: W1 = o1@wo1^T+bo1; {q,k,v}h2 = W1@wqkv2^T+bqkv2
// ---------------------------------------------------------------------------
__global__ __launch_bounds__(256) void k_att12(
  const float* __restrict__ o1, const float* __restrict__ wo, const float* __restrict__ bo,
  const float* __restrict__ wqkv, const float* __restrict__ bqkv,
  u16* __restrict__ qh2, u16* __restrict__ kh2, u16* __restrict__ vh2)
{
  __shared__ u16 X[64][136];
  __shared__ u16 Y[64][392];
  const int tid=threadIdx.x, nl=tid>>2, part=tid&3;
  const int row = blockIdx.x*64 + nl;
  #pragma unroll
  for (int j=0;j<8;j++){
    int c = part*32 + j*4;
    f4 mv = *(const f4*)(o1 + (size_t)row*D_ + c);
    u16 ov[4];
    #pragma unroll
    for (int i=0;i<4;i++) ov[i]=f2b(nn(mv[i],2e4f));   // sentinel: NaN in o1
    uint2 pk; __builtin_memcpy(&pk, ov, 8);
    *(uint2*)&X[nl][c]=pk;
  }
  __syncthreads();
  const int lane=tid&63, w=tid>>6, l15=lane&15, hi=lane>>4, rw=w*16;
  {
    f4 acc[8];
    #pragma unroll
    for (int t=0;t<8;t++){ float bb=bo[l15+16*t]; acc[t]=(f4){bb,bb,bb,bb}; }
    #pragma unroll
    for (int kk=0;kk<4;kk++){
      s8 a = *(const s8*)&X[rw+l15][kk*32+hi*8];
      #pragma unroll
      for (int t=0;t<8;t++){
        s8 bf = ldw8f(wo + (size_t)(t*16+l15)*D_ + kk*32+hi*8);
        acc[t]=mfma16(a,bf,acc[t]);
      }
    }
    #pragma unroll
    for (int t=0;t<8;t++){
      #pragma unroll
      for (int r=0;r<4;r++) Y[rw+hi*4+r][l15+16*t]=f2b(acc[t][r]);
    }
  }
  __syncthreads();
  f4 a2[24];
  #pragma unroll
  for (int t=0;t<24;t++){ float bb=bqkv[l15+16*t]; a2[t]=(f4){bb,bb,bb,bb}; }
  #pragma unroll
  for (int kk=0;kk<4;kk++){
    s8 a = *(const s8*)&Y[rw+l15][kk*32+hi*8];
    #pragma unroll
    for (int t=0;t<24;t++){
      s8 bf = ldw8f(wqkv + (size_t)(t*16+l15)*D_ + kk*32+hi*8);
      a2[t]=mfma16(a,bf,a2[t]);
    }
  }
  __syncthreads();
  #pragma unroll
  for (int t=0;t<24;t++){
    #pragma unroll
    for (int r=0;r<4;r++) Y[rw+hi*4+r][l15+16*t]=f2b(a2[t][r]);
  }
  __syncthreads();
  const int b=row>>7, q=row&127;
  #pragma unroll
  for (int j=0;j<12;j++){
    int u=part+4*j, col0=u*8;
    int sel=col0>>7, c2=col0&127, h=c2>>5, d=c2&31;
    u16* base = sel==0? qh2 : (sel==1? kh2 : vh2);
    *(uint4*)(base + ((size_t)(b*H_+h)*T_ + q)*32 + d) = *(const uint4*)&Y[nl][col0];
  }
}

// ---------------------------------------------------------------------------
// K5c: W2 = o2@wo2^T+bo2; kh3 = W2@wk3^T+bk3; vh3T = (W2@wv3^T+bv3)^T
// ---------------------------------------------------------------------------
__global__ __launch_bounds__(256) void k_att23(
  const float* __restrict__ o2, const float* __restrict__ wo, const float* __restrict__ bo,
  const float* __restrict__ wqkv3, const float* __restrict__ bqkv3,
  u16* __restrict__ kh3, u16* __restrict__ vh3T)
{
  __shared__ u16 X[64][136];
  __shared__ u16 Y[64][264];
  const int tid=threadIdx.x, nl=tid>>2, part=tid&3;
  const int row = blockIdx.x*64 + nl;
  #pragma unroll
  for (int j=0;j<8;j++){
    int c = part*32 + j*4;
    f4 mv = *(const f4*)(o2 + (size_t)row*D_ + c);
    u16 ov[4];
    #pragma unroll
    for (int i=0;i<4;i++) ov[i]=f2b(nn(mv[i],3e4f));   // sentinel: NaN in o2
    uint2 pk; __builtin_memcpy(&pk, ov, 8);
    *(uint2*)&X[nl][c]=pk;
  }
  __syncthreads();
  const int lane=tid&63, w=tid>>6, l15=lane&15, hi=lane>>4, rw=w*16;
  {
    f4 acc[8];
    #pragma unroll
    for (int t=0;t<8;t++){ float bb=bo[l15+16*t]; acc[t]=(f4){bb,bb,bb,bb}; }
    #pragma unroll
    for (int kk=0;kk<4;kk++){
      s8 a = *(const s8*)&X[rw+l15][kk*32+hi*8];
      #pragma unroll
      for (int t=0;t<8;t++){
        s8 bf = ldw8f(wo + (size_t)(t*16+l15)*D_ + kk*32+hi*8);
        acc[t]=mfma16(a,bf,acc[t]);
      }
    }
    #pragma unroll
    for (int t=0;t<8;t++){
      #pragma unroll
      for (int r=0;r<4;r++) Y[rw+hi*4+r][l15+16*t]=f2b(acc[t][r]);
    }
  }
  __syncthreads();
  f4 a2[16];
  #pragma unroll
  for (int t=0;t<16;t++){ float bb=bqkv3[128 + l15+16*t]; a2[t]=(f4){bb,bb,bb,bb}; }
  #pragma unroll
  for (int kk=0;kk<4;kk++){
    s8 a = *(const s8*)&Y[rw+l15][kk*32+hi*8];
    #pragma unroll
    for (int t=0;t<16;t++){
      s8 bf = ldw8f(wqkv3 + (size_t)(128 + t*16+l15)*D_ + kk*32+hi*8);
      a2[t]=mfma16(a,bf,a2[t]);
    }
  }
  __syncthreads();
  #pragma unroll
  for (int t=0;t<16;t++){
    #pragma unroll
    for (int r=0;r<4;r++) Y[rw+hi*4+r][l15+16*t]=f2b(a2[t][r]);
  }
  __syncthreads();
  const int b=row>>7, q=row&127;
  #pragma unroll
  for (int j=0;j<4;j++){
    int u=part+4*j, col0=u*8, h=col0>>5, d=col0&31;
    *(uint4*)(kh3 + ((size_t)(b*H_+h)*T_ + q)*32 + d) = *(const uint4*)&Y[nl][col0];
  }
  #pragma unroll
  for (int cc=0;cc<32;cc++){
    int c2 = part*32 + cc;
    int h=c2>>5, d=c2&31;
    vh3T[((size_t)(b*H_+h)*32 + d)*T_ + q] = Y[nl][128+c2];
  }
}

// ---------------------------------------------------------------------------
// K6a: mha3 (q=W0, kv from W2) + wo3 + residual V1 -> V2, x=LN2(V2)
// ---------------------------------------------------------------------------
__global__ __launch_bounds__(256,2) void k_mha3(
  const u16* __restrict__ W0, const u16* __restrict__ V1,
  const float* __restrict__ wqkv3, const float* __restrict__ bqkv3,
  const u16* __restrict__ kh3, const u16* __restrict__ vh3T,
  const float* __restrict__ wo3, const float* __restrict__ bo3,
  const float* __restrict__ l2g, const float* __restrict__ l2b,
  u16* __restrict__ V2, u16* __restrict__ XLN)
{
  __shared__ u16 Wt[64][136];
  __shared__ u16 Q3[64][136];
  __shared__ u16 P3[64][136];
  const int tid=threadIdx.x, nl=tid>>2, part=tid&3;
  const int b = blockIdx.x/157, tb = blockIdx.x - b*157;
  const int n0 = tb*64;
  {
    const int ns = min(n0+nl, N_-1);
    const u16* src = W0 + ((size_t)b*N_+ns)*D_;
    #pragma unroll
    for (int j=0;j<4;j++){ int u=part+4*j; *(uint4*)&Wt[nl][u*8] = *(const uint4*)(src+u*8); }
  }
  __syncthreads();
  const int lane=tid&63, w=tid>>6, l15=lane&15, hi=lane>>4, rw=w*16;
  {
    f4 acc[8];
    #pragma unroll
    for (int t=0;t<8;t++){ float bb=bqkv3[l15+16*t]; acc[t]=(f4){bb,bb,bb,bb}; }
    #pragma unroll
    for (int kk=0;kk<4;kk++){
      s8 a = *(const s8*)&Wt[rw+l15][kk*32+hi*8];
      #pragma unroll
      for (int t=0;t<8;t++){
        s8 bf = ldw8f(wqkv3 + (size_t)(t*16+l15)*D_ + kk*32+hi*8);
        acc[t]=mfma16(a,bf,acc[t]);
      }
    }
    #pragma unroll
    for (int t=0;t<8;t++){
      #pragma unroll
      for (int r=0;r<4;r++) Q3[rw+hi*4+r][l15+16*t]=f2b(acc[t][r]);
    }
  }
  __syncthreads();
  const float scale=0.17677669529663687f;
  f4 oacc[8];
  #pragma unroll
  for (int t=0;t<8;t++) oacc[t]=(f4){0.f,0.f,0.f,0.f};
  #pragma unroll
  for (int h=0;h<H_;h++){
    f4 sa[8];
    #pragma unroll
    for (int t=0;t<8;t++) sa[t]=(f4){0.f,0.f,0.f,0.f};
    s8 aq = *(const s8*)&Q3[rw+l15][h*32+hi*8];
    #pragma unroll
    for (int t=0;t<8;t++){
      s8 bf = *(const s8*)(kh3 + ((size_t)(b*H_+h)*T_ + t*16+l15)*32 + hi*8);
      sa[t]=mfma16(aq,bf,sa[t]);
    }
    #pragma unroll
    for (int r=0;r<4;r++){
      const int row=rw+hi*4+r;
      float mx=-1e30f;
      float sv[8];
      #pragma unroll
      for (int t=0;t<8;t++){ sv[t]=sa[t][r]*scale; mx=fmaxf(mx,sv[t]); }
      mx=fmaxf(mx,__shfl_xor(mx,1)); mx=fmaxf(mx,__shfl_xor(mx,2));
      mx=fmaxf(mx,__shfl_xor(mx,4)); mx=fmaxf(mx,__shfl_xor(mx,8));
      float se=0.f; float pv[8];
      #pragma unroll
      for (int t=0;t<8;t++){ pv[t]=__expf(sv[t]-mx); se+=pv[t]; }
      se=rsum16(se);
      float inv=1.f/se;
      #pragma unroll
      for (int t=0;t<8;t++) P3[row][l15+16*t]=f2b(pv[t]*inv);
    }
    __syncthreads();
    #pragma unroll
    for (int kk=0;kk<4;kk++){
      s8 ap = *(const s8*)&P3[rw+l15][kk*32+hi*8];
      #pragma unroll
      for (int t2=0;t2<2;t2++){
        s8 bf = *(const s8*)(vh3T + ((size_t)(b*H_+h)*32 + t2*16+l15)*T_ + kk*32+hi*8);
        oacc[h*2+t2]=mfma16(ap,bf,oacc[h*2+t2]);
      }
    }
    __syncthreads();
  }
  #pragma unroll
  for (int t=0;t<8;t++){
    #pragma unroll
    for (int r=0;r<4;r++) Q3[rw+hi*4+r][l15+16*t]=f2b(oacc[t][r]);
  }
  __syncthreads();
  f4 a2[8];
  #pragma unroll
  for (int t=0;t<8;t++){ float bb=bo3[l15+16*t]; a2[t]=(f4){bb,bb,bb,bb}; }
  #pragma unroll
  for (int kk=0;kk<4;kk++){
    s8 a = *(const s8*)&Q3[rw+l15][kk*32+hi*8];
    #pragma unroll
    for (int t=0;t<8;t++){
      s8 bf = ldw8f(wo3 + (size_t)(t*16+l15)*D_ + kk*32+hi*8);
      a2[t]=mfma16(a,bf,a2[t]);
    }
  }
  __syncthreads();
  float g2v[8],b2v[8];
  #pragma unroll
  for (int t=0;t<8;t++){ g2v[t]=l2g[l15+16*t]; b2v[t]=l2b[l15+16*t]; }
  #pragma unroll
  for (int r=0;r<4;r++){
    const int row=rw+hi*4+r;
    const int nr = min(n0+row, N_-1);
    const size_t gr=(size_t)b*N_+nr;
    float tmp[8]; float s=0.f,s2=0.f;
    #pragma unroll
    for (int t=0;t<8;t++){
      float vv = b2f(V1[gr*D_ + l15+16*t]) + a2[t][r];
      tmp[t]=vv; s+=vv; s2+=vv*vv;
    }
    s=rsum16(s); s2=rsum16(s2);
    float mean=s*(1.f/128.f);
    float rstd=rsqrtf(s2*(1.f/128.f)-mean*mean+1e-5f);
    #pragma unroll
    for (int t=0;t<8;t++){
      P3[row][l15+16*t]=f2b(nn(tmp[t],1e4f));
      Wt[row][l15+16*t]=f2b(nn((tmp[t]-mean)*rstd*g2v[t]+b2v[t],1e4f));
    }
  }
  __syncthreads();
  if (n0+nl < N_){
    const size_t gd=(size_t)b*N_+n0+nl;
    #pragma unroll
    for (int j=0;j<4;j++){
      int u=part+4*j;
      *(uint4*)(V2 + gd*D_ + u*8) = *(const uint4*)&P3[nl][u*8];
      *(uint4*)(XLN + gd*D_ + u*8) = *(const uint4*)&Wt[nl][u*8];
    }
  }
}

// ---------------------------------------------------------------------------
// K6b: FFN: V3(f32 out) = V2 + W2f(silu(W1f(x)))
// ---------------------------------------------------------------------------
__global__ __launch_bounds__(256,2) void k_ffn(
  const u16* __restrict__ XLN, const u16* __restrict__ V2,
  const float* __restrict__ w1, const float* __restrict__ b1,
  const float* __restrict__ w2, const float* __restrict__ b2,
  float* __restrict__ V3)
{
  __shared__ u16 Xs[64][136];
  __shared__ u16 Hs[64][136];
  const int tid=threadIdx.x, nl=tid>>2, part=tid&3;
  const size_t gn = (size_t)blockIdx.x*64 + nl;
  #pragma unroll
  for (int j=0;j<4;j++){ int u=part+4*j; *(uint4*)&Xs[nl][u*8] = *(const uint4*)(XLN + gn*D_ + u*8); }
  __syncthreads();
  const int lane=tid&63, w=tid>>6, l15=lane&15, hi=lane>>4, rw=w*16;
  f4 accf[8];
  #pragma unroll
  for (int t=0;t<8;t++){ float bb=b2[l15+16*t]; accf[t]=(f4){bb,bb,bb,bb}; }
  for (int half=0;half<2;half++){
    f4 ah[8];
    #pragma unroll
    for (int t=0;t<8;t++){ float bb=b1[half*128 + l15+16*t]; ah[t]=(f4){bb,bb,bb,bb}; }
    #pragma unroll
    for (int kk=0;kk<4;kk++){
      s8 a = *(const s8*)&Xs[rw+l15][kk*32+hi*8];
      #pragma unroll
      for (int t=0;t<8;t++){
        s8 bf = ldw8f(w1 + (size_t)(half*128 + t*16+l15)*D_ + kk*32+hi*8);
        ah[t]=mfma16(a,bf,ah[t]);
      }
    }
    __syncthreads();
    #pragma unroll
    for (int t=0;t<8;t++){
      #pragma unroll
      for (int r=0;r<4;r++) Hs[rw+hi*4+r][l15+16*t]=f2b(silu_f(ah[t][r]));
    }
    __syncthreads();
    #pragma unroll
    for (int kk=0;kk<4;kk++){
      s8 a = *(const s8*)&Hs[rw+l15][kk*32+hi*8];
      #pragma unroll
      for (int t=0;t<8;t++){
        s8 bf = ldw8f(w2 + (size_t)(t*16+l15)*256 + half*128 + kk*32+hi*8);
        accf[t]=mfma16(a,bf,accf[t]);
      }
    }
    __syncthreads();
  }
  // V3 = V2 + FFN, f32 stores (16-lane-contiguous 64B segments)
  #pragma unroll
  for (int r=0;r<4;r++){
    const int row=rw+hi*4+r;
    const size_t gr=(size_t)blockIdx.x*64+row;
    #pragma unroll
    for (int t=0;t<8;t++){
      int col=l15+16*t;
      V3[gr*D_+col] = nn(b2f(V2[gr*D_+col])+accf[t][r], 9e3f);  // sentinel: k_ffn
    }
  }
}

// ---------------------------------------------------------------------------
extern "C" void kernel_launch(void* const* d_in, const int* in_sizes, int n_in,
                              void* d_out, int out_size, void* d_ws, size_t ws_size,
                              hipStream_t stream)
{
  const float* V     = (const float*)d_in[0];
  const float* E     = (const float*)d_in[1];
  const int* edges   = (const int*)d_in[2];
  const float* senc  = (const float*)d_in[3];
  const float* fe_w1=(const float*)d_in[4];  const float* fe_b1=(const float*)d_in[5];
  const float* fe_w2=(const float*)d_in[6];  const float* fe_b2=(const float*)d_in[7];
  const float* fe_g =(const float*)d_in[8];  const float* fe_be=(const float*)d_in[9];
  const float* fn_w1=(const float*)d_in[10]; const float* fn_b1=(const float*)d_in[11];
  const float* fn_w2=(const float*)d_in[12]; const float* fn_b2=(const float*)d_in[13];
  const float* fn_g =(const float*)d_in[14]; const float* fn_be=(const float*)d_in[15];
  const float* ln1_g=(const float*)d_in[16]; const float* ln1_b=(const float*)d_in[17];
  const float* ln2_g=(const float*)d_in[18]; const float* ln2_b=(const float*)d_in[19];
  const float* Q    =(const float*)d_in[20];
  const float* a1_wqkv=(const float*)d_in[21]; const float* a1_bqkv=(const float*)d_in[22];
  const float* a1_wo=(const float*)d_in[23];   const float* a1_bo=(const float*)d_in[24];
  const float* a2_wqkv=(const float*)d_in[25]; const float* a2_bqkv=(const float*)d_in[26];
  const float* a2_wo=(const float*)d_in[27];   const float* a2_bo=(const float*)d_in[28];
  const float* a3_wqkv=(const float*)d_in[29]; const float* a3_bqkv=(const float*)d_in[30];
  const float* a3_wo=(const float*)d_in[31];   const float* a3_bo=(const float*)d_in[32];
  const float* ffn_w1=(const float*)d_in[33];  const float* ffn_b1=(const float*)d_in[34];
  const float* ffn_w2=(const float*)d_in[35];  const float* ffn_b2=(const float*)d_in[36];

  char* ws = (char*)d_ws;
  size_t off = 0;
  auto alloc = [&](size_t bytes)->void*{ void* p = ws + off; off += (bytes + 255) & ~(size_t)255; return p; };
  float* m0s = (float*)alloc((size_t)B_*N_*64*4);
  float* m1s = (float*)alloc((size_t)B_*N_*64*4);
  float* c0s = (float*)alloc((size_t)B_*N_*4);
  float* c1s = (float*)alloc((size_t)B_*N_*4);
  u16* V1  = (u16*)alloc((size_t)B_*N_*D_*2);
  u16* W0  = (u16*)alloc((size_t)B_*N_*D_*2);
  u16* kh1 = (u16*)alloc((size_t)B_*H_*N_*32*2);
  u16* vh1 = (u16*)alloc((size_t)B_*H_*N_*32*2);
  u16* qh1 = (u16*)alloc((size_t)H_*T_*32*2);
  float* o1 = (float*)alloc((size_t)B_*T_*D_*4);
  u16* qh2 = (u16*)alloc((size_t)B_*H_*T_*32*2);
  u16* kh2 = (u16*)alloc((size_t)B_*H_*T_*32*2);
  u16* vh2 = (u16*)alloc((size_t)B_*H_*T_*32*2);
  float* o2 = (float*)alloc((size_t)B_*T_*D_*4);
  u16* kh3 = (u16*)alloc((size_t)B_*H_*T_*32*2);
  u16* vh3T= (u16*)alloc((size_t)B_*H_*32*T_*2);
  u16* V2  = (u16*)alloc((size_t)B_*N_*D_*2);
  u16* XLN = (u16*)alloc((size_t)B_*N_*D_*2);
  if (ws_size < off) return;

  float* outp = (float*)d_out;
  float* V3out = outp;
  float* Eout  = outp + (size_t)B_*N_*D_;

  hipMemsetAsync(d_ws, 0, off, stream);
  k_edge<<<(B_*NE_)/64,256,0,stream>>>(V,E,edges,senc, fe_w1,fe_b1,fe_w2,fe_b2,fe_g,fe_be,
                                       m0s,m1s,c0s,c1s, Eout);
  k_node<<<(B_*N_)/64,256,0,stream>>>(V,senc,m0s,m1s,c0s,c1s, fn_w1,fn_b1,fn_w2,fn_b2,fn_g,fn_be,
                                      ln1_g,ln1_b, V1,W0);
  k_qh1<<<T_/64,256,0,stream>>>(Q, a1_wqkv, a1_bqkv, qh1);
  k_kv1<<<(B_*N_)/64,256,0,stream>>>(W0, a1_wqkv, a1_bqkv, kh1, vh1);
  k_mha1<<<(B_*H_*T_)/4,256,0,stream>>>(qh1,kh1,vh1,o1);
  k_att12<<<(B_*T_)/64,256,0,stream>>>(o1, a1_wo, a1_bo, a2_wqkv, a2_bqkv, qh2,kh2,vh2);
  k_mha2<<<(B_*H_*T_)/4,256,0,stream>>>(qh2,kh2,vh2,o2);
  k_att23<<<(B_*T_)/64,256,0,stream>>>(o2, a2_wo, a2_bo, a3_wqkv, a3_bqkv, kh3, vh3T);
  k_mha3<<<B_*157,256,0,stream>>>(W0,V1, a3_wqkv,a3_bqkv, kh3,vh3T, a3_wo,a3_bo,
                                  ln2_g,ln2_b, V2,XLN);
  k_ffn<<<(B_*N_)/64,256,0,stream>>>(XLN,V2, ffn_w1,ffn_b1, ffn_w2,ffn_b2, V3out);
}

// Round 5
// 790.628 us; speedup vs baseline: 1.9143x; 1.9143x over previous
//
#include <hip/hip_runtime.h>
#include <hip/hip_bf16.h>

#define B_ 4
#define N_ 10000
#define NE_ 100000
#define D_ 128
#define S_ 64
#define H_ 4
#define T_ 128

typedef unsigned short u16;
typedef unsigned int u32;
typedef __attribute__((ext_vector_type(4))) float f4;
typedef __attribute__((ext_vector_type(8))) short s8;

#define DEVI static __device__ __forceinline__

DEVI float b2f(u16 u){ union{u32 i; float f;} v; v.i=((u32)u)<<16; return v.f; }
DEVI u16 f2b(float f){ union{float ff; u32 i;} v; v.ff=f; u32 i=v.i; return (u16)((i+0x7fffu+((i>>16)&1u))>>16); }
DEVI f4 mfma16(s8 a, s8 b, f4 c){ return __builtin_amdgcn_mfma_f32_16x16x32_bf16(a,b,c,0,0,0); }
DEVI float rsum16(float x){ x+=__shfl_xor(x,1); x+=__shfl_xor(x,2); x+=__shfl_xor(x,4); x+=__shfl_xor(x,8); return x; }
DEVI float silu_f(float v){ return v/(1.f+__expf(-v)); }
DEVI float nn(float v, float s){ return (v==v)? v : s; }
DEVI float lo2f(u32 u){ union{u32 i; float f;} v; v.i=u<<16; return v.f; }
DEVI float hi2f(u32 u){ union{u32 i; float f;} v; v.i=u&0xffff0000u; return v.f; }

// load 8 consecutive f32 -> 8 bf16 packed fragment (for small kernels)
DEVI s8 ldw8f(const float* p){
  f4 a = *(const f4*)p;
  f4 c = *(const f4*)(p+4);
  union { u16 t[8]; s8 v; } u;
  #pragma unroll
  for (int i=0;i<4;i++){ u.t[i]=f2b(a[i]); u.t[4+i]=f2b(c[i]); }
  return u.v;
}
DEVI uint4 cvt8(const float* p){
  f4 a = *(const f4*)p;
  f4 c = *(const f4*)(p+4);
  union { u16 t[8]; uint4 v; } u;
  #pragma unroll
  for (int i=0;i<4;i++){ u.t[i]=f2b(a[i]); u.t[4+i]=f2b(c[i]); }
  return u.v;
}

// ---------------------------------------------------------------------------
// weight preconversion f32 -> bf16, 9 segments concatenated in ws
// ---------------------------------------------------------------------------
#define WO_FE1 0
#define WO_FE2 65536
#define WO_FN1 81920
#define WO_FN2 122880
#define WO_A1  139264
#define WO_A3  188416
#define WO_A3O 237568
#define WO_FF1 253952
#define WO_FF2 286720
#define WTOT   319488

__global__ __launch_bounds__(256) void k_cvtw(
  const float* __restrict__ s0, const float* __restrict__ s1,
  const float* __restrict__ s2, const float* __restrict__ s3,
  const float* __restrict__ s4, const float* __restrict__ s5,
  const float* __restrict__ s6, const float* __restrict__ s7,
  const float* __restrict__ s8v, u16* __restrict__ dst)
{
  int i = (blockIdx.x*256 + threadIdx.x)*8;
  if (i >= WTOT) return;
  const float* src; int off;
  if      (i < WO_FE2){ src=s0;  off=WO_FE1; }
  else if (i < WO_FN1){ src=s1;  off=WO_FE2; }
  else if (i < WO_FN2){ src=s2;  off=WO_FN1; }
  else if (i < WO_A1 ){ src=s3;  off=WO_FN2; }
  else if (i < WO_A3 ){ src=s4;  off=WO_A1;  }
  else if (i < WO_A3O){ src=s5;  off=WO_A3;  }
  else if (i < WO_FF1){ src=s6;  off=WO_A3O; }
  else if (i < WO_FF2){ src=s7;  off=WO_FF1; }
  else                { src=s8v; off=WO_FF2; }
  *(uint4*)(dst+i) = cvt8(src + (i-off));
}

// ---------------------------------------------------------------------------
// K1: edge MLP, col-split GEMMs (wave w owns output cols w*32..w*32+31)
// ---------------------------------------------------------------------------
__global__ __launch_bounds__(256,2) void k_edge(
  const float* __restrict__ V, const float* __restrict__ E, const int* __restrict__ edges,
  const float* __restrict__ senc,
  const u16* __restrict__ w1b, const float* __restrict__ b1,
  const u16* __restrict__ w2b, const float* __restrict__ b2,
  const float* __restrict__ lng, const float* __restrict__ lnb,
  float* __restrict__ m0s, float* __restrict__ m1s,
  float* __restrict__ c0s, float* __restrict__ c1s,
  float* __restrict__ Eout)
{
  __shared__ u16 X[64][520];
  __shared__ int gi0[64], gi1[64];
  __shared__ float fvalid[64];
  __shared__ float rsA[64][4], rsB[64][4];
  const int tid = threadIdx.x;
  const int el = tid>>2, part = tid&3;
  const int ge = blockIdx.x*64 + el;
  const int b = ge / NE_;
  const int2 ed = *(const int2*)(edges + (size_t)ge*2);
  const int i0 = min(max(ed.x,0),N_-1), i1 = min(max(ed.y,0),N_-1);
  if (part==0){
    gi0[el] = b*N_ + i0; gi1[el] = b*N_ + i1;
    fvalid[el] = (ed.x>=0 && ed.y>=0) ? 1.f : 0.f;
  }
  {
    const float* Vb = V + (size_t)b*N_*D_;
    const float* Sb = senc + (size_t)b*N_*S_;
    const float* Ep = E + (size_t)ge*D_;
    #pragma unroll
    for (int j=0;j<16;j++){
      int u = part + 4*j;
      const float* p;
      if (u<16)      p = Vb + (size_t)i0*D_ + u*8;
      else if (u<24) p = Sb + (size_t)i0*S_ + (u-16)*8;
      else if (u<40) p = Vb + (size_t)i1*D_ + (u-24)*8;
      else if (u<48) p = Sb + (size_t)i1*S_ + (u-40)*8;
      else           p = Ep + (u-48)*8;
      *(uint4*)&X[el][u*8] = cvt8(p);
    }
  }
  __syncthreads();
  if (tid < 64){
    atomicAdd(&c0s[gi0[tid]], 1.f);
    atomicAdd(&c1s[gi1[tid]], 1.f);
  }
  const int lane = tid&63, w = tid>>6;
  const int l15 = lane&15, hi = lane>>4;
  const int colb = w*32;
  // stage 1: H = silu(X @ w1^T + b1), this wave's 32 cols, all 64 rows
  f4 acc[4][2];
  #pragma unroll
  for (int m=0;m<4;m++)
    #pragma unroll
    for (int tl=0;tl<2;tl++){ float bb=b1[colb+tl*16+l15]; acc[m][tl]=(f4){bb,bb,bb,bb}; }
  for (int kk=0;kk<16;kk++){
    s8 bfr[2];
    #pragma unroll
    for (int tl=0;tl<2;tl++)
      bfr[tl] = *(const s8*)(w1b + (size_t)(colb+tl*16+l15)*512 + kk*32 + hi*8);
    #pragma unroll
    for (int m=0;m<4;m++){
      s8 a = *(const s8*)&X[m*16+l15][kk*32 + hi*8];
      #pragma unroll
      for (int tl=0;tl<2;tl++) acc[m][tl] = mfma16(a, bfr[tl], acc[m][tl]);
    }
  }
  __syncthreads();   // stage-1 reads of X done before H overwrite
  #pragma unroll
  for (int m=0;m<4;m++)
    #pragma unroll
    for (int tl=0;tl<2;tl++)
      #pragma unroll
      for (int r=0;r<4;r++)
        X[m*16+hi*4+r][colb+tl*16+l15] = f2b(silu_f(acc[m][tl][r]));
  __syncthreads();
  // stage 2: Y = H @ w2^T + b2
  f4 a2[4][2];
  #pragma unroll
  for (int m=0;m<4;m++)
    #pragma unroll
    for (int tl=0;tl<2;tl++){ float bb=b2[colb+tl*16+l15]; a2[m][tl]=(f4){bb,bb,bb,bb}; }
  #pragma unroll
  for (int kk=0;kk<4;kk++){
    s8 bfr[2];
    #pragma unroll
    for (int tl=0;tl<2;tl++)
      bfr[tl] = *(const s8*)(w2b + (size_t)(colb+tl*16+l15)*128 + kk*32 + hi*8);
    #pragma unroll
    for (int m=0;m<4;m++){
      s8 a = *(const s8*)&X[m*16+l15][kk*32 + hi*8];
      #pragma unroll
      for (int tl=0;tl<2;tl++) a2[m][tl] = mfma16(a, bfr[tl], a2[m][tl]);
    }
  }
  // cross-wave LN row reduction (each row spans 4 waves now)
  #pragma unroll
  for (int m=0;m<4;m++)
    #pragma unroll
    for (int r=0;r<4;r++){
      float ps=0.f, pq=0.f;
      #pragma unroll
      for (int tl=0;tl<2;tl++){ float v=a2[m][tl][r]; ps+=v; pq+=v*v; }
      ps=rsum16(ps); pq=rsum16(pq);
      if (l15==0){ int row=m*16+hi*4+r; rsA[row][w]=ps; rsB[row][w]=pq; }
    }
  __syncthreads();
  float gv[2], bev[2];
  #pragma unroll
  for (int tl=0;tl<2;tl++){ gv[tl]=lng[colb+tl*16+l15]; bev[tl]=lnb[colb+tl*16+l15]; }
  const int ge0 = blockIdx.x*64;
  #pragma unroll
  for (int m=0;m<4;m++)
    #pragma unroll
    for (int r=0;r<4;r++){
      const int row = m*16+hi*4+r;
      float s  = rsA[row][0]+rsA[row][1]+rsA[row][2]+rsA[row][3];
      float s2 = rsB[row][0]+rsB[row][1]+rsB[row][2]+rsB[row][3];
      const float mean = s*(1.f/128.f);
      const float rstd = rsqrtf(s2*(1.f/128.f) - mean*mean + 1e-5f);
      const float vm = fvalid[row];
      const int g0 = gi0[row], g1 = gi1[row];
      #pragma unroll
      for (int tl=0;tl<2;tl++){
        const int col = colb+tl*16+l15;
        float ev = ((a2[m][tl][r]-mean)*rstd*gv[tl] + bev[tl]) * vm;
        if (col < 64) atomicAdd(m0s + (size_t)g0*64 + col, ev);
        else          atomicAdd(m1s + (size_t)g1*64 + (col-64), ev);
        const size_t eidx = (size_t)(ge0+row)*D_ + col;
        Eout[eidx] = E[eidx] + ev;
      }
    }
}

// ---------------------------------------------------------------------------
// K2: node MLP + V1 = V+v_emb + W0 = LN(V1), col-split
// ---------------------------------------------------------------------------
__global__ __launch_bounds__(256,2) void k_node(
  const float* __restrict__ V, const float* __restrict__ senc,
  const float* __restrict__ m0s, const float* __restrict__ m1s,
  const float* __restrict__ c0s, const float* __restrict__ c1s,
  const u16* __restrict__ w1b, const float* __restrict__ b1,
  const u16* __restrict__ w2b, const float* __restrict__ b2,
  const float* __restrict__ lng, const float* __restrict__ lnb,
  const float* __restrict__ l1g, const float* __restrict__ l1b,
  u16* __restrict__ V1, u16* __restrict__ W0)
{
  __shared__ u16 X[64][328];
  __shared__ float rsA[64][4], rsB[64][4];
  const int tid=threadIdx.x, nl=tid>>2, part=tid&3;
  const int gn = blockIdx.x*64 + nl;
  const int b = gn / N_, n = gn - b*N_;
  {
    const float* Vp = V + ((size_t)b*N_ + n)*D_;
    const float* Sp = senc + ((size_t)b*N_ + n)*S_;
    #pragma unroll
    for (int j=0;j<6;j++){
      int u = part + 4*j;
      const float* p = (u<16)? Vp + u*8 : Sp + (u-16)*8;
      *(uint4*)&X[nl][u*8] = cvt8(p);
    }
    const float rc0 = 1.f/fmaxf(c0s[gn],1.f), rc1 = 1.f/fmaxf(c1s[gn],1.f);
    #pragma unroll
    for (int j=0;j<8;j++){
      int c = part*32 + j*4;
      const float* src = (c<64)? m0s + (size_t)gn*64 + c : m1s + (size_t)gn*64 + (c-64);
      float rr = (c<64)? rc0 : rc1;
      f4 mv = *(const f4*)src;
      u16 ov[4];
      #pragma unroll
      for (int i=0;i<4;i++) ov[i]=f2b(mv[i]*rr);
      uint2 pk; __builtin_memcpy(&pk, ov, 8);
      *(uint2*)&X[nl][192+c] = pk;
    }
  }
  __syncthreads();
  const int lane=tid&63, w=tid>>6, l15=lane&15, hi=lane>>4, colb=w*32;
  // stage 1: K=320
  f4 acc[4][2];
  #pragma unroll
  for (int m=0;m<4;m++)
    #pragma unroll
    for (int tl=0;tl<2;tl++){ float bb=b1[colb+tl*16+l15]; acc[m][tl]=(f4){bb,bb,bb,bb}; }
  for (int kk=0;kk<10;kk++){
    s8 bfr[2];
    #pragma unroll
    for (int tl=0;tl<2;tl++)
      bfr[tl] = *(const s8*)(w1b + (size_t)(colb+tl*16+l15)*320 + kk*32 + hi*8);
    #pragma unroll
    for (int m=0;m<4;m++){
      s8 a = *(const s8*)&X[m*16+l15][kk*32+hi*8];
      #pragma unroll
      for (int tl=0;tl<2;tl++) acc[m][tl]=mfma16(a,bfr[tl],acc[m][tl]);
    }
  }
  __syncthreads();
  #pragma unroll
  for (int m=0;m<4;m++)
    #pragma unroll
    for (int tl=0;tl<2;tl++)
      #pragma unroll
      for (int r=0;r<4;r++)
        X[m*16+hi*4+r][192+colb+tl*16+l15] = f2b(silu_f(acc[m][tl][r]));
  __syncthreads();
  // stage 2
  f4 a2[4][2];
  #pragma unroll
  for (int m=0;m<4;m++)
    #pragma unroll
    for (int tl=0;tl<2;tl++){ float bb=b2[colb+tl*16+l15]; a2[m][tl]=(f4){bb,bb,bb,bb}; }
  #pragma unroll
  for (int kk=0;kk<4;kk++){
    s8 bfr[2];
    #pragma unroll
    for (int tl=0;tl<2;tl++)
      bfr[tl] = *(const s8*)(w2b + (size_t)(colb+tl*16+l15)*128 + kk*32 + hi*8);
    #pragma unroll
    for (int m=0;m<4;m++){
      s8 a = *(const s8*)&X[m*16+l15][192 + kk*32+hi*8];
      #pragma unroll
      for (int tl=0;tl<2;tl++) a2[m][tl]=mfma16(a,bfr[tl],a2[m][tl]);
    }
  }
  // LN round 1 (over v_emb GEMM output)
  #pragma unroll
  for (int m=0;m<4;m++)
    #pragma unroll
    for (int r=0;r<4;r++){
      float ps=0.f, pq=0.f;
      #pragma unroll
      for (int tl=0;tl<2;tl++){ float v=a2[m][tl][r]; ps+=v; pq+=v*v; }
      ps=rsum16(ps); pq=rsum16(pq);
      if (l15==0){ int row=m*16+hi*4+r; rsA[row][w]=ps; rsB[row][w]=pq; }
    }
  __syncthreads();
  float gv[2],bev[2],g1v[2],b1v[2];
  #pragma unroll
  for (int tl=0;tl<2;tl++){
    int col=colb+tl*16+l15;
    gv[tl]=lng[col]; bev[tl]=lnb[col]; g1v[tl]=l1g[col]; b1v[tl]=l1b[col];
  }
  #pragma unroll
  for (int m=0;m<4;m++)
    #pragma unroll
    for (int r=0;r<4;r++){
      const int row=m*16+hi*4+r;
      float s  = rsA[row][0]+rsA[row][1]+rsA[row][2]+rsA[row][3];
      float s2 = rsB[row][0]+rsB[row][1]+rsB[row][2]+rsB[row][3];
      float mean=s*(1.f/128.f);
      float rstd=rsqrtf(s2*(1.f/128.f)-mean*mean+1e-5f);
      #pragma unroll
      for (int tl=0;tl<2;tl++){
        float ve=(a2[m][tl][r]-mean)*rstd*gv[tl]+bev[tl];
        a2[m][tl][r] = b2f(X[row][colb+tl*16+l15]) + ve;   // tmp = V1
      }
    }
  __syncthreads();   // all waves done reading round-1 rs
  // LN round 2 (over V1)
  #pragma unroll
  for (int m=0;m<4;m++)
    #pragma unroll
    for (int r=0;r<4;r++){
      float ps=0.f, pq=0.f;
      #pragma unroll
      for (int tl=0;tl<2;tl++){ float v=a2[m][tl][r]; ps+=v; pq+=v*v; }
      ps=rsum16(ps); pq=rsum16(pq);
      if (l15==0){ int row=m*16+hi*4+r; rsA[row][w]=ps; rsB[row][w]=pq; }
    }
  __syncthreads();
  #pragma unroll
  for (int m=0;m<4;m++)
    #pragma unroll
    for (int r=0;r<4;r++){
      const int row=m*16+hi*4+r;
      float sv  = rsA[row][0]+rsA[row][1]+rsA[row][2]+rsA[row][3];
      float sv2 = rsB[row][0]+rsB[row][1]+rsB[row][2]+rsB[row][3];
      float m2=sv*(1.f/128.f);
      float rs2=rsqrtf(sv2*(1.f/128.f)-m2*m2+1e-5f);
      #pragma unroll
      for (int tl=0;tl<2;tl++){
        int col=colb+tl*16+l15;
        float tmp=a2[m][tl][r];
        X[row][col]     = f2b(tmp);
        X[row][192+col] = f2b((tmp-m2)*rs2*g1v[tl]+b1v[tl]);
      }
    }
  __syncthreads();
  #pragma unroll
  for (int j=0;j<4;j++){
    int u=part+4*j;
    *(uint4*)(V1 + (size_t)gn*D_ + u*8) = *(const uint4*)&X[nl][u*8];
    *(uint4*)(W0 + (size_t)gn*D_ + u*8) = *(const uint4*)&X[nl][192 + u*8];
  }
}

// ---------------------------------------------------------------------------
// K3q: qh1 = Q@wq1^T+bq1  (tiny, unchanged)
// ---------------------------------------------------------------------------
__global__ __launch_bounds__(256) void k_qh1(
  const float* __restrict__ Q, const float* __restrict__ wqkv, const float* __restrict__ bqkv,
  u16* __restrict__ qh1)
{
  __shared__ u16 X[64][136];
  const int tid=threadIdx.x, nl=tid>>2, part=tid&3;
  const int q = blockIdx.x*64 + nl;
  #pragma unroll
  for (int j=0;j<4;j++){ int u=part+4*j; *(uint4*)&X[nl][u*8] = cvt8(Q + (size_t)q*D_ + u*8); }
  __syncthreads();
  const int lane=tid&63, w=tid>>6, l15=lane&15, hi=lane>>4, rw=w*16;
  f4 acc[8];
  #pragma unroll
  for (int t=0;t<8;t++){ float bb=bqkv[l15+16*t]; acc[t]=(f4){bb,bb,bb,bb}; }
  #pragma unroll
  for (int kk=0;kk<4;kk++){
    s8 a = *(const s8*)&X[rw+l15][kk*32+hi*8];
    #pragma unroll
    for (int t=0;t<8;t++){
      s8 bf = ldw8f(wqkv + (size_t)(t*16+l15)*D_ + kk*32+hi*8);
      acc[t]=mfma16(a,bf,acc[t]);
    }
  }
  __syncthreads();
  #pragma unroll
  for (int t=0;t<8;t++){
    #pragma unroll
    for (int r=0;r<4;r++) X[rw+hi*4+r][l15+16*t]=f2b(acc[t][r]);
  }
  __syncthreads();
  #pragma unroll
  for (int j=0;j<4;j++){
    int u=part+4*j, col0=u*8, h=col0>>5, d=col0&31;
    *(uint4*)(qh1 + ((size_t)h*T_ + q)*32 + d) = *(const uint4*)&X[nl][col0];
  }
}

// ---------------------------------------------------------------------------
// K3: kh1/vh1 = W0 @ [wk1;wv1]^T, col-split (wave owns 64 of 256 out cols)
// ---------------------------------------------------------------------------
__global__ __launch_bounds__(256,2) void k_kv1(
  const u16* __restrict__ W0, const u16* __restrict__ wqkvb, const float* __restrict__ bqkv,
  u16* __restrict__ kh1, u16* __restrict__ vh1)
{
  __shared__ u16 X[64][264];
  const int tid=threadIdx.x, nl=tid>>2, part=tid&3;
  const int gn = blockIdx.x*64 + nl;
  const int b = gn / N_, n = gn - b*N_;
  #pragma unroll
  for (int j=0;j<4;j++){ int u=part+4*j; *(uint4*)&X[nl][u*8] = *(const uint4*)(W0 + (size_t)gn*D_ + u*8); }
  __syncthreads();
  const int lane=tid&63, w=tid>>6, l15=lane&15, hi=lane>>4;
  const int colb = w*64;  // of 256 kv out cols
  f4 acc[4][4];
  #pragma unroll
  for (int m=0;m<4;m++)
    #pragma unroll
    for (int tl=0;tl<4;tl++){ float bb=bqkv[128 + colb+tl*16+l15]; acc[m][tl]=(f4){bb,bb,bb,bb}; }
  #pragma unroll
  for (int kk=0;kk<4;kk++){
    s8 bfr[4];
    #pragma unroll
    for (int tl=0;tl<4;tl++)
      bfr[tl] = *(const s8*)(wqkvb + (size_t)(128 + colb+tl*16+l15)*D_ + kk*32+hi*8);
    #pragma unroll
    for (int m=0;m<4;m++){
      s8 a = *(const s8*)&X[m*16+l15][kk*32+hi*8];
      #pragma unroll
      for (int tl=0;tl<4;tl++) acc[m][tl]=mfma16(a,bfr[tl],acc[m][tl]);
    }
  }
  __syncthreads();
  #pragma unroll
  for (int m=0;m<4;m++)
    #pragma unroll
    for (int tl=0;tl<4;tl++)
      #pragma unroll
      for (int r=0;r<4;r++)
        X[m*16+hi*4+r][colb+tl*16+l15]=f2b(acc[m][tl][r]);
  __syncthreads();
  #pragma unroll
  for (int j=0;j<8;j++){
    int u=part+4*j, col0=u*8;
    u16* dst;
    if (col0<128){ int h=col0>>5, d=col0&31; dst = kh1 + ((size_t)(b*H_+h)*N_ + n)*32 + d; }
    else { int c2=col0-128; int h=c2>>5, d=c2&31; dst = vh1 + ((size_t)(b*H_+h)*N_ + n)*32 + d; }
    *(uint4*)dst = *(const uint4*)&X[nl][col0];
  }
}

// ---------------------------------------------------------------------------
// online-softmax wave-per-row attention core (hd=32)
// ---------------------------------------------------------------------------
DEVI void mha_core(const float* qv, const u16* Kb, const u16* Vb, int nk,
                   int lane, float* outp)
{
  const float scale = 0.17677669529663687f;
  float m=-1e30f, ssum=0.f, o[32];
  #pragma unroll
  for (int i=0;i<32;i++) o[i]=0.f;
  for (int c0=0;c0<nk;c0+=64){
    int key=c0+lane, keyc = key<nk? key: nk-1;
    const uint4* kp=(const uint4*)(Kb+(size_t)keyc*32);
    float sa=0.f;
    #pragma unroll
    for (int i=0;i<4;i++){ uint4 u=kp[i];
      sa += qv[i*8+0]*lo2f(u.x)+qv[i*8+1]*hi2f(u.x)+qv[i*8+2]*lo2f(u.y)+qv[i*8+3]*hi2f(u.y)
          + qv[i*8+4]*lo2f(u.z)+qv[i*8+5]*hi2f(u.z)+qv[i*8+6]*lo2f(u.w)+qv[i*8+7]*hi2f(u.w);
    }
    float s=sa*scale;
    float mn=fmaxf(m,s);
    float corr=__expf(m-mn);
    float p=(key<nk)?__expf(s-mn):0.f;
    ssum=ssum*corr+p;
    const uint4* vp=(const uint4*)(Vb+(size_t)keyc*32);
    #pragma unroll
    for (int i=0;i<4;i++){ uint4 u=vp[i];
      o[i*8+0]=o[i*8+0]*corr+p*lo2f(u.x); o[i*8+1]=o[i*8+1]*corr+p*hi2f(u.x);
      o[i*8+2]=o[i*8+2]*corr+p*lo2f(u.y); o[i*8+3]=o[i*8+3]*corr+p*hi2f(u.y);
      o[i*8+4]=o[i*8+4]*corr+p*lo2f(u.z); o[i*8+5]=o[i*8+5]*corr+p*hi2f(u.z);
      o[i*8+6]=o[i*8+6]*corr+p*lo2f(u.w); o[i*8+7]=o[i*8+7]*corr+p*hi2f(u.w);
    }
    m=mn;
  }
  float M=m;
  #pragma unroll
  for (int d=32;d>=1;d>>=1) M=fmaxf(M,__shfl_xor(M,d));
  float sc=__expf(m-M);
  float sm=ssum*sc;
  #pragma unroll
  for (int d=32;d>=1;d>>=1) sm+=__shfl_xor(sm,d);
  float inv=1.f/sm;
  #pragma unroll
  for (int i=0;i<32;i++){
    float v=o[i]*sc;
    #pragma unroll
    for (int d=32;d>=1;d>>=1) v+=__shfl_xor(v,d);
    if (lane==0) outp[i]=v*inv;
  }
}

__global__ __launch_bounds__(256) void k_mha1(
  const u16* __restrict__ qh1, const u16* __restrict__ kh1, const u16* __restrict__ vh1,
  float* __restrict__ o1)
{
  const int blk=blockIdx.x, bh=blk>>5, b=bh>>2, h=bh&3;
  const int w=threadIdx.x>>6, lane=threadIdx.x&63;
  const int q=(blk&31)*4+w;
  float qv[32];
  const uint4* qp=(const uint4*)(qh1 + ((size_t)h*T_+q)*32);
  #pragma unroll
  for (int i=0;i<4;i++){ uint4 u=qp[i];
    qv[i*8+0]=lo2f(u.x); qv[i*8+1]=hi2f(u.x); qv[i*8+2]=lo2f(u.y); qv[i*8+3]=hi2f(u.y);
    qv[i*8+4]=lo2f(u.z); qv[i*8+5]=hi2f(u.z); qv[i*8+6]=lo2f(u.w); qv[i*8+7]=hi2f(u.w); }
  mha_core(qv, kh1+(size_t)bh*N_*32, vh1+(size_t)bh*N_*32, N_, lane,
           o1+((size_t)b*T_+q)*D_+h*32);
}

__global__ __launch_bounds__(256) void k_mha2(
  const u16* __restrict__ qh2, const u16* __restrict__ kh2, const u16* __restrict__ vh2,
  float* __restrict__ o2)
{
  const int blk=blockIdx.x, bh=blk>>5, b=bh>>2, h=bh&3;
  const int w=threadIdx.x>>6, lane=threadIdx.x&63;
  const int q=(blk&31)*4+w;
  float qv[32];
  const uint4* qp=(const uint4*)(qh2 + ((size_t)bh*T_+q)*32);
  #pragma unroll
  for (int i=0;i<4;i++){ uint4 u=qp[i];
    qv[i*8+0]=lo2f(u.x); qv[i*8+1]=hi2f(u.x); qv[i*8+2]=lo2f(u.y); qv[i*8+3]=hi2f(u.y);
    qv[i*8+4]=lo2f(u.z); qv[i*8+5]=hi2f(u.z); qv[i*8+6]=lo2f(u.w); qv[i*8+7]=hi2f(u.w); }
  mha_core(qv, kh2+(size_t)bh*T_*32, vh2+(size_t)bh*T_*32, T_, lane,
           o2+((size_t)b*T_+q)*D_+h*32);
}

// ---------------------------------------------------------------------------
// K5a: W1 = o1@wo1^T+bo1; {q,k,v}h2 = W1@wqkv2^T+bqkv2  (tiny, unchanged)
// ---------------------------------------------------------------------------
__global__ __launch_bounds__(256) void k_att12(
  const float* __restrict__ o1, const float* __restrict__ wo, const float* __restrict__ bo,
  const float* __restrict__ wqkv, const float* __restrict__ bqkv,
  u16* __restrict__ qh2, u16* __restrict__ kh2, u16* __restrict__ vh2)
{
  __shared__ u16 X[64][136];
  __shared__ u16 Y[64][392];
  const int tid=threadIdx.x, nl=tid>>2, part=tid&3;
  const int row = blockIdx.x*64 + nl;
  #pragma unroll
  for (int j=0;j<8;j++){
    int c = part*32 + j*4;
    f4 mv = *(const f4*)(o1 + (size_t)row*D_ + c);
    u16 ov[4];
    #pragma unroll
    for (int i=0;i<4;i++) ov[i]=f2b(nn(mv[i],2e4f));
    uint2 pk; __builtin_memcpy(&pk, ov, 8);
    *(uint2*)&X[nl][c]=pk;
  }
  __syncthreads();
  const int lane=tid&63, w=tid>>6, l15=lane&15, hi=lane>>4, rw=w*16;
  {
    f4 acc[8];
    #pragma unroll
    for (int t=0;t<8;t++){ float bb=bo[l15+16*t]; acc[t]=(f4){bb,bb,bb,bb}; }
    #pragma unroll
    for (int kk=0;kk<4;kk++){
      s8 a = *(const s8*)&X[rw+l15][kk*32+hi*8];
      #pragma unroll
      for (int t=0;t<8;t++){
        s8 bf = ldw8f(wo + (size_t)(t*16+l15)*D_ + kk*32+hi*8);
        acc[t]=mfma16(a,bf,acc[t]);
      }
    }
    #pragma unroll
    for (int t=0;t<8;t++){
      #pragma unroll
      for (int r=0;r<4;r++) Y[rw+hi*4+r][l15+16*t]=f2b(acc[t][r]);
    }
  }
  __syncthreads();
  f4 a2[24];
  #pragma unroll
  for (int t=0;t<24;t++){ float bb=bqkv[l15+16*t]; a2[t]=(f4){bb,bb,bb,bb}; }
  #pragma unroll
  for (int kk=0;kk<4;kk++){
    s8 a = *(const s8*)&Y[rw+l15][kk*32+hi*8];
    #pragma unroll
    for (int t=0;t<24;t++){
      s8 bf = ldw8f(wqkv + (size_t)(t*16+l15)*D_ + kk*32+hi*8);
      a2[t]=mfma16(a,bf,a2[t]);
    }
  }
  __syncthreads();
  #pragma unroll
  for (int t=0;t<24;t++){
    #pragma unroll
    for (int r=0;r<4;r++) Y[rw+hi*4+r][l15+16*t]=f2b(a2[t][r]);
  }
  __syncthreads();
  const int b=row>>7, q=row&127;
  #pragma unroll
  for (int j=0;j<12;j++){
    int u=part+4*j, col0=u*8;
    int sel=col0>>7, c2=col0&127, h=c2>>5, d=c2&31;
    u16* base = sel==0? qh2 : (sel==1? kh2 : vh2);
    *(uint4*)(base + ((size_t)(b*H_+h)*T_ + q)*32 + d) = *(const uint4*)&Y[nl][col0];
  }
}

// ---------------------------------------------------------------------------
// K5c: W2 = o2@wo2^T+bo2; kh3, vh3T  (tiny, unchanged)
// ---------------------------------------------------------------------------
__global__ __launch_bounds__(256) void k_att23(
  const float* __restrict__ o2, const float* __restrict__ wo, const float* __restrict__ bo,
  const float* __restrict__ wqkv3, const float* __restrict__ bqkv3,
  u16* __restrict__ kh3, u16* __restrict__ vh3T)
{
  __shared__ u16 X[64][136];
  __shared__ u16 Y[64][264];
  const int tid=threadIdx.x, nl=tid>>2, part=tid&3;
  const int row = blockIdx.x*64 + nl;
  #pragma unroll
  for (int j=0;j<8;j++){
    int c = part*32 + j*4;
    f4 mv = *(const f4*)(o2 + (size_t)row*D_ + c);
    u16 ov[4];
    #pragma unroll
    for (int i=0;i<4;i++) ov[i]=f2b(nn(mv[i],3e4f));
    uint2 pk; __builtin_memcpy(&pk, ov, 8);
    *(uint2*)&X[nl][c]=pk;
  }
  __syncthreads();
  const int lane=tid&63, w=tid>>6, l15=lane&15, hi=lane>>4, rw=w*16;
  {
    f4 acc[8];
    #pragma unroll
    for (int t=0;t<8;t++){ float bb=bo[l15+16*t]; acc[t]=(f4){bb,bb,bb,bb}; }
    #pragma unroll
    for (int kk=0;kk<4;kk++){
      s8 a = *(const s8*)&X[rw+l15][kk*32+hi*8];
      #pragma unroll
      for (int t=0;t<8;t++){
        s8 bf = ldw8f(wo + (size_t)(t*16+l15)*D_ + kk*32+hi*8);
        acc[t]=mfma16(a,bf,acc[t]);
      }
    }
    #pragma unroll
    for (int t=0;t<8;t++){
      #pragma unroll
      for (int r=0;r<4;r++) Y[rw+hi*4+r][l15+16*t]=f2b(acc[t][r]);
    }
  }
  __syncthreads();
  f4 a2[16];
  #pragma unroll
  for (int t=0;t<16;t++){ float bb=bqkv3[128 + l15+16*t]; a2[t]=(f4){bb,bb,bb,bb}; }
  #pragma unroll
  for (int kk=0;kk<4;kk++){
    s8 a = *(const s8*)&Y[rw+l15][kk*32+hi*8];
    #pragma unroll
    for (int t=0;t<16;t++){
      s8 bf = ldw8f(wqkv3 + (size_t)(128 + t*16+l15)*D_ + kk*32+hi*8);
      a2[t]=mfma16(a,bf,a2[t]);
    }
  }
  __syncthreads();
  #pragma unroll
  for (int t=0;t<16;t++){
    #pragma unroll
    for (int r=0;r<4;r++) Y[rw+hi*4+r][l15+16*t]=f2b(a2[t][r]);
  }
  __syncthreads();
  const int b=row>>7, q=row&127;
  #pragma unroll
  for (int j=0;j<4;j++){
    int u=part+4*j, col0=u*8, h=col0>>5, d=col0&31;
    *(uint4*)(kh3 + ((size_t)(b*H_+h)*T_ + q)*32 + d) = *(const uint4*)&Y[nl][col0];
  }
  #pragma unroll
  for (int cc=0;cc<32;cc++){
    int c2 = part*32 + cc;
    int h=c2>>5, d=c2&31;
    vh3T[((size_t)(b*H_+h)*32 + d)*T_ + q] = Y[nl][128+c2];
  }
}

// ---------------------------------------------------------------------------
// K6a: mha3 + wo3 + residual V1 -> V2, x=LN2(V2); projections col-split
// ---------------------------------------------------------------------------
__global__ __launch_bounds__(256,2) void k_mha3(
  const u16* __restrict__ W0, const u16* __restrict__ V1,
  const u16* __restrict__ wq3b, const float* __restrict__ bqkv3,
  const u16* __restrict__ kh3, const u16* __restrict__ vh3T,
  const u16* __restrict__ wo3b, const float* __restrict__ bo3,
  const float* __restrict__ l2g, const float* __restrict__ l2b,
  u16* __restrict__ V2, u16* __restrict__ XLN)
{
  __shared__ u16 Wt[64][136];
  __shared__ u16 Q3[64][136];
  __shared__ u16 P3[64][136];
  __shared__ float rsA[64][4], rsB[64][4];
  const int tid=threadIdx.x, nl=tid>>2, part=tid&3;
  const int b = blockIdx.x/157, tb = blockIdx.x - b*157;
  const int n0 = tb*64;
  {
    const int ns = min(n0+nl, N_-1);
    const u16* src = W0 + ((size_t)b*N_+ns)*D_;
    #pragma unroll
    for (int j=0;j<4;j++){ int u=part+4*j; *(uint4*)&Wt[nl][u*8] = *(const uint4*)(src+u*8); }
  }
  __syncthreads();
  const int lane=tid&63, w=tid>>6, l15=lane&15, hi=lane>>4;
  const int rw=w*16, colb=w*32;
  // Q3 = Wt @ wq3^T + bq3, col-split
  {
    f4 acc[4][2];
    #pragma unroll
    for (int m=0;m<4;m++)
      #pragma unroll
      for (int tl=0;tl<2;tl++){ float bb=bqkv3[colb+tl*16+l15]; acc[m][tl]=(f4){bb,bb,bb,bb}; }
    #pragma unroll
    for (int kk=0;kk<4;kk++){
      s8 bfr[2];
      #pragma unroll
      for (int tl=0;tl<2;tl++)
        bfr[tl] = *(const s8*)(wq3b + (size_t)(colb+tl*16+l15)*D_ + kk*32+hi*8);
      #pragma unroll
      for (int m=0;m<4;m++){
        s8 a = *(const s8*)&Wt[m*16+l15][kk*32+hi*8];
        #pragma unroll
        for (int tl=0;tl<2;tl++) acc[m][tl]=mfma16(a,bfr[tl],acc[m][tl]);
      }
    }
    #pragma unroll
    for (int m=0;m<4;m++)
      #pragma unroll
      for (int tl=0;tl<2;tl++)
        #pragma unroll
        for (int r=0;r<4;r++)
          Q3[m*16+hi*4+r][colb+tl*16+l15]=f2b(acc[m][tl][r]);
  }
  __syncthreads();
  // attention (row-split, rows rw..rw+15 per wave)
  const float scale=0.17677669529663687f;
  f4 oacc[8];
  #pragma unroll
  for (int t=0;t<8;t++) oacc[t]=(f4){0.f,0.f,0.f,0.f};
  #pragma unroll
  for (int h=0;h<H_;h++){
    f4 sa[8];
    #pragma unroll
    for (int t=0;t<8;t++) sa[t]=(f4){0.f,0.f,0.f,0.f};
    s8 aq = *(const s8*)&Q3[rw+l15][h*32+hi*8];
    #pragma unroll
    for (int t=0;t<8;t++){
      s8 bf = *(const s8*)(kh3 + ((size_t)(b*H_+h)*T_ + t*16+l15)*32 + hi*8);
      sa[t]=mfma16(aq,bf,sa[t]);
    }
    #pragma unroll
    for (int r=0;r<4;r++){
      const int row=rw+hi*4+r;
      float mx=-1e30f;
      float sv[8];
      #pragma unroll
      for (int t=0;t<8;t++){ sv[t]=sa[t][r]*scale; mx=fmaxf(mx,sv[t]); }
      mx=fmaxf(mx,__shfl_xor(mx,1)); mx=fmaxf(mx,__shfl_xor(mx,2));
      mx=fmaxf(mx,__shfl_xor(mx,4)); mx=fmaxf(mx,__shfl_xor(mx,8));
      float se=0.f; float pv[8];
      #pragma unroll
      for (int t=0;t<8;t++){ pv[t]=__expf(sv[t]-mx); se+=pv[t]; }
      se=rsum16(se);
      float inv=1.f/se;
      #pragma unroll
      for (int t=0;t<8;t++) P3[row][l15+16*t]=f2b(pv[t]*inv);
    }
    __syncthreads();
    #pragma unroll
    for (int kk=0;kk<4;kk++){
      s8 ap = *(const s8*)&P3[rw+l15][kk*32+hi*8];
      #pragma unroll
      for (int t2=0;t2<2;t2++){
        s8 bf = *(const s8*)(vh3T + ((size_t)(b*H_+h)*32 + t2*16+l15)*T_ + kk*32+hi*8);
        oacc[h*2+t2]=mfma16(ap,bf,oacc[h*2+t2]);
      }
    }
    __syncthreads();
  }
  #pragma unroll
  for (int t=0;t<8;t++){
    #pragma unroll
    for (int r=0;r<4;r++) Q3[rw+hi*4+r][l15+16*t]=f2b(oacc[t][r]);
  }
  __syncthreads();
  // wo3 GEMM col-split + residual + LN2 (cross-wave)
  f4 a2[4][2];
  #pragma unroll
  for (int m=0;m<4;m++)
    #pragma unroll
    for (int tl=0;tl<2;tl++){ float bb=bo3[colb+tl*16+l15]; a2[m][tl]=(f4){bb,bb,bb,bb}; }
  #pragma unroll
  for (int kk=0;kk<4;kk++){
    s8 bfr[2];
    #pragma unroll
    for (int tl=0;tl<2;tl++)
      bfr[tl] = *(const s8*)(wo3b + (size_t)(colb+tl*16+l15)*D_ + kk*32+hi*8);
    #pragma unroll
    for (int m=0;m<4;m++){
      s8 a = *(const s8*)&Q3[m*16+l15][kk*32+hi*8];
      #pragma unroll
      for (int tl=0;tl<2;tl++) a2[m][tl]=mfma16(a,bfr[tl],a2[m][tl]);
    }
  }
  #pragma unroll
  for (int m=0;m<4;m++)
    #pragma unroll
    for (int r=0;r<4;r++){
      const int row=m*16+hi*4+r;
      const int nr = min(n0+row, N_-1);
      const size_t gr=(size_t)b*N_+nr;
      float ps=0.f, pq=0.f;
      #pragma unroll
      for (int tl=0;tl<2;tl++){
        float tmp = b2f(V1[gr*D_ + colb+tl*16+l15]) + a2[m][tl][r];
        a2[m][tl][r]=tmp; ps+=tmp; pq+=tmp*tmp;
      }
      ps=rsum16(ps); pq=rsum16(pq);
      if (l15==0){ rsA[row][w]=ps; rsB[row][w]=pq; }
    }
  __syncthreads();
  float g2v[2],b2v[2];
  #pragma unroll
  for (int tl=0;tl<2;tl++){ g2v[tl]=l2g[colb+tl*16+l15]; b2v[tl]=l2b[colb+tl*16+l15]; }
  #pragma unroll
  for (int m=0;m<4;m++)
    #pragma unroll
    for (int r=0;r<4;r++){
      const int row=m*16+hi*4+r;
      float s  = rsA[row][0]+rsA[row][1]+rsA[row][2]+rsA[row][3];
      float s2 = rsB[row][0]+rsB[row][1]+rsB[row][2]+rsB[row][3];
      float mean=s*(1.f/128.f);
      float rstd=rsqrtf(s2*(1.f/128.f)-mean*mean+1e-5f);
      #pragma unroll
      for (int tl=0;tl<2;tl++){
        int col=colb+tl*16+l15;
        float tmp=a2[m][tl][r];
        P3[row][col]=f2b(tmp);
        Wt[row][col]=f2b((tmp-mean)*rstd*g2v[tl]+b2v[tl]);
      }
    }
  __syncthreads();
  if (n0+nl < N_){
    const size_t gd=(size_t)b*N_+n0+nl;
    #pragma unroll
    for (int j=0;j<4;j++){
      int u=part+4*j;
      *(uint4*)(V2 + gd*D_ + u*8) = *(const uint4*)&P3[nl][u*8];
      *(uint4*)(XLN + gd*D_ + u*8) = *(const uint4*)&Wt[nl][u*8];
    }
  }
}

// ---------------------------------------------------------------------------
// K6b: FFN col-split: V3(f32) = V2 + W2f(silu(W1f(x)))
// ---------------------------------------------------------------------------
__global__ __launch_bounds__(256,2) void k_ffn(
  const u16* __restrict__ XLN, const u16* __restrict__ V2,
  const u16* __restrict__ w1b, const float* __restrict__ b1,
  const u16* __restrict__ w2b, const float* __restrict__ b2,
  float* __restrict__ V3)
{
  __shared__ u16 Xs[64][136];
  __shared__ u16 Hs[64][136];
  const int tid=threadIdx.x, nl=tid>>2, part=tid&3;
  const size_t gn = (size_t)blockIdx.x*64 + nl;
  #pragma unroll
  for (int j=0;j<4;j++){ int u=part+4*j; *(uint4*)&Xs[nl][u*8] = *(const uint4*)(XLN + gn*D_ + u*8); }
  __syncthreads();
  const int lane=tid&63, w=tid>>6, l15=lane&15, hi=lane>>4, colb=w*32;
  f4 accf[4][2];
  #pragma unroll
  for (int m=0;m<4;m++)
    #pragma unroll
    for (int tl=0;tl<2;tl++){ float bb=b2[colb+tl*16+l15]; accf[m][tl]=(f4){bb,bb,bb,bb}; }
  for (int half=0;half<2;half++){
    f4 ah[4][2];
    #pragma unroll
    for (int m=0;m<4;m++)
      #pragma unroll
      for (int tl=0;tl<2;tl++){ float bb=b1[half*128+colb+tl*16+l15]; ah[m][tl]=(f4){bb,bb,bb,bb}; }
    #pragma unroll
    for (int kk=0;kk<4;kk++){
      s8 bfr[2];
      #pragma unroll
      for (int tl=0;tl<2;tl++)
        bfr[tl] = *(const s8*)(w1b + (size_t)(half*128+colb+tl*16+l15)*D_ + kk*32+hi*8);
      #pragma unroll
      for (int m=0;m<4;m++){
        s8 a = *(const s8*)&Xs[m*16+l15][kk*32+hi*8];
        #pragma unroll
        for (int tl=0;tl<2;tl++) ah[m][tl]=mfma16(a,bfr[tl],ah[m][tl]);
      }
    }
    __syncthreads();   // prev-half Hs reads done before overwrite
    #pragma unroll
    for (int m=0;m<4;m++)
      #pragma unroll
      for (int tl=0;tl<2;tl++)
        #pragma unroll
        for (int r=0;r<4;r++)
          Hs[m*16+hi*4+r][colb+tl*16+l15]=f2b(silu_f(ah[m][tl][r]));
    __syncthreads();
    #pragma unroll
    for (int kk=0;kk<4;kk++){
      s8 bfr[2];
      #pragma unroll
      for (int tl=0;tl<2;tl++)
        bfr[tl] = *(const s8*)(w2b + (size_t)(colb+tl*16+l15)*256 + half*128 + kk*32+hi*8);
      #pragma unroll
      for (int m=0;m<4;m++){
        s8 a = *(const s8*)&Hs[m*16+l15][kk*32+hi*8];
        #pragma unroll
        for (int tl=0;tl<2;tl++) accf[m][tl]=mfma16(a,bfr[tl],accf[m][tl]);
      }
    }
  }
  #pragma unroll
  for (int m=0;m<4;m++)
    #pragma unroll
    for (int r=0;r<4;r++){
      const int row=m*16+hi*4+r;
      const size_t gr=(size_t)blockIdx.x*64+row;
      #pragma unroll
      for (int tl=0;tl<2;tl++){
        int col=colb+tl*16+l15;
        V3[gr*D_+col] = b2f(V2[gr*D_+col]) + accf[m][tl][r];
      }
    }
}

// ---------------------------------------------------------------------------
extern "C" void kernel_launch(void* const* d_in, const int* in_sizes, int n_in,
                              void* d_out, int out_size, void* d_ws, size_t ws_size,
                              hipStream_t stream)
{
  const float* V     = (const float*)d_in[0];
  const float* E     = (const float*)d_in[1];
  const int* edges   = (const int*)d_in[2];
  const float* senc  = (const float*)d_in[3];
  const float* fe_w1=(const float*)d_in[4];  const float* fe_b1=(const float*)d_in[5];
  const float* fe_w2=(const float*)d_in[6];  const float* fe_b2=(const float*)d_in[7];
  const float* fe_g =(const float*)d_in[8];  const float* fe_be=(const float*)d_in[9];
  const float* fn_w1=(const float*)d_in[10]; const float* fn_b1=(const float*)d_in[11];
  const float* fn_w2=(const float*)d_in[12]; const float* fn_b2=(const float*)d_in[13];
  const float* fn_g =(const float*)d_in[14]; const float* fn_be=(const float*)d_in[15];
  const float* ln1_g=(const float*)d_in[16]; const float* ln1_b=(const float*)d_in[17];
  const float* ln2_g=(const float*)d_in[18]; const float* ln2_b=(const float*)d_in[19];
  const float* Q    =(const float*)d_in[20];
  const float* a1_wqkv=(const float*)d_in[21]; const float* a1_bqkv=(const float*)d_in[22];
  const float* a1_wo=(const float*)d_in[23];   const float* a1_bo=(const float*)d_in[24];
  const float* a2_wqkv=(const float*)d_in[25]; const float* a2_bqkv=(const float*)d_in[26];
  const float* a2_wo=(const float*)d_in[27];   const float* a2_bo=(const float*)d_in[28];
  const float* a3_wqkv=(const float*)d_in[29]; const float* a3_bqkv=(const float*)d_in[30];
  const float* a3_wo=(const float*)d_in[31];   const float* a3_bo=(const float*)d_in[32];
  const float* ffn_w1=(const float*)d_in[33];  const float* ffn_b1=(const float*)d_in[34];
  const float* ffn_w2=(const float*)d_in[35];  const float* ffn_b2=(const float*)d_in[36];

  char* ws = (char*)d_ws;
  size_t off = 0;
  auto alloc = [&](size_t bytes)->void*{ void* p = ws + off; off += (bytes + 255) & ~(size_t)255; return p; };
  float* m0s = (float*)alloc((size_t)B_*N_*64*4);
  float* m1s = (float*)alloc((size_t)B_*N_*64*4);
  float* c0s = (float*)alloc((size_t)B_*N_*4);
  float* c1s = (float*)alloc((size_t)B_*N_*4);
  const size_t zero_bytes = off;          // only the atomic accumulators need zeroing
  u16* wcat = (u16*)alloc((size_t)WTOT*2);
  u16* V1  = (u16*)alloc((size_t)B_*N_*D_*2);
  u16* W0  = (u16*)alloc((size_t)B_*N_*D_*2);
  u16* kh1 = (u16*)alloc((size_t)B_*H_*N_*32*2);
  u16* vh1 = (u16*)alloc((size_t)B_*H_*N_*32*2);
  u16* qh1 = (u16*)alloc((size_t)H_*T_*32*2);
  float* o1 = (float*)alloc((size_t)B_*T_*D_*4);
  u16* qh2 = (u16*)alloc((size_t)B_*H_*T_*32*2);
  u16* kh2 = (u16*)alloc((size_t)B_*H_*T_*32*2);
  u16* vh2 = (u16*)alloc((size_t)B_*H_*T_*32*2);
  float* o2 = (float*)alloc((size_t)B_*T_*D_*4);
  u16* kh3 = (u16*)alloc((size_t)B_*H_*T_*32*2);
  u16* vh3T= (u16*)alloc((size_t)B_*H_*32*T_*2);
  u16* V2  = (u16*)alloc((size_t)B_*N_*D_*2);
  u16* XLN = (u16*)alloc((size_t)B_*N_*D_*2);
  if (ws_size < off) return;

  u16* w_fe1 = wcat + WO_FE1;
  u16* w_fe2 = wcat + WO_FE2;
  u16* w_fn1 = wcat + WO_FN1;
  u16* w_fn2 = wcat + WO_FN2;
  u16* w_a1  = wcat + WO_A1;
  u16* w_a3  = wcat + WO_A3;
  u16* w_a3o = wcat + WO_A3O;
  u16* w_ff1 = wcat + WO_FF1;
  u16* w_ff2 = wcat + WO_FF2;

  float* outp = (float*)d_out;
  float* V3out = outp;
  float* Eout  = outp + (size_t)B_*N_*D_;

  hipMemsetAsync(d_ws, 0, zero_bytes, stream);
  k_cvtw<<<(WTOT/8+255)/256,256,0,stream>>>(fe_w1,fe_w2,fn_w1,fn_w2,a1_wqkv,a3_wqkv,a3_wo,
                                            ffn_w1,ffn_w2, wcat);
  k_edge<<<(B_*NE_)/64,256,0,stream>>>(V,E,edges,senc, w_fe1,fe_b1, w_fe2,fe_b2, fe_g,fe_be,
                                       m0s,m1s,c0s,c1s, Eout);
  k_node<<<(B_*N_)/64,256,0,stream>>>(V,senc,m0s,m1s,c0s,c1s, w_fn1,fn_b1, w_fn2,fn_b2,
                                      fn_g,fn_be, ln1_g,ln1_b, V1,W0);
  k_qh1<<<T_/64,256,0,stream>>>(Q, a1_wqkv, a1_bqkv, qh1);
  k_kv1<<<(B_*N_)/64,256,0,stream>>>(W0, w_a1, a1_bqkv, kh1, vh1);
  k_mha1<<<(B_*H_*T_)/4,256,0,stream>>>(qh1,kh1,vh1,o1);
  k_att12<<<(B_*T_)/64,256,0,stream>>>(o1, a1_wo, a1_bo, a2_wqkv, a2_bqkv, qh2,kh2,vh2);
  k_mha2<<<(B_*H_*T_)/4,256,0,stream>>>(qh2,kh2,vh2,o2);
  k_att23<<<(B_*T_)/64,256,0,stream>>>(o2, a2_wo, a2_bo, a3_wqkv, a3_bqkv, kh3, vh3T);
  k_mha3<<<B_*157,256,0,stream>>>(W0,V1, w_a3,a3_bqkv, kh3,vh3T, w_a3o,a3_bo,
                                  ln2_g,ln2_b, V2,XLN);
  k_ffn<<<(B_*N_)/64,256,0,stream>>>(XLN,V2, w_ff1,ffn_b1, w_ff2,ffn_b2, V3out);
}

// Round 6
// 627.351 us; speedup vs baseline: 2.4125x; 1.2603x over previous
//
#include <hip/hip_runtime.h>
#include <hip/hip_bf16.h>

#define B_ 4
#define N_ 10000
#define NE_ 100000
#define D_ 128
#define S_ 64
#define H_ 4
#define T_ 128

typedef unsigned short u16;
typedef unsigned int u32;
typedef __attribute__((ext_vector_type(4))) float f4;
typedef __attribute__((ext_vector_type(8))) short s8;

#define DEVI static __device__ __forceinline__

DEVI float b2f(u16 u){ union{u32 i; float f;} v; v.i=((u32)u)<<16; return v.f; }
DEVI u16 f2b(float f){ union{float ff; u32 i;} v; v.ff=f; u32 i=v.i; return (u16)((i+0x7fffu+((i>>16)&1u))>>16); }
DEVI f4 mfma16(s8 a, s8 b, f4 c){ return __builtin_amdgcn_mfma_f32_16x16x32_bf16(a,b,c,0,0,0); }
DEVI float rsum16(float x){ x+=__shfl_xor(x,1); x+=__shfl_xor(x,2); x+=__shfl_xor(x,4); x+=__shfl_xor(x,8); return x; }
DEVI float silu_f(float v){ return v/(1.f+__expf(-v)); }
DEVI float nn(float v, float s){ return (v==v)? v : s; }
DEVI float lo2f(u32 u){ union{u32 i; float f;} v; v.i=u<<16; return v.f; }
DEVI float hi2f(u32 u){ union{u32 i; float f;} v; v.i=u&0xffff0000u; return v.f; }

DEVI s8 ldw8f(const float* p){
  f4 a = *(const f4*)p;
  f4 c = *(const f4*)(p+4);
  union { u16 t[8]; s8 v; } u;
  #pragma unroll
  for (int i=0;i<4;i++){ u.t[i]=f2b(a[i]); u.t[4+i]=f2b(c[i]); }
  return u.v;
}
DEVI uint4 cvt8(const float* p){
  f4 a = *(const f4*)p;
  f4 c = *(const f4*)(p+4);
  union { u16 t[8]; uint4 v; } u;
  #pragma unroll
  for (int i=0;i<4;i++){ u.t[i]=f2b(a[i]); u.t[4+i]=f2b(c[i]); }
  return u.v;
}
// non-temporal variant: for streaming reads that must not evict L2-resident
// atomic accumulators / weights
DEVI uint4 cvt8nt(const float* p){
  f4 a = __builtin_nontemporal_load((const f4*)p);
  f4 c = __builtin_nontemporal_load((const f4*)(p+4));
  union { u16 t[8]; uint4 v; } u;
  #pragma unroll
  for (int i=0;i<4;i++){ u.t[i]=f2b(a[i]); u.t[4+i]=f2b(c[i]); }
  return u.v;
}

// ---------------------------------------------------------------------------
// weight preconversion f32 -> bf16, 9 segments concatenated in ws
// ---------------------------------------------------------------------------
#define WO_FE1 0
#define WO_FE2 65536
#define WO_FN1 81920
#define WO_FN2 122880
#define WO_A1  139264
#define WO_A3  188416
#define WO_A3O 237568
#define WO_FF1 253952
#define WO_FF2 286720
#define WTOT   319488

__global__ __launch_bounds__(256) void k_cvtw(
  const float* __restrict__ s0, const float* __restrict__ s1,
  const float* __restrict__ s2, const float* __restrict__ s3,
  const float* __restrict__ s4, const float* __restrict__ s5,
  const float* __restrict__ s6, const float* __restrict__ s7,
  const float* __restrict__ s8v, u16* __restrict__ dst)
{
  int i = (blockIdx.x*256 + threadIdx.x)*8;
  if (i >= WTOT) return;
  const float* src; int off;
  if      (i < WO_FE2){ src=s0;  off=WO_FE1; }
  else if (i < WO_FN1){ src=s1;  off=WO_FE2; }
  else if (i < WO_FN2){ src=s2;  off=WO_FN1; }
  else if (i < WO_A1 ){ src=s3;  off=WO_FN2; }
  else if (i < WO_A3 ){ src=s4;  off=WO_A1;  }
  else if (i < WO_A3O){ src=s5;  off=WO_A3;  }
  else if (i < WO_FF1){ src=s6;  off=WO_A3O; }
  else if (i < WO_FF2){ src=s7;  off=WO_FF1; }
  else                { src=s8v; off=WO_FF2; }
  *(uint4*)(dst+i) = cvt8(src + (i-off));
}

// ---------------------------------------------------------------------------
// K1: edge MLP, col-split. E staged once (nt), reused from LDS for Eout (nt).
// ---------------------------------------------------------------------------
__global__ __launch_bounds__(256,2) void k_edge(
  const float* __restrict__ V, const float* __restrict__ E, const int* __restrict__ edges,
  const float* __restrict__ senc,
  const u16* __restrict__ w1b, const float* __restrict__ b1,
  const u16* __restrict__ w2b, const float* __restrict__ b2,
  const float* __restrict__ lng, const float* __restrict__ lnb,
  float* __restrict__ m0s, float* __restrict__ m1s,
  float* __restrict__ c0s, float* __restrict__ c1s,
  float* __restrict__ Eout)
{
  __shared__ u16 X[64][520];
  __shared__ int gi0[64], gi1[64];
  __shared__ float fvalid[64];
  __shared__ float rsA[64][4], rsB[64][4];
  const int tid = threadIdx.x;
  const int el = tid>>2, part = tid&3;
  const int ge = blockIdx.x*64 + el;
  const int b = ge / NE_;
  const int2 ed = *(const int2*)(edges + (size_t)ge*2);
  const int i0 = min(max(ed.x,0),N_-1), i1 = min(max(ed.y,0),N_-1);
  if (part==0){
    gi0[el] = b*N_ + i0; gi1[el] = b*N_ + i1;
    fvalid[el] = (ed.x>=0 && ed.y>=0) ? 1.f : 0.f;
  }
  {
    const float* Vb = V + (size_t)b*N_*D_;
    const float* Sb = senc + (size_t)b*N_*S_;
    const float* Ep = E + (size_t)ge*D_;
    #pragma unroll
    for (int j=0;j<16;j++){
      int u = part + 4*j;
      if (u<48){
        const float* p;
        if (u<16)      p = Vb + (size_t)i0*D_ + u*8;
        else if (u<24) p = Sb + (size_t)i0*S_ + (u-16)*8;
        else if (u<40) p = Vb + (size_t)i1*D_ + (u-24)*8;
        else           p = Sb + (size_t)i1*S_ + (u-40)*8;
        *(uint4*)&X[el][u*8] = cvt8(p);
      } else {
        *(uint4*)&X[el][u*8] = cvt8nt(Ep + (u-48)*8);   // E: stream, don't cache
      }
    }
  }
  __syncthreads();
  if (tid < 64){
    atomicAdd(&c0s[gi0[tid]], 1.f);
    atomicAdd(&c1s[gi1[tid]], 1.f);
  }
  const int lane = tid&63, w = tid>>6;
  const int l15 = lane&15, hi = lane>>4;
  const int colb = w*32;
  // stage 1: H = silu(X @ w1^T + b1)
  f4 acc[4][2];
  #pragma unroll
  for (int m=0;m<4;m++)
    #pragma unroll
    for (int tl=0;tl<2;tl++){ float bb=b1[colb+tl*16+l15]; acc[m][tl]=(f4){bb,bb,bb,bb}; }
  for (int kk=0;kk<16;kk++){
    s8 bfr[2];
    #pragma unroll
    for (int tl=0;tl<2;tl++)
      bfr[tl] = *(const s8*)(w1b + (size_t)(colb+tl*16+l15)*512 + kk*32 + hi*8);
    #pragma unroll
    for (int m=0;m<4;m++){
      s8 a = *(const s8*)&X[m*16+l15][kk*32 + hi*8];
      #pragma unroll
      for (int tl=0;tl<2;tl++) acc[m][tl] = mfma16(a, bfr[tl], acc[m][tl]);
    }
  }
  __syncthreads();
  #pragma unroll
  for (int m=0;m<4;m++)
    #pragma unroll
    for (int tl=0;tl<2;tl++)
      #pragma unroll
      for (int r=0;r<4;r++)
        X[m*16+hi*4+r][colb+tl*16+l15] = f2b(silu_f(acc[m][tl][r]));
  __syncthreads();
  // stage 2: Y = H @ w2^T + b2
  f4 a2[4][2];
  #pragma unroll
  for (int m=0;m<4;m++)
    #pragma unroll
    for (int tl=0;tl<2;tl++){ float bb=b2[colb+tl*16+l15]; a2[m][tl]=(f4){bb,bb,bb,bb}; }
  #pragma unroll
  for (int kk=0;kk<4;kk++){
    s8 bfr[2];
    #pragma unroll
    for (int tl=0;tl<2;tl++)
      bfr[tl] = *(const s8*)(w2b + (size_t)(colb+tl*16+l15)*128 + kk*32 + hi*8);
    #pragma unroll
    for (int m=0;m<4;m++){
      s8 a = *(const s8*)&X[m*16+l15][kk*32 + hi*8];
      #pragma unroll
      for (int tl=0;tl<2;tl++) a2[m][tl] = mfma16(a, bfr[tl], a2[m][tl]);
    }
  }
  // cross-wave LN row reduction
  #pragma unroll
  for (int m=0;m<4;m++)
    #pragma unroll
    for (int r=0;r<4;r++){
      float ps=0.f, pq=0.f;
      #pragma unroll
      for (int tl=0;tl<2;tl++){ float v=a2[m][tl][r]; ps+=v; pq+=v*v; }
      ps=rsum16(ps); pq=rsum16(pq);
      if (l15==0){ int row=m*16+hi*4+r; rsA[row][w]=ps; rsB[row][w]=pq; }
    }
  __syncthreads();
  float gv[2], bev[2];
  #pragma unroll
  for (int tl=0;tl<2;tl++){ gv[tl]=lng[colb+tl*16+l15]; bev[tl]=lnb[colb+tl*16+l15]; }
  const int ge0 = blockIdx.x*64;
  #pragma unroll
  for (int m=0;m<4;m++)
    #pragma unroll
    for (int r=0;r<4;r++){
      const int row = m*16+hi*4+r;
      float s  = rsA[row][0]+rsA[row][1]+rsA[row][2]+rsA[row][3];
      float s2 = rsB[row][0]+rsB[row][1]+rsB[row][2]+rsB[row][3];
      const float mean = s*(1.f/128.f);
      const float rstd = rsqrtf(s2*(1.f/128.f) - mean*mean + 1e-5f);
      const float vm = fvalid[row];
      const int g0 = gi0[row], g1 = gi1[row];
      #pragma unroll
      for (int tl=0;tl<2;tl++){
        const int col = colb+tl*16+l15;
        float ev = ((a2[m][tl][r]-mean)*rstd*gv[tl] + bev[tl]) * vm;
        ev = nn(ev, 7e3f);
        if (col < 64) atomicAdd(m0s + (size_t)g0*64 + col, ev);
        else          atomicAdd(m1s + (size_t)g1*64 + (col-64), ev);
        // E is still live in LDS cols 384..511 (stages 1-2 only touched 0..127)
        float ef = b2f(X[row][384+col]);
        __builtin_nontemporal_store(ef + ev, Eout + (size_t)(ge0+row)*D_ + col);
      }
    }
}

// ---------------------------------------------------------------------------
// K2: node MLP + V1 = V+v_emb + W0 = LN(V1), col-split
// ---------------------------------------------------------------------------
__global__ __launch_bounds__(256,2) void k_node(
  const float* __restrict__ V, const float* __restrict__ senc,
  const float* __restrict__ m0s, const float* __restrict__ m1s,
  const float* __restrict__ c0s, const float* __restrict__ c1s,
  const u16* __restrict__ w1b, const float* __restrict__ b1,
  const u16* __restrict__ w2b, const float* __restrict__ b2,
  const float* __restrict__ lng, const float* __restrict__ lnb,
  const float* __restrict__ l1g, const float* __restrict__ l1b,
  u16* __restrict__ V1, u16* __restrict__ W0)
{
  __shared__ u16 X[64][328];
  __shared__ float rsA[64][4], rsB[64][4];
  const int tid=threadIdx.x, nl=tid>>2, part=tid&3;
  const int gn = blockIdx.x*64 + nl;
  const int b = gn / N_, n = gn - b*N_;
  {
    const float* Vp = V + ((size_t)b*N_ + n)*D_;
    const float* Sp = senc + ((size_t)b*N_ + n)*S_;
    #pragma unroll
    for (int j=0;j<6;j++){
      int u = part + 4*j;
      const float* p = (u<16)? Vp + u*8 : Sp + (u-16)*8;
      *(uint4*)&X[nl][u*8] = cvt8(p);
    }
    const float rc0 = 1.f/fmaxf(c0s[gn],1.f), rc1 = 1.f/fmaxf(c1s[gn],1.f);
    #pragma unroll
    for (int j=0;j<8;j++){
      int c = part*32 + j*4;
      const float* src = (c<64)? m0s + (size_t)gn*64 + c : m1s + (size_t)gn*64 + (c-64);
      float rr = (c<64)? rc0 : rc1;
      f4 mv = *(const f4*)src;
      u16 ov[4];
      #pragma unroll
      for (int i=0;i<4;i++) ov[i]=f2b(mv[i]*rr);
      uint2 pk; __builtin_memcpy(&pk, ov, 8);
      *(uint2*)&X[nl][192+c] = pk;
    }
  }
  __syncthreads();
  const int lane=tid&63, w=tid>>6, l15=lane&15, hi=lane>>4, colb=w*32;
  f4 acc[4][2];
  #pragma unroll
  for (int m=0;m<4;m++)
    #pragma unroll
    for (int tl=0;tl<2;tl++){ float bb=b1[colb+tl*16+l15]; acc[m][tl]=(f4){bb,bb,bb,bb}; }
  for (int kk=0;kk<10;kk++){
    s8 bfr[2];
    #pragma unroll
    for (int tl=0;tl<2;tl++)
      bfr[tl] = *(const s8*)(w1b + (size_t)(colb+tl*16+l15)*320 + kk*32 + hi*8);
    #pragma unroll
    for (int m=0;m<4;m++){
      s8 a = *(const s8*)&X[m*16+l15][kk*32+hi*8];
      #pragma unroll
      for (int tl=0;tl<2;tl++) acc[m][tl]=mfma16(a,bfr[tl],acc[m][tl]);
    }
  }
  __syncthreads();
  #pragma unroll
  for (int m=0;m<4;m++)
    #pragma unroll
    for (int tl=0;tl<2;tl++)
      #pragma unroll
      for (int r=0;r<4;r++)
        X[m*16+hi*4+r][192+colb+tl*16+l15] = f2b(silu_f(acc[m][tl][r]));
  __syncthreads();
  f4 a2[4][2];
  #pragma unroll
  for (int m=0;m<4;m++)
    #pragma unroll
    for (int tl=0;tl<2;tl++){ float bb=b2[colb+tl*16+l15]; a2[m][tl]=(f4){bb,bb,bb,bb}; }
  #pragma unroll
  for (int kk=0;kk<4;kk++){
    s8 bfr[2];
    #pragma unroll
    for (int tl=0;tl<2;tl++)
      bfr[tl] = *(const s8*)(w2b + (size_t)(colb+tl*16+l15)*128 + kk*32 + hi*8);
    #pragma unroll
    for (int m=0;m<4;m++){
      s8 a = *(const s8*)&X[m*16+l15][192 + kk*32+hi*8];
      #pragma unroll
      for (int tl=0;tl<2;tl++) a2[m][tl]=mfma16(a,bfr[tl],a2[m][tl]);
    }
  }
  #pragma unroll
  for (int m=0;m<4;m++)
    #pragma unroll
    for (int r=0;r<4;r++){
      float ps=0.f, pq=0.f;
      #pragma unroll
      for (int tl=0;tl<2;tl++){ float v=a2[m][tl][r]; ps+=v; pq+=v*v; }
      ps=rsum16(ps); pq=rsum16(pq);
      if (l15==0){ int row=m*16+hi*4+r; rsA[row][w]=ps; rsB[row][w]=pq; }
    }
  __syncthreads();
  float gv[2],bev[2],g1v[2],b1v[2];
  #pragma unroll
  for (int tl=0;tl<2;tl++){
    int col=colb+tl*16+l15;
    gv[tl]=lng[col]; bev[tl]=lnb[col]; g1v[tl]=l1g[col]; b1v[tl]=l1b[col];
  }
  #pragma unroll
  for (int m=0;m<4;m++)
    #pragma unroll
    for (int r=0;r<4;r++){
      const int row=m*16+hi*4+r;
      float s  = rsA[row][0]+rsA[row][1]+rsA[row][2]+rsA[row][3];
      float s2 = rsB[row][0]+rsB[row][1]+rsB[row][2]+rsB[row][3];
      float mean=s*(1.f/128.f);
      float rstd=rsqrtf(s2*(1.f/128.f)-mean*mean+1e-5f);
      #pragma unroll
      for (int tl=0;tl<2;tl++){
        float ve=(a2[m][tl][r]-mean)*rstd*gv[tl]+bev[tl];
        a2[m][tl][r] = b2f(X[row][colb+tl*16+l15]) + ve;
      }
    }
  __syncthreads();
  #pragma unroll
  for (int m=0;m<4;m++)
    #pragma unroll
    for (int r=0;r<4;r++){
      float ps=0.f, pq=0.f;
      #pragma unroll
      for (int tl=0;tl<2;tl++){ float v=a2[m][tl][r]; ps+=v; pq+=v*v; }
      ps=rsum16(ps); pq=rsum16(pq);
      if (l15==0){ int row=m*16+hi*4+r; rsA[row][w]=ps; rsB[row][w]=pq; }
    }
  __syncthreads();
  #pragma unroll
  for (int m=0;m<4;m++)
    #pragma unroll
    for (int r=0;r<4;r++){
      const int row=m*16+hi*4+r;
      float sv  = rsA[row][0]+rsA[row][1]+rsA[row][2]+rsA[row][3];
      float sv2 = rsB[row][0]+rsB[row][1]+rsB[row][2]+rsB[row][3];
      float m2=sv*(1.f/128.f);
      float rs2=rsqrtf(sv2*(1.f/128.f)-m2*m2+1e-5f);
      #pragma unroll
      for (int tl=0;tl<2;tl++){
        int col=colb+tl*16+l15;
        float tmp=a2[m][tl][r];
        X[row][col]     = f2b(tmp);
        X[row][192+col] = f2b((tmp-m2)*rs2*g1v[tl]+b1v[tl]);
      }
    }
  __syncthreads();
  #pragma unroll
  for (int j=0;j<4;j++){
    int u=part+4*j;
    *(uint4*)(V1 + (size_t)gn*D_ + u*8) = *(const uint4*)&X[nl][u*8];
    *(uint4*)(W0 + (size_t)gn*D_ + u*8) = *(const uint4*)&X[nl][192 + u*8];
  }
}

// ---------------------------------------------------------------------------
// K3q: qh1 = Q@wq1^T+bq1
// ---------------------------------------------------------------------------
__global__ __launch_bounds__(256) void k_qh1(
  const float* __restrict__ Q, const float* __restrict__ wqkv, const float* __restrict__ bqkv,
  u16* __restrict__ qh1)
{
  __shared__ u16 X[64][136];
  const int tid=threadIdx.x, nl=tid>>2, part=tid&3;
  const int q = blockIdx.x*64 + nl;
  #pragma unroll
  for (int j=0;j<4;j++){ int u=part+4*j; *(uint4*)&X[nl][u*8] = cvt8(Q + (size_t)q*D_ + u*8); }
  __syncthreads();
  const int lane=tid&63, w=tid>>6, l15=lane&15, hi=lane>>4, rw=w*16;
  f4 acc[8];
  #pragma unroll
  for (int t=0;t<8;t++){ float bb=bqkv[l15+16*t]; acc[t]=(f4){bb,bb,bb,bb}; }
  #pragma unroll
  for (int kk=0;kk<4;kk++){
    s8 a = *(const s8*)&X[rw+l15][kk*32+hi*8];
    #pragma unroll
    for (int t=0;t<8;t++){
      s8 bf = ldw8f(wqkv + (size_t)(t*16+l15)*D_ + kk*32+hi*8);
      acc[t]=mfma16(a,bf,acc[t]);
    }
  }
  __syncthreads();
  #pragma unroll
  for (int t=0;t<8;t++){
    #pragma unroll
    for (int r=0;r<4;r++) X[rw+hi*4+r][l15+16*t]=f2b(acc[t][r]);
  }
  __syncthreads();
  #pragma unroll
  for (int j=0;j<4;j++){
    int u=part+4*j, col0=u*8, h=col0>>5, d=col0&31;
    *(uint4*)(qh1 + ((size_t)h*T_ + q)*32 + d) = *(const uint4*)&X[nl][col0];
  }
}

// ---------------------------------------------------------------------------
// K3: kh1/vh1 = W0 @ [wk1;wv1]^T, col-split
// ---------------------------------------------------------------------------
__global__ __launch_bounds__(256,2) void k_kv1(
  const u16* __restrict__ W0, const u16* __restrict__ wqkvb, const float* __restrict__ bqkv,
  u16* __restrict__ kh1, u16* __restrict__ vh1)
{
  __shared__ u16 X[64][264];
  const int tid=threadIdx.x, nl=tid>>2, part=tid&3;
  const int gn = blockIdx.x*64 + nl;
  const int b = gn / N_, n = gn - b*N_;
  #pragma unroll
  for (int j=0;j<4;j++){ int u=part+4*j; *(uint4*)&X[nl][u*8] = *(const uint4*)(W0 + (size_t)gn*D_ + u*8); }
  __syncthreads();
  const int lane=tid&63, w=tid>>6, l15=lane&15, hi=lane>>4;
  const int colb = w*64;
  f4 acc[4][4];
  #pragma unroll
  for (int m=0;m<4;m++)
    #pragma unroll
    for (int tl=0;tl<4;tl++){ float bb=bqkv[128 + colb+tl*16+l15]; acc[m][tl]=(f4){bb,bb,bb,bb}; }
  #pragma unroll
  for (int kk=0;kk<4;kk++){
    s8 bfr[4];
    #pragma unroll
    for (int tl=0;tl<4;tl++)
      bfr[tl] = *(const s8*)(wqkvb + (size_t)(128 + colb+tl*16+l15)*D_ + kk*32+hi*8);
    #pragma unroll
    for (int m=0;m<4;m++){
      s8 a = *(const s8*)&X[m*16+l15][kk*32+hi*8];
      #pragma unroll
      for (int tl=0;tl<4;tl++) acc[m][tl]=mfma16(a,bfr[tl],acc[m][tl]);
    }
  }
  __syncthreads();
  #pragma unroll
  for (int m=0;m<4;m++)
    #pragma unroll
    for (int tl=0;tl<4;tl++)
      #pragma unroll
      for (int r=0;r<4;r++)
        X[m*16+hi*4+r][colb+tl*16+l15]=f2b(acc[m][tl][r]);
  __syncthreads();
  #pragma unroll
  for (int j=0;j<8;j++){
    int u=part+4*j, col0=u*8;
    u16* dst;
    if (col0<128){ int h=col0>>5, d=col0&31; dst = kh1 + ((size_t)(b*H_+h)*N_ + n)*32 + d; }
    else { int c2=col0-128; int h=c2>>5, d=c2&31; dst = vh1 + ((size_t)(b*H_+h)*N_ + n)*32 + d; }
    *(uint4*)dst = *(const uint4*)&X[nl][col0];
  }
}

// ---------------------------------------------------------------------------
// K4: mha1 MFMA flash-decode. Partials per (bh, key-chunk), then combine.
// ---------------------------------------------------------------------------
#define NCH 20
#define CHK 512

__global__ __launch_bounds__(256,2) void k_mha1p(
  const u16* __restrict__ qh1, const u16* __restrict__ kh1, const u16* __restrict__ vh1,
  float* __restrict__ pm, float* __restrict__ pl, float* __restrict__ po)
{
  __shared__ u16 VT[32][72];     // V^T for current 64-key tile (row stride 144B, 16B aligned)
  __shared__ u16 P[4][32][72];   // per-wave P tiles
  const int bh = blockIdx.x / NCH, ch = blockIdx.x - bh*NCH;
  const int tid = threadIdx.x, w = tid>>6, lane = tid&63, l15=lane&15, hi=lane>>4;
  const int h = bh & 3;
  const int k0 = ch*CHK;
  const int nk = min(CHK, N_ - k0);
  const u16* Kb = kh1 + ((size_t)bh*N_ + k0)*32;
  const u16* Vb = vh1 + ((size_t)bh*N_ + k0)*32;
  s8 aq[2];
  #pragma unroll
  for (int qt=0;qt<2;qt++)
    aq[qt] = *(const s8*)(qh1 + ((size_t)h*T_ + w*32 + qt*16 + l15)*32 + hi*8);
  const float scale = 0.17677669529663687f;
  float m_reg[2][4], l_reg[2][4];
  f4 acc[2][2];
  #pragma unroll
  for (int qt=0;qt<2;qt++){
    #pragma unroll
    for (int r=0;r<4;r++){ m_reg[qt][r]=-1e30f; l_reg[qt][r]=0.f; }
    #pragma unroll
    for (int dt=0;dt<2;dt++) acc[qt][dt]=(f4){0.f,0.f,0.f,0.f};
  }
  const int ntile = (nk+63)>>6;
  for (int kt=0; kt<ntile; kt++){
    {
      int key = tid>>2, dseg = tid&3;
      int kg = kt*64 + key;
      uint4 v = (kg<nk)? *(const uint4*)(Vb + (size_t)kg*32 + dseg*8) : (uint4){0,0,0,0};
      const u16* vv = (const u16*)&v;
      #pragma unroll
      for (int i=0;i<8;i++) VT[dseg*8+i][key] = vv[i];
    }
    __syncthreads();
    // S = Q K^T (A=Q rows, B=K rows-as-cols)
    f4 sa[2][4];
    #pragma unroll
    for (int kt4=0;kt4<4;kt4++){
      int key = kt*64 + kt4*16 + l15;
      int keyc = min(key, nk-1);
      s8 bk = *(const s8*)(Kb + (size_t)keyc*32 + hi*8);
      #pragma unroll
      for (int qt=0;qt<2;qt++)
        sa[qt][kt4] = mfma16(aq[qt], bk, (f4){0.f,0.f,0.f,0.f});
    }
    // online softmax (row = qt*16 + hi*4 + r, col = key)
    #pragma unroll
    for (int qt=0;qt<2;qt++){
      #pragma unroll
      for (int r=0;r<4;r++){
        float s[4];
        float mx = -1e30f;
        #pragma unroll
        for (int kt4=0;kt4<4;kt4++){
          int key = kt*64 + kt4*16 + l15;
          s[kt4] = (key<nk)? sa[qt][kt4][r]*scale : -1e30f;
          mx = fmaxf(mx, s[kt4]);
        }
        mx=fmaxf(mx,__shfl_xor(mx,1)); mx=fmaxf(mx,__shfl_xor(mx,2));
        mx=fmaxf(mx,__shfl_xor(mx,4)); mx=fmaxf(mx,__shfl_xor(mx,8));
        float mn = fmaxf(m_reg[qt][r], mx);
        float corr = __expf(m_reg[qt][r]-mn);
        float ps=0.f;
        #pragma unroll
        for (int kt4=0;kt4<4;kt4++){
          float p = __expf(s[kt4]-mn);
          ps += p;
          P[w][qt*16+hi*4+r][kt4*16+l15] = f2b(p);
        }
        ps = rsum16(ps);
        l_reg[qt][r] = l_reg[qt][r]*corr + ps;
        m_reg[qt][r] = mn;
        #pragma unroll
        for (int dt=0;dt<2;dt++) acc[qt][dt][r] *= corr;
      }
    }
    __syncthreads();
    // O += P @ V  (A=P rows=q, B=V^T cols=dim)
    #pragma unroll
    for (int ks=0;ks<2;ks++){
      s8 bv[2];
      #pragma unroll
      for (int dt=0;dt<2;dt++)
        bv[dt] = *(const s8*)&VT[dt*16+l15][ks*32+hi*8];
      #pragma unroll
      for (int qt=0;qt<2;qt++){
        s8 pa = *(const s8*)&P[w][qt*16+l15][ks*32+hi*8];
        #pragma unroll
        for (int dt=0;dt<2;dt++)
          acc[qt][dt]=mfma16(pa,bv[dt],acc[qt][dt]);
      }
    }
    __syncthreads();
  }
  const size_t pbase = ((size_t)bh*NCH + ch)*128;
  #pragma unroll
  for (int qt=0;qt<2;qt++)
    #pragma unroll
    for (int r=0;r<4;r++){
      int row = w*32 + qt*16 + hi*4 + r;
      if (l15==0){ pm[pbase+row]=m_reg[qt][r]; pl[pbase+row]=l_reg[qt][r]; }
      #pragma unroll
      for (int dt=0;dt<2;dt++)
        po[(pbase+row)*32 + dt*16 + l15] = acc[qt][dt][r];
    }
}

__global__ __launch_bounds__(256) void k_mha1c(
  const float* __restrict__ pm, const float* __restrict__ pl, const float* __restrict__ po,
  float* __restrict__ o1)
{
  int gid = blockIdx.x*256 + threadIdx.x;       // 65536 = 2048 rows x 32 dims
  int row = gid >> 5, dim = gid & 31;
  int bh = row >> 7, q = row & 127;
  int b = bh >> 2, h = bh & 3;
  float M = -1e30f;
  #pragma unroll
  for (int ch=0; ch<NCH; ch++) M = fmaxf(M, pm[((size_t)bh*NCH+ch)*128 + q]);
  float L=0.f, O=0.f;
  for (int ch=0; ch<NCH; ch++){
    size_t pb = ((size_t)bh*NCH+ch)*128 + q;
    float e = __expf(pm[pb]-M);
    L += pl[pb]*e;
    O += po[pb*32+dim]*e;
  }
  o1[((size_t)b*T_+q)*D_ + h*32 + dim] = O / L;
}

// ---------------------------------------------------------------------------
// scalar online-softmax core (kept for mha2: only 128 keys)
// ---------------------------------------------------------------------------
DEVI void mha_core(const float* qv, const u16* Kb, const u16* Vb, int nk,
                   int lane, float* outp)
{
  const float scale = 0.17677669529663687f;
  float m=-1e30f, ssum=0.f, o[32];
  #pragma unroll
  for (int i=0;i<32;i++) o[i]=0.f;
  for (int c0=0;c0<nk;c0+=64){
    int key=c0+lane, keyc = key<nk? key: nk-1;
    const uint4* kp=(const uint4*)(Kb+(size_t)keyc*32);
    float sa=0.f;
    #pragma unroll
    for (int i=0;i<4;i++){ uint4 u=kp[i];
      sa += qv[i*8+0]*lo2f(u.x)+qv[i*8+1]*hi2f(u.x)+qv[i*8+2]*lo2f(u.y)+qv[i*8+3]*hi2f(u.y)
          + qv[i*8+4]*lo2f(u.z)+qv[i*8+5]*hi2f(u.z)+qv[i*8+6]*lo2f(u.w)+qv[i*8+7]*hi2f(u.w);
    }
    float s=sa*scale;
    float mn=fmaxf(m,s);
    float corr=__expf(m-mn);
    float p=(key<nk)?__expf(s-mn):0.f;
    ssum=ssum*corr+p;
    const uint4* vp=(const uint4*)(Vb+(size_t)keyc*32);
    #pragma unroll
    for (int i=0;i<4;i++){ uint4 u=vp[i];
      o[i*8+0]=o[i*8+0]*corr+p*lo2f(u.x); o[i*8+1]=o[i*8+1]*corr+p*hi2f(u.x);
      o[i*8+2]=o[i*8+2]*corr+p*lo2f(u.y); o[i*8+3]=o[i*8+3]*corr+p*hi2f(u.y);
      o[i*8+4]=o[i*8+4]*corr+p*lo2f(u.z); o[i*8+5]=o[i*8+5]*corr+p*hi2f(u.z);
      o[i*8+6]=o[i*8+6]*corr+p*lo2f(u.w); o[i*8+7]=o[i*8+7]*corr+p*hi2f(u.w);
    }
    m=mn;
  }
  float M=m;
  #pragma unroll
  for (int d=32;d>=1;d>>=1) M=fmaxf(M,__shfl_xor(M,d));
  float sc=__expf(m-M);
  float sm=ssum*sc;
  #pragma unroll
  for (int d=32;d>=1;d>>=1) sm+=__shfl_xor(sm,d);
  float inv=1.f/sm;
  #pragma unroll
  for (int i=0;i<32;i++){
    float v=o[i]*sc;
    #pragma unroll
    for (int d=32;d>=1;d>>=1) v+=__shfl_xor(v,d);
    if (lane==0) outp[i]=v*inv;
  }
}

__global__ __launch_bounds__(256) void k_mha2(
  const u16* __restrict__ qh2, const u16* __restrict__ kh2, const u16* __restrict__ vh2,
  float* __restrict__ o2)
{
  const int blk=blockIdx.x, bh=blk>>5, b=bh>>2, h=bh&3;
  const int w=threadIdx.x>>6, lane=threadIdx.x&63;
  const int q=(blk&31)*4+w;
  float qv[32];
  const uint4* qp=(const uint4*)(qh2 + ((size_t)bh*T_+q)*32);
  #pragma unroll
  for (int i=0;i<4;i++){ uint4 u=qp[i];
    qv[i*8+0]=lo2f(u.x); qv[i*8+1]=hi2f(u.x); qv[i*8+2]=lo2f(u.y); qv[i*8+3]=hi2f(u.y);
    qv[i*8+4]=lo2f(u.z); qv[i*8+5]=hi2f(u.z); qv[i*8+6]=lo2f(u.w); qv[i*8+7]=hi2f(u.w); }
  mha_core(qv, kh2+(size_t)bh*T_*32, vh2+(size_t)bh*T_*32, T_, lane,
           o2+((size_t)b*T_+q)*D_+h*32);
}

// ---------------------------------------------------------------------------
// K5a: W1 = o1@wo1^T+bo1; {q,k,v}h2 = W1@wqkv2^T+bqkv2
// ---------------------------------------------------------------------------
__global__ __launch_bounds__(256) void k_att12(
  const float* __restrict__ o1, const float* __restrict__ wo, const float* __restrict__ bo,
  const float* __restrict__ wqkv, const float* __restrict__ bqkv,
  u16* __restrict__ qh2, u16* __restrict__ kh2, u16* __restrict__ vh2)
{
  __shared__ u16 X[64][136];
  __shared__ u16 Y[64][392];
  const int tid=threadIdx.x, nl=tid>>2, part=tid&3;
  const int row = blockIdx.x*64 + nl;
  #pragma unroll
  for (int j=0;j<8;j++){
    int c = part*32 + j*4;
    f4 mv = *(const f4*)(o1 + (size_t)row*D_ + c);
    u16 ov[4];
    #pragma unroll
    for (int i=0;i<4;i++) ov[i]=f2b(nn(mv[i],2e4f));
    uint2 pk; __builtin_memcpy(&pk, ov, 8);
    *(uint2*)&X[nl][c]=pk;
  }
  __syncthreads();
  const int lane=tid&63, w=tid>>6, l15=lane&15, hi=lane>>4, rw=w*16;
  {
    f4 acc[8];
    #pragma unroll
    for (int t=0;t<8;t++){ float bb=bo[l15+16*t]; acc[t]=(f4){bb,bb,bb,bb}; }
    #pragma unroll
    for (int kk=0;kk<4;kk++){
      s8 a = *(const s8*)&X[rw+l15][kk*32+hi*8];
      #pragma unroll
      for (int t=0;t<8;t++){
        s8 bf = ldw8f(wo + (size_t)(t*16+l15)*D_ + kk*32+hi*8);
        acc[t]=mfma16(a,bf,acc[t]);
      }
    }
    #pragma unroll
    for (int t=0;t<8;t++){
      #pragma unroll
      for (int r=0;r<4;r++) Y[rw+hi*4+r][l15+16*t]=f2b(acc[t][r]);
    }
  }
  __syncthreads();
  f4 a2[24];
  #pragma unroll
  for (int t=0;t<24;t++){ float bb=bqkv[l15+16*t]; a2[t]=(f4){bb,bb,bb,bb}; }
  #pragma unroll
  for (int kk=0;kk<4;kk++){
    s8 a = *(const s8*)&Y[rw+l15][kk*32+hi*8];
    #pragma unroll
    for (int t=0;t<24;t++){
      s8 bf = ldw8f(wqkv + (size_t)(t*16+l15)*D_ + kk*32+hi*8);
      a2[t]=mfma16(a,bf,a2[t]);
    }
  }
  __syncthreads();
  #pragma unroll
  for (int t=0;t<24;t++){
    #pragma unroll
    for (int r=0;r<4;r++) Y[rw+hi*4+r][l15+16*t]=f2b(a2[t][r]);
  }
  __syncthreads();
  const int b=row>>7, q=row&127;
  #pragma unroll
  for (int j=0;j<12;j++){
    int u=part+4*j, col0=u*8;
    int sel=col0>>7, c2=col0&127, h=c2>>5, d=c2&31;
    u16* base = sel==0? qh2 : (sel==1? kh2 : vh2);
    *(uint4*)(base + ((size_t)(b*H_+h)*T_ + q)*32 + d) = *(const uint4*)&Y[nl][col0];
  }
}

// ---------------------------------------------------------------------------
// K5c: W2 = o2@wo2^T+bo2; kh3, vh3T
// ---------------------------------------------------------------------------
__global__ __launch_bounds__(256) void k_att23(
  const float* __restrict__ o2, const float* __restrict__ wo, const float* __restrict__ bo,
  const float* __restrict__ wqkv3, const float* __restrict__ bqkv3,
  u16* __restrict__ kh3, u16* __restrict__ vh3T)
{
  __shared__ u16 X[64][136];
  __shared__ u16 Y[64][264];
  const int tid=threadIdx.x, nl=tid>>2, part=tid&3;
  const int row = blockIdx.x*64 + nl;
  #pragma unroll
  for (int j=0;j<8;j++){
    int c = part*32 + j*4;
    f4 mv = *(const f4*)(o2 + (size_t)row*D_ + c);
    u16 ov[4];
    #pragma unroll
    for (int i=0;i<4;i++) ov[i]=f2b(nn(mv[i],3e4f));
    uint2 pk; __builtin_memcpy(&pk, ov, 8);
    *(uint2*)&X[nl][c]=pk;
  }
  __syncthreads();
  const int lane=tid&63, w=tid>>6, l15=lane&15, hi=lane>>4, rw=w*16;
  {
    f4 acc[8];
    #pragma unroll
    for (int t=0;t<8;t++){ float bb=bo[l15+16*t]; acc[t]=(f4){bb,bb,bb,bb}; }
    #pragma unroll
    for (int kk=0;kk<4;kk++){
      s8 a = *(const s8*)&X[rw+l15][kk*32+hi*8];
      #pragma unroll
      for (int t=0;t<8;t++){
        s8 bf = ldw8f(wo + (size_t)(t*16+l15)*D_ + kk*32+hi*8);
        acc[t]=mfma16(a,bf,acc[t]);
      }
    }
    #pragma unroll
    for (int t=0;t<8;t++){
      #pragma unroll
      for (int r=0;r<4;r++) Y[rw+hi*4+r][l15+16*t]=f2b(acc[t][r]);
    }
  }
  __syncthreads();
  f4 a2[16];
  #pragma unroll
  for (int t=0;t<16;t++){ float bb=bqkv3[128 + l15+16*t]; a2[t]=(f4){bb,bb,bb,bb}; }
  #pragma unroll
  for (int kk=0;kk<4;kk++){
    s8 a = *(const s8*)&Y[rw+l15][kk*32+hi*8];
    #pragma unroll
    for (int t=0;t<16;t++){
      s8 bf = ldw8f(wqkv3 + (size_t)(128 + t*16+l15)*D_ + kk*32+hi*8);
      a2[t]=mfma16(a,bf,a2[t]);
    }
  }
  __syncthreads();
  #pragma unroll
  for (int t=0;t<16;t++){
    #pragma unroll
    for (int r=0;r<4;r++) Y[rw+hi*4+r][l15+16*t]=f2b(a2[t][r]);
  }
  __syncthreads();
  const int b=row>>7, q=row&127;
  #pragma unroll
  for (int j=0;j<4;j++){
    int u=part+4*j, col0=u*8, h=col0>>5, d=col0&31;
    *(uint4*)(kh3 + ((size_t)(b*H_+h)*T_ + q)*32 + d) = *(const uint4*)&Y[nl][col0];
  }
  #pragma unroll
  for (int cc=0;cc<32;cc++){
    int c2 = part*32 + cc;
    int h=c2>>5, d=c2&31;
    vh3T[((size_t)(b*H_+h)*32 + d)*T_ + q] = Y[nl][128+c2];
  }
}

// ---------------------------------------------------------------------------
// K6a: mha3 + wo3 + residual V1 -> V2, x=LN2(V2)
// ---------------------------------------------------------------------------
__global__ __launch_bounds__(256,2) void k_mha3(
  const u16* __restrict__ W0, const u16* __restrict__ V1,
  const u16* __restrict__ wq3b, const float* __restrict__ bqkv3,
  const u16* __restrict__ kh3, const u16* __restrict__ vh3T,
  const u16* __restrict__ wo3b, const float* __restrict__ bo3,
  const float* __restrict__ l2g, const float* __restrict__ l2b,
  u16* __restrict__ V2, u16* __restrict__ XLN)
{
  __shared__ u16 Wt[64][136];
  __shared__ u16 Q3[64][136];
  __shared__ u16 P3[64][136];
  __shared__ float rsA[64][4], rsB[64][4];
  const int tid=threadIdx.x, nl=tid>>2, part=tid&3;
  const int b = blockIdx.x/157, tb = blockIdx.x - b*157;
  const int n0 = tb*64;
  {
    const int ns = min(n0+nl, N_-1);
    const u16* src = W0 + ((size_t)b*N_+ns)*D_;
    #pragma unroll
    for (int j=0;j<4;j++){ int u=part+4*j; *(uint4*)&Wt[nl][u*8] = *(const uint4*)(src+u*8); }
  }
  __syncthreads();
  const int lane=tid&63, w=tid>>6, l15=lane&15, hi=lane>>4;
  const int rw=w*16, colb=w*32;
  {
    f4 acc[4][2];
    #pragma unroll
    for (int m=0;m<4;m++)
      #pragma unroll
      for (int tl=0;tl<2;tl++){ float bb=bqkv3[colb+tl*16+l15]; acc[m][tl]=(f4){bb,bb,bb,bb}; }
    #pragma unroll
    for (int kk=0;kk<4;kk++){
      s8 bfr[2];
      #pragma unroll
      for (int tl=0;tl<2;tl++)
        bfr[tl] = *(const s8*)(wq3b + (size_t)(colb+tl*16+l15)*D_ + kk*32+hi*8);
      #pragma unroll
      for (int m=0;m<4;m++){
        s8 a = *(const s8*)&Wt[m*16+l15][kk*32+hi*8];
        #pragma unroll
        for (int tl=0;tl<2;tl++) acc[m][tl]=mfma16(a,bfr[tl],acc[m][tl]);
      }
    }
    #pragma unroll
    for (int m=0;m<4;m++)
      #pragma unroll
      for (int tl=0;tl<2;tl++)
        #pragma unroll
        for (int r=0;r<4;r++)
          Q3[m*16+hi*4+r][colb+tl*16+l15]=f2b(acc[m][tl][r]);
  }
  __syncthreads();
  const float scale=0.17677669529663687f;
  f4 oacc[8];
  #pragma unroll
  for (int t=0;t<8;t++) oacc[t]=(f4){0.f,0.f,0.f,0.f};
  #pragma unroll
  for (int h=0;h<H_;h++){
    f4 sa[8];
    #pragma unroll
    for (int t=0;t<8;t++) sa[t]=(f4){0.f,0.f,0.f,0.f};
    s8 aq = *(const s8*)&Q3[rw+l15][h*32+hi*8];
    #pragma unroll
    for (int t=0;t<8;t++){
      s8 bf = *(const s8*)(kh3 + ((size_t)(b*H_+h)*T_ + t*16+l15)*32 + hi*8);
      sa[t]=mfma16(aq,bf,sa[t]);
    }
    #pragma unroll
    for (int r=0;r<4;r++){
      const int row=rw+hi*4+r;
      float mx=-1e30f;
      float sv[8];
      #pragma unroll
      for (int t=0;t<8;t++){ sv[t]=sa[t][r]*scale; mx=fmaxf(mx,sv[t]); }
      mx=fmaxf(mx,__shfl_xor(mx,1)); mx=fmaxf(mx,__shfl_xor(mx,2));
      mx=fmaxf(mx,__shfl_xor(mx,4)); mx=fmaxf(mx,__shfl_xor(mx,8));
      float se=0.f; float pv[8];
      #pragma unroll
      for (int t=0;t<8;t++){ pv[t]=__expf(sv[t]-mx); se+=pv[t]; }
      se=rsum16(se);
      float inv=1.f/se;
      #pragma unroll
      for (int t=0;t<8;t++) P3[row][l15+16*t]=f2b(pv[t]*inv);
    }
    __syncthreads();
    #pragma unroll
    for (int kk=0;kk<4;kk++){
      s8 ap = *(const s8*)&P3[rw+l15][kk*32+hi*8];
      #pragma unroll
      for (int t2=0;t2<2;t2++){
        s8 bf = *(const s8*)(vh3T + ((size_t)(b*H_+h)*32 + t2*16+l15)*T_ + kk*32+hi*8);
        oacc[h*2+t2]=mfma16(ap,bf,oacc[h*2+t2]);
      }
    }
    __syncthreads();
  }
  #pragma unroll
  for (int t=0;t<8;t++){
    #pragma unroll
    for (int r=0;r<4;r++) Q3[rw+hi*4+r][l15+16*t]=f2b(oacc[t][r]);
  }
  __syncthreads();
  f4 a2[4][2];
  #pragma unroll
  for (int m=0;m<4;m++)
    #pragma unroll
    for (int tl=0;tl<2;tl++){ float bb=bo3[colb+tl*16+l15]; a2[m][tl]=(f4){bb,bb,bb,bb}; }
  #pragma unroll
  for (int kk=0;kk<4;kk++){
    s8 bfr[2];
    #pragma unroll
    for (int tl=0;tl<2;tl++)
      bfr[tl] = *(const s8*)(wo3b + (size_t)(colb+tl*16+l15)*D_ + kk*32+hi*8);
    #pragma unroll
    for (int m=0;m<4;m++){
      s8 a = *(const s8*)&Q3[m*16+l15][kk*32+hi*8];
      #pragma unroll
      for (int tl=0;tl<2;tl++) a2[m][tl]=mfma16(a,bfr[tl],a2[m][tl]);
    }
  }
  #pragma unroll
  for (int m=0;m<4;m++)
    #pragma unroll
    for (int r=0;r<4;r++){
      const int row=m*16+hi*4+r;
      const int nr = min(n0+row, N_-1);
      const size_t gr=(size_t)b*N_+nr;
      float ps=0.f, pq=0.f;
      #pragma unroll
      for (int tl=0;tl<2;tl++){
        float tmp = b2f(V1[gr*D_ + colb+tl*16+l15]) + a2[m][tl][r];
        a2[m][tl][r]=tmp; ps+=tmp; pq+=tmp*tmp;
      }
      ps=rsum16(ps); pq=rsum16(pq);
      if (l15==0){ rsA[row][w]=ps; rsB[row][w]=pq; }
    }
  __syncthreads();
  float g2v[2],b2v[2];
  #pragma unroll
  for (int tl=0;tl<2;tl++){ g2v[tl]=l2g[colb+tl*16+l15]; b2v[tl]=l2b[colb+tl*16+l15]; }
  #pragma unroll
  for (int m=0;m<4;m++)
    #pragma unroll
    for (int r=0;r<4;r++){
      const int row=m*16+hi*4+r;
      float s  = rsA[row][0]+rsA[row][1]+rsA[row][2]+rsA[row][3];
      float s2 = rsB[row][0]+rsB[row][1]+rsB[row][2]+rsB[row][3];
      float mean=s*(1.f/128.f);
      float rstd=rsqrtf(s2*(1.f/128.f)-mean*mean+1e-5f);
      #pragma unroll
      for (int tl=0;tl<2;tl++){
        int col=colb+tl*16+l15;
        float tmp=a2[m][tl][r];
        P3[row][col]=f2b(tmp);
        Wt[row][col]=f2b((tmp-mean)*rstd*g2v[tl]+b2v[tl]);
      }
    }
  __syncthreads();
  if (n0+nl < N_){
    const size_t gd=(size_t)b*N_+n0+nl;
    #pragma unroll
    for (int j=0;j<4;j++){
      int u=part+4*j;
      *(uint4*)(V2 + gd*D_ + u*8) = *(const uint4*)&P3[nl][u*8];
      *(uint4*)(XLN + gd*D_ + u*8) = *(const uint4*)&Wt[nl][u*8];
    }
  }
}

// ---------------------------------------------------------------------------
// K6b: FFN col-split: V3(f32) = V2 + W2f(silu(W1f(x)))
// ---------------------------------------------------------------------------
__global__ __launch_bounds__(256,2) void k_ffn(
  const u16* __restrict__ XLN, const u16* __restrict__ V2,
  const u16* __restrict__ w1b, const float* __restrict__ b1,
  const u16* __restrict__ w2b, const float* __restrict__ b2,
  float* __restrict__ V3)
{
  __shared__ u16 Xs[64][136];
  __shared__ u16 Hs[64][136];
  const int tid=threadIdx.x, nl=tid>>2, part=tid&3;
  const size_t gn = (size_t)blockIdx.x*64 + nl;
  #pragma unroll
  for (int j=0;j<4;j++){ int u=part+4*j; *(uint4*)&Xs[nl][u*8] = *(const uint4*)(XLN + gn*D_ + u*8); }
  __syncthreads();
  const int lane=tid&63, w=tid>>6, l15=lane&15, hi=lane>>4, colb=w*32;
  f4 accf[4][2];
  #pragma unroll
  for (int m=0;m<4;m++)
    #pragma unroll
    for (int tl=0;tl<2;tl++){ float bb=b2[colb+tl*16+l15]; accf[m][tl]=(f4){bb,bb,bb,bb}; }
  for (int half=0;half<2;half++){
    f4 ah[4][2];
    #pragma unroll
    for (int m=0;m<4;m++)
      #pragma unroll
      for (int tl=0;tl<2;tl++){ float bb=b1[half*128+colb+tl*16+l15]; ah[m][tl]=(f4){bb,bb,bb,bb}; }
    #pragma unroll
    for (int kk=0;kk<4;kk++){
      s8 bfr[2];
      #pragma unroll
      for (int tl=0;tl<2;tl++)
        bfr[tl] = *(const s8*)(w1b + (size_t)(half*128+colb+tl*16+l15)*D_ + kk*32+hi*8);
      #pragma unroll
      for (int m=0;m<4;m++){
        s8 a = *(const s8*)&Xs[m*16+l15][kk*32+hi*8];
        #pragma unroll
        for (int tl=0;tl<2;tl++) ah[m][tl]=mfma16(a,bfr[tl],ah[m][tl]);
      }
    }
    __syncthreads();
    #pragma unroll
    for (int m=0;m<4;m++)
      #pragma unroll
      for (int tl=0;tl<2;tl++)
        #pragma unroll
        for (int r=0;r<4;r++)
          Hs[m*16+hi*4+r][colb+tl*16+l15]=f2b(silu_f(ah[m][tl][r]));
    __syncthreads();
    #pragma unroll
    for (int kk=0;kk<4;kk++){
      s8 bfr[2];
      #pragma unroll
      for (int tl=0;tl<2;tl++)
        bfr[tl] = *(const s8*)(w2b + (size_t)(colb+tl*16+l15)*256 + half*128 + kk*32+hi*8);
      #pragma unroll
      for (int m=0;m<4;m++){
        s8 a = *(const s8*)&Hs[m*16+l15][kk*32+hi*8];
        #pragma unroll
        for (int tl=0;tl<2;tl++) accf[m][tl]=mfma16(a,bfr[tl],accf[m][tl]);
      }
    }
  }
  #pragma unroll
  for (int m=0;m<4;m++)
    #pragma unroll
    for (int r=0;r<4;r++){
      const int row=m*16+hi*4+r;
      const size_t gr=(size_t)blockIdx.x*64+row;
      #pragma unroll
      for (int tl=0;tl<2;tl++){
        int col=colb+tl*16+l15;
        V3[gr*D_+col] = b2f(V2[gr*D_+col]) + accf[m][tl][r];
      }
    }
}

// ---------------------------------------------------------------------------
extern "C" void kernel_launch(void* const* d_in, const int* in_sizes, int n_in,
                              void* d_out, int out_size, void* d_ws, size_t ws_size,
                              hipStream_t stream)
{
  const float* V     = (const float*)d_in[0];
  const float* E     = (const float*)d_in[1];
  const int* edges   = (const int*)d_in[2];
  const float* senc  = (const float*)d_in[3];
  const float* fe_w1=(const float*)d_in[4];  const float* fe_b1=(const float*)d_in[5];
  const float* fe_w2=(const float*)d_in[6];  const float* fe_b2=(const float*)d_in[7];
  const float* fe_g =(const float*)d_in[8];  const float* fe_be=(const float*)d_in[9];
  const float* fn_w1=(const float*)d_in[10]; const float* fn_b1=(const float*)d_in[11];
  const float* fn_w2=(const float*)d_in[12]; const float* fn_b2=(const float*)d_in[13];
  const float* fn_g =(const float*)d_in[14]; const float* fn_be=(const float*)d_in[15];
  const float* ln1_g=(const float*)d_in[16]; const float* ln1_b=(const float*)d_in[17];
  const float* ln2_g=(const float*)d_in[18]; const float* ln2_b=(const float*)d_in[19];
  const float* Q    =(const float*)d_in[20];
  const float* a1_wqkv=(const float*)d_in[21]; const float* a1_bqkv=(const float*)d_in[22];
  const float* a1_wo=(const float*)d_in[23];   const float* a1_bo=(const float*)d_in[24];
  const float* a2_wqkv=(const float*)d_in[25]; const float* a2_bqkv=(const float*)d_in[26];
  const float* a2_wo=(const float*)d_in[27];   const float* a2_bo=(const float*)d_in[28];
  const float* a3_wqkv=(const float*)d_in[29]; const float* a3_bqkv=(const float*)d_in[30];
  const float* a3_wo=(const float*)d_in[31];   const float* a3_bo=(const float*)d_in[32];
  const float* ffn_w1=(const float*)d_in[33];  const float* ffn_b1=(const float*)d_in[34];
  const float* ffn_w2=(const float*)d_in[35];  const float* ffn_b2=(const float*)d_in[36];

  char* ws = (char*)d_ws;
  size_t off = 0;
  auto alloc = [&](size_t bytes)->void*{ void* p = ws + off; off += (bytes + 255) & ~(size_t)255; return p; };
  float* m0s = (float*)alloc((size_t)B_*N_*64*4);
  float* m1s = (float*)alloc((size_t)B_*N_*64*4);
  float* c0s = (float*)alloc((size_t)B_*N_*4);
  float* c1s = (float*)alloc((size_t)B_*N_*4);
  const size_t zero_bytes = off;
  u16* wcat = (u16*)alloc((size_t)WTOT*2);
  u16* V1  = (u16*)alloc((size_t)B_*N_*D_*2);
  u16* W0  = (u16*)alloc((size_t)B_*N_*D_*2);
  u16* kh1 = (u16*)alloc((size_t)B_*H_*N_*32*2);
  u16* vh1 = (u16*)alloc((size_t)B_*H_*N_*32*2);
  u16* qh1 = (u16*)alloc((size_t)H_*T_*32*2);
  float* o1 = (float*)alloc((size_t)B_*T_*D_*4);
  u16* qh2 = (u16*)alloc((size_t)B_*H_*T_*32*2);
  u16* kh2 = (u16*)alloc((size_t)B_*H_*T_*32*2);
  u16* vh2 = (u16*)alloc((size_t)B_*H_*T_*32*2);
  float* o2 = (float*)alloc((size_t)B_*T_*D_*4);
  u16* kh3 = (u16*)alloc((size_t)B_*H_*T_*32*2);
  u16* vh3T= (u16*)alloc((size_t)B_*H_*32*T_*2);
  u16* V2  = (u16*)alloc((size_t)B_*N_*D_*2);
  u16* XLN = (u16*)alloc((size_t)B_*N_*D_*2);
  float* pmw = (float*)alloc((size_t)B_*H_*NCH*128*4);
  float* plw = (float*)alloc((size_t)B_*H_*NCH*128*4);
  float* pow_ = (float*)alloc((size_t)B_*H_*NCH*128*32*4);
  if (ws_size < off) return;

  u16* w_fe1 = wcat + WO_FE1;
  u16* w_fe2 = wcat + WO_FE2;
  u16* w_fn1 = wcat + WO_FN1;
  u16* w_fn2 = wcat + WO_FN2;
  u16* w_a1  = wcat + WO_A1;
  u16* w_a3  = wcat + WO_A3;
  u16* w_a3o = wcat + WO_A3O;
  u16* w_ff1 = wcat + WO_FF1;
  u16* w_ff2 = wcat + WO_FF2;

  float* outp = (float*)d_out;
  float* V3out = outp;
  float* Eout  = outp + (size_t)B_*N_*D_;

  hipMemsetAsync(d_ws, 0, zero_bytes, stream);
  k_cvtw<<<(WTOT/8+255)/256,256,0,stream>>>(fe_w1,fe_w2,fn_w1,fn_w2,a1_wqkv,a3_wqkv,a3_wo,
                                            ffn_w1,ffn_w2, wcat);
  k_edge<<<(B_*NE_)/64,256,0,stream>>>(V,E,edges,senc, w_fe1,fe_b1, w_fe2,fe_b2, fe_g,fe_be,
                                       m0s,m1s,c0s,c1s, Eout);
  k_node<<<(B_*N_)/64,256,0,stream>>>(V,senc,m0s,m1s,c0s,c1s, w_fn1,fn_b1, w_fn2,fn_b2,
                                      fn_g,fn_be, ln1_g,ln1_b, V1,W0);
  k_qh1<<<T_/64,256,0,stream>>>(Q, a1_wqkv, a1_bqkv, qh1);
  k_kv1<<<(B_*N_)/64,256,0,stream>>>(W0, w_a1, a1_bqkv, kh1, vh1);
  k_mha1p<<<B_*H_*NCH,256,0,stream>>>(qh1,kh1,vh1, pmw,plw,pow_);
  k_mha1c<<<(B_*H_*T_*32)/256,256,0,stream>>>(pmw,plw,pow_, o1);
  k_att12<<<(B_*T_)/64,256,0,stream>>>(o1, a1_wo, a1_bo, a2_wqkv, a2_bqkv, qh2,kh2,vh2);
  k_mha2<<<(B_*H_*T_)/4,256,0,stream>>>(qh2,kh2,vh2,o2);
  k_att23<<<(B_*T_)/64,256,0,stream>>>(o2, a2_wo, a2_bo, a3_wqkv, a3_bqkv, kh3, vh3T);
  k_mha3<<<B_*157,256,0,stream>>>(W0,V1, w_a3,a3_bqkv, kh3,vh3T, w_a3o,a3_bo,
                                  ln2_g,ln2_b, V2,XLN);
  k_ffn<<<(B_*N_)/64,256,0,stream>>>(XLN,V2, w_ff1,ffn_b1, w_ff2,ffn_b2, V3out);
}

// Round 7
// 619.664 us; speedup vs baseline: 2.4424x; 1.0124x over previous
//
#include <hip/hip_runtime.h>
#include <hip/hip_bf16.h>

#define B_ 4
#define N_ 10000
#define NE_ 100000
#define D_ 128
#define S_ 64
#define H_ 4
#define T_ 128

typedef unsigned short u16;
typedef unsigned int u32;
typedef __attribute__((ext_vector_type(4))) float f4;
typedef __attribute__((ext_vector_type(8))) short s8;

#define DEVI static __device__ __forceinline__

DEVI float b2f(u16 u){ union{u32 i; float f;} v; v.i=((u32)u)<<16; return v.f; }
DEVI u16 f2b(float f){ union{float ff; u32 i;} v; v.ff=f; u32 i=v.i; return (u16)((i+0x7fffu+((i>>16)&1u))>>16); }
DEVI f4 mfma16(s8 a, s8 b, f4 c){ return __builtin_amdgcn_mfma_f32_16x16x32_bf16(a,b,c,0,0,0); }
DEVI float rsum16(float x){ x+=__shfl_xor(x,1); x+=__shfl_xor(x,2); x+=__shfl_xor(x,4); x+=__shfl_xor(x,8); return x; }
DEVI float silu_f(float v){ return v/(1.f+__expf(-v)); }
DEVI float nn(float v, float s){ return (v==v)? v : s; }
DEVI float lo2f(u32 u){ union{u32 i; float f;} v; v.i=u<<16; return v.f; }
DEVI float hi2f(u32 u){ union{u32 i; float f;} v; v.i=u&0xffff0000u; return v.f; }

DEVI s8 ldw8f(const float* p){
  f4 a = *(const f4*)p;
  f4 c = *(const f4*)(p+4);
  union { u16 t[8]; s8 v; } u;
  #pragma unroll
  for (int i=0;i<4;i++){ u.t[i]=f2b(a[i]); u.t[4+i]=f2b(c[i]); }
  return u.v;
}
DEVI uint4 cvt8(const float* p){
  f4 a = *(const f4*)p;
  f4 c = *(const f4*)(p+4);
  union { u16 t[8]; uint4 v; } u;
  #pragma unroll
  for (int i=0;i<4;i++){ u.t[i]=f2b(a[i]); u.t[4+i]=f2b(c[i]); }
  return u.v;
}
DEVI uint4 cvt8nt(const float* p){
  f4 a = __builtin_nontemporal_load((const f4*)p);
  f4 c = __builtin_nontemporal_load((const f4*)(p+4));
  union { u16 t[8]; uint4 v; } u;
  #pragma unroll
  for (int i=0;i<4;i++){ u.t[i]=f2b(a[i]); u.t[4+i]=f2b(c[i]); }
  return u.v;
}

// ---------------------------------------------------------------------------
// weight preconversion f32 -> bf16
// ---------------------------------------------------------------------------
#define WO_FE1 0
#define WO_FE2 65536
#define WO_FN1 81920
#define WO_FN2 122880
#define WO_A1  139264
#define WO_A3  188416
#define WO_A3O 237568
#define WO_FF1 253952
#define WO_FF2 286720
#define WTOT   319488

__global__ __launch_bounds__(256) void k_cvtw(
  const float* __restrict__ s0, const float* __restrict__ s1,
  const float* __restrict__ s2, const float* __restrict__ s3,
  const float* __restrict__ s4, const float* __restrict__ s5,
  const float* __restrict__ s6, const float* __restrict__ s7,
  const float* __restrict__ s8v, u16* __restrict__ dst)
{
  int i = (blockIdx.x*256 + threadIdx.x)*8;
  if (i >= WTOT) return;
  const float* src; int off;
  if      (i < WO_FE2){ src=s0;  off=WO_FE1; }
  else if (i < WO_FN1){ src=s1;  off=WO_FE2; }
  else if (i < WO_FN2){ src=s2;  off=WO_FN1; }
  else if (i < WO_A1 ){ src=s3;  off=WO_FN2; }
  else if (i < WO_A3 ){ src=s4;  off=WO_A1;  }
  else if (i < WO_A3O){ src=s5;  off=WO_A3;  }
  else if (i < WO_FF1){ src=s6;  off=WO_A3O; }
  else if (i < WO_FF2){ src=s7;  off=WO_FF1; }
  else                { src=s8v; off=WO_FF2; }
  *(uint4*)(dst+i) = cvt8(src + (i-off));
}

// ---------------------------------------------------------------------------
// K1: edge MLP. 512 threads (8 waves, 16 out-cols each) -> 16 waves/CU.
// ---------------------------------------------------------------------------
__global__ __launch_bounds__(512,4) void k_edge(
  const float* __restrict__ V, const float* __restrict__ E, const int* __restrict__ edges,
  const float* __restrict__ senc,
  const u16* __restrict__ w1b, const float* __restrict__ b1,
  const u16* __restrict__ w2b, const float* __restrict__ b2,
  const float* __restrict__ lng, const float* __restrict__ lnb,
  float* __restrict__ m0s, float* __restrict__ m1s,
  float* __restrict__ c0s, float* __restrict__ c1s,
  float* __restrict__ Eout)
{
  __shared__ u16 X[64][520];
  __shared__ int gi0[64], gi1[64];
  __shared__ float fvalid[64];
  __shared__ float rsA[64][8], rsB[64][8];
  const int tid = threadIdx.x;
  const int el = tid>>3, part = tid&7;
  const int ge = blockIdx.x*64 + el;
  const int b = ge / NE_;
  const int2 ed = *(const int2*)(edges + (size_t)ge*2);
  const int i0 = min(max(ed.x,0),N_-1), i1 = min(max(ed.y,0),N_-1);
  if (part==0){
    gi0[el] = b*N_ + i0; gi1[el] = b*N_ + i1;
    fvalid[el] = (ed.x>=0 && ed.y>=0) ? 1.f : 0.f;
  }
  {
    const float* Vb = V + (size_t)b*N_*D_;
    const float* Sb = senc + (size_t)b*N_*S_;
    const float* Ep = E + (size_t)ge*D_;
    #pragma unroll
    for (int j=0;j<8;j++){
      int u = part + 8*j;
      if (u<48){
        const float* p;
        if (u<16)      p = Vb + (size_t)i0*D_ + u*8;
        else if (u<24) p = Sb + (size_t)i0*S_ + (u-16)*8;
        else if (u<40) p = Vb + (size_t)i1*D_ + (u-24)*8;
        else           p = Sb + (size_t)i1*S_ + (u-40)*8;
        *(uint4*)&X[el][u*8] = cvt8(p);
      } else {
        *(uint4*)&X[el][u*8] = cvt8nt(Ep + (u-48)*8);
      }
    }
  }
  __syncthreads();
  if (tid < 64){
    atomicAdd(&c0s[gi0[tid]], 1.f);
    atomicAdd(&c1s[gi1[tid]], 1.f);
  }
  const int lane = tid&63, w = tid>>6;        // w in 0..7
  const int l15 = lane&15, hi = lane>>4;
  const int colb = w*16;                       // 16 output cols per wave
  // stage 1: H = silu(X @ w1^T + b1)
  f4 acc[4];
  #pragma unroll
  for (int m=0;m<4;m++){ float bb=b1[colb+l15]; acc[m]=(f4){bb,bb,bb,bb}; }
  for (int kk=0;kk<16;kk++){
    s8 bfr = *(const s8*)(w1b + (size_t)(colb+l15)*512 + kk*32 + hi*8);
    #pragma unroll
    for (int m=0;m<4;m++){
      s8 a = *(const s8*)&X[m*16+l15][kk*32 + hi*8];
      acc[m] = mfma16(a, bfr, acc[m]);
    }
  }
  __syncthreads();   // stage-1 reads of X done before H overwrite
  #pragma unroll
  for (int m=0;m<4;m++)
    #pragma unroll
    for (int r=0;r<4;r++)
      X[m*16+hi*4+r][colb+l15] = f2b(silu_f(acc[m][r]));
  __syncthreads();
  // stage 2: Y = H @ w2^T + b2
  f4 a2[4];
  #pragma unroll
  for (int m=0;m<4;m++){ float bb=b2[colb+l15]; a2[m]=(f4){bb,bb,bb,bb}; }
  #pragma unroll
  for (int kk=0;kk<4;kk++){
    s8 bfr = *(const s8*)(w2b + (size_t)(colb+l15)*128 + kk*32 + hi*8);
    #pragma unroll
    for (int m=0;m<4;m++){
      s8 a = *(const s8*)&X[m*16+l15][kk*32 + hi*8];
      a2[m] = mfma16(a, bfr, a2[m]);
    }
  }
  // cross-wave LN row reduction (rows span 8 waves)
  #pragma unroll
  for (int m=0;m<4;m++)
    #pragma unroll
    for (int r=0;r<4;r++){
      float v=a2[m][r];
      float ps=rsum16(v), pq=rsum16(v*v);
      if (l15==0){ int row=m*16+hi*4+r; rsA[row][w]=ps; rsB[row][w]=pq; }
    }
  __syncthreads();
  const float gv=lng[colb+l15], bev=lnb[colb+l15];
  const int ge0 = blockIdx.x*64;
  #pragma unroll
  for (int m=0;m<4;m++)
    #pragma unroll
    for (int r=0;r<4;r++){
      const int row = m*16+hi*4+r;
      float s=0.f, s2=0.f;
      #pragma unroll
      for (int ww=0;ww<8;ww++){ s+=rsA[row][ww]; s2+=rsB[row][ww]; }
      const float mean = s*(1.f/128.f);
      const float rstd = rsqrtf(s2*(1.f/128.f) - mean*mean + 1e-5f);
      const float vm = fvalid[row];
      const int col = colb+l15;
      float ev = ((a2[m][r]-mean)*rstd*gv + bev) * vm;
      ev = nn(ev, 7e3f);
      if (col < 64) atomicAdd(m0s + (size_t)gi0[row]*64 + col, ev);
      else          atomicAdd(m1s + (size_t)gi1[row]*64 + (col-64), ev);
      float ef = b2f(X[row][384+col]);   // E live in LDS cols 384..511
      __builtin_nontemporal_store(ef + ev, Eout + (size_t)(ge0+row)*D_ + col);
    }
}

// ---------------------------------------------------------------------------
// K2: node MLP + V1 + W0=LN(V1) + FUSED kv1 (kh1/vh1 = W0 @ [wk1;wv1]^T)
// ---------------------------------------------------------------------------
__global__ __launch_bounds__(256,2) void k_nodekv(
  const float* __restrict__ V, const float* __restrict__ senc,
  const float* __restrict__ m0s, const float* __restrict__ m1s,
  const float* __restrict__ c0s, const float* __restrict__ c1s,
  const u16* __restrict__ w1b, const float* __restrict__ b1,
  const u16* __restrict__ w2b, const float* __restrict__ b2,
  const float* __restrict__ lng, const float* __restrict__ lnb,
  const float* __restrict__ l1g, const float* __restrict__ l1b,
  const u16* __restrict__ wqkvb, const float* __restrict__ bqkv,
  u16* __restrict__ V1, u16* __restrict__ W0,
  u16* __restrict__ kh1, u16* __restrict__ vh1)
{
  __shared__ u16 X[64][328];
  __shared__ float rsA[64][4], rsB[64][4];
  const int tid=threadIdx.x, nl=tid>>2, part=tid&3;
  const int gn = blockIdx.x*64 + nl;
  const int b = gn / N_, n = gn - b*N_;
  {
    const float* Vp = V + ((size_t)b*N_ + n)*D_;
    const float* Sp = senc + ((size_t)b*N_ + n)*S_;
    #pragma unroll
    for (int j=0;j<6;j++){
      int u = part + 4*j;
      const float* p = (u<16)? Vp + u*8 : Sp + (u-16)*8;
      *(uint4*)&X[nl][u*8] = cvt8(p);
    }
    const float rc0 = 1.f/fmaxf(c0s[gn],1.f), rc1 = 1.f/fmaxf(c1s[gn],1.f);
    #pragma unroll
    for (int j=0;j<8;j++){
      int c = part*32 + j*4;
      const float* src = (c<64)? m0s + (size_t)gn*64 + c : m1s + (size_t)gn*64 + (c-64);
      float rr = (c<64)? rc0 : rc1;
      f4 mv = *(const f4*)src;
      u16 ov[4];
      #pragma unroll
      for (int i=0;i<4;i++) ov[i]=f2b(mv[i]*rr);
      uint2 pk; __builtin_memcpy(&pk, ov, 8);
      *(uint2*)&X[nl][192+c] = pk;
    }
  }
  __syncthreads();
  const int lane=tid&63, w=tid>>6, l15=lane&15, hi=lane>>4, colb=w*32;
  f4 acc[4][2];
  #pragma unroll
  for (int m=0;m<4;m++)
    #pragma unroll
    for (int tl=0;tl<2;tl++){ float bb=b1[colb+tl*16+l15]; acc[m][tl]=(f4){bb,bb,bb,bb}; }
  for (int kk=0;kk<10;kk++){
    s8 bfr[2];
    #pragma unroll
    for (int tl=0;tl<2;tl++)
      bfr[tl] = *(const s8*)(w1b + (size_t)(colb+tl*16+l15)*320 + kk*32 + hi*8);
    #pragma unroll
    for (int m=0;m<4;m++){
      s8 a = *(const s8*)&X[m*16+l15][kk*32+hi*8];
      #pragma unroll
      for (int tl=0;tl<2;tl++) acc[m][tl]=mfma16(a,bfr[tl],acc[m][tl]);
    }
  }
  __syncthreads();
  #pragma unroll
  for (int m=0;m<4;m++)
    #pragma unroll
    for (int tl=0;tl<2;tl++)
      #pragma unroll
      for (int r=0;r<4;r++)
        X[m*16+hi*4+r][192+colb+tl*16+l15] = f2b(silu_f(acc[m][tl][r]));
  __syncthreads();
  f4 a2[4][2];
  #pragma unroll
  for (int m=0;m<4;m++)
    #pragma unroll
    for (int tl=0;tl<2;tl++){ float bb=b2[colb+tl*16+l15]; a2[m][tl]=(f4){bb,bb,bb,bb}; }
  #pragma unroll
  for (int kk=0;kk<4;kk++){
    s8 bfr[2];
    #pragma unroll
    for (int tl=0;tl<2;tl++)
      bfr[tl] = *(const s8*)(w2b + (size_t)(colb+tl*16+l15)*128 + kk*32 + hi*8);
    #pragma unroll
    for (int m=0;m<4;m++){
      s8 a = *(const s8*)&X[m*16+l15][192 + kk*32+hi*8];
      #pragma unroll
      for (int tl=0;tl<2;tl++) a2[m][tl]=mfma16(a,bfr[tl],a2[m][tl]);
    }
  }
  #pragma unroll
  for (int m=0;m<4;m++)
    #pragma unroll
    for (int r=0;r<4;r++){
      float ps=0.f, pq=0.f;
      #pragma unroll
      for (int tl=0;tl<2;tl++){ float v=a2[m][tl][r]; ps+=v; pq+=v*v; }
      ps=rsum16(ps); pq=rsum16(pq);
      if (l15==0){ int row=m*16+hi*4+r; rsA[row][w]=ps; rsB[row][w]=pq; }
    }
  __syncthreads();
  float gv[2],bev[2],g1v[2],b1v[2];
  #pragma unroll
  for (int tl=0;tl<2;tl++){
    int col=colb+tl*16+l15;
    gv[tl]=lng[col]; bev[tl]=lnb[col]; g1v[tl]=l1g[col]; b1v[tl]=l1b[col];
  }
  #pragma unroll
  for (int m=0;m<4;m++)
    #pragma unroll
    for (int r=0;r<4;r++){
      const int row=m*16+hi*4+r;
      float s  = rsA[row][0]+rsA[row][1]+rsA[row][2]+rsA[row][3];
      float s2 = rsB[row][0]+rsB[row][1]+rsB[row][2]+rsB[row][3];
      float mean=s*(1.f/128.f);
      float rstd=rsqrtf(s2*(1.f/128.f)-mean*mean+1e-5f);
      #pragma unroll
      for (int tl=0;tl<2;tl++){
        float ve=(a2[m][tl][r]-mean)*rstd*gv[tl]+bev[tl];
        a2[m][tl][r] = b2f(X[row][colb+tl*16+l15]) + ve;
      }
    }
  __syncthreads();
  #pragma unroll
  for (int m=0;m<4;m++)
    #pragma unroll
    for (int r=0;r<4;r++){
      float ps=0.f, pq=0.f;
      #pragma unroll
      for (int tl=0;tl<2;tl++){ float v=a2[m][tl][r]; ps+=v; pq+=v*v; }
      ps=rsum16(ps); pq=rsum16(pq);
      if (l15==0){ int row=m*16+hi*4+r; rsA[row][w]=ps; rsB[row][w]=pq; }
    }
  __syncthreads();
  #pragma unroll
  for (int m=0;m<4;m++)
    #pragma unroll
    for (int r=0;r<4;r++){
      const int row=m*16+hi*4+r;
      float sv  = rsA[row][0]+rsA[row][1]+rsA[row][2]+rsA[row][3];
      float sv2 = rsB[row][0]+rsB[row][1]+rsB[row][2]+rsB[row][3];
      float m2=sv*(1.f/128.f);
      float rs2=rsqrtf(sv2*(1.f/128.f)-m2*m2+1e-5f);
      #pragma unroll
      for (int tl=0;tl<2;tl++){
        int col=colb+tl*16+l15;
        float tmp=a2[m][tl][r];
        X[row][col]     = f2b(tmp);
        X[row][192+col] = f2b((tmp-m2)*rs2*g1v[tl]+b1v[tl]);
      }
    }
  __syncthreads();
  // V1/W0 stores (read X) + kv GEMM (reads X[192..319]) - both read-only on X
  #pragma unroll
  for (int j=0;j<4;j++){
    int u=part+4*j;
    *(uint4*)(V1 + (size_t)gn*D_ + u*8) = *(const uint4*)&X[nl][u*8];
    *(uint4*)(W0 + (size_t)gn*D_ + u*8) = *(const uint4*)&X[nl][192 + u*8];
  }
  const int colb2 = w*64;   // of 256 kv output cols
  f4 acck[4][4];
  #pragma unroll
  for (int m=0;m<4;m++)
    #pragma unroll
    for (int tl=0;tl<4;tl++){ float bb=bqkv[128 + colb2+tl*16+l15]; acck[m][tl]=(f4){bb,bb,bb,bb}; }
  #pragma unroll
  for (int kk=0;kk<4;kk++){
    s8 bfr[4];
    #pragma unroll
    for (int tl=0;tl<4;tl++)
      bfr[tl] = *(const s8*)(wqkvb + (size_t)(128 + colb2+tl*16+l15)*D_ + kk*32+hi*8);
    #pragma unroll
    for (int m=0;m<4;m++){
      s8 a = *(const s8*)&X[m*16+l15][192 + kk*32+hi*8];
      #pragma unroll
      for (int tl=0;tl<4;tl++) acck[m][tl]=mfma16(a,bfr[tl],acck[m][tl]);
    }
  }
  __syncthreads();   // all X reads (stores + GEMM) done before overwrite
  #pragma unroll
  for (int m=0;m<4;m++)
    #pragma unroll
    for (int tl=0;tl<4;tl++)
      #pragma unroll
      for (int r=0;r<4;r++)
        X[m*16+hi*4+r][colb2+tl*16+l15]=f2b(acck[m][tl][r]);
  __syncthreads();
  #pragma unroll
  for (int j=0;j<8;j++){
    int u=part+4*j, col0=u*8;
    u16* dst;
    if (col0<128){ int h=col0>>5, d=col0&31; dst = kh1 + ((size_t)(b*H_+h)*N_ + n)*32 + d; }
    else { int c2=col0-128; int h=c2>>5, d=c2&31; dst = vh1 + ((size_t)(b*H_+h)*N_ + n)*32 + d; }
    *(uint4*)dst = *(const uint4*)&X[nl][col0];
  }
}

// ---------------------------------------------------------------------------
// K3q: qh1 = Q@wq1^T+bq1
// ---------------------------------------------------------------------------
__global__ __launch_bounds__(256) void k_qh1(
  const float* __restrict__ Q, const float* __restrict__ wqkv, const float* __restrict__ bqkv,
  u16* __restrict__ qh1)
{
  __shared__ u16 X[64][136];
  const int tid=threadIdx.x, nl=tid>>2, part=tid&3;
  const int q = blockIdx.x*64 + nl;
  #pragma unroll
  for (int j=0;j<4;j++){ int u=part+4*j; *(uint4*)&X[nl][u*8] = cvt8(Q + (size_t)q*D_ + u*8); }
  __syncthreads();
  const int lane=tid&63, w=tid>>6, l15=lane&15, hi=lane>>4, rw=w*16;
  f4 acc[8];
  #pragma unroll
  for (int t=0;t<8;t++){ float bb=bqkv[l15+16*t]; acc[t]=(f4){bb,bb,bb,bb}; }
  #pragma unroll
  for (int kk=0;kk<4;kk++){
    s8 a = *(const s8*)&X[rw+l15][kk*32+hi*8];
    #pragma unroll
    for (int t=0;t<8;t++){
      s8 bf = ldw8f(wqkv + (size_t)(t*16+l15)*D_ + kk*32+hi*8);
      acc[t]=mfma16(a,bf,acc[t]);
    }
  }
  __syncthreads();
  #pragma unroll
  for (int t=0;t<8;t++){
    #pragma unroll
    for (int r=0;r<4;r++) X[rw+hi*4+r][l15+16*t]=f2b(acc[t][r]);
  }
  __syncthreads();
  #pragma unroll
  for (int j=0;j<4;j++){
    int u=part+4*j, col0=u*8, h=col0>>5, d=col0&31;
    *(uint4*)(qh1 + ((size_t)h*T_ + q)*32 + d) = *(const uint4*)&X[nl][col0];
  }
}

// ---------------------------------------------------------------------------
// K4: mha1 MFMA flash-decode
// ---------------------------------------------------------------------------
#define NCH 20
#define CHK 512

__global__ __launch_bounds__(256,2) void k_mha1p(
  const u16* __restrict__ qh1, const u16* __restrict__ kh1, const u16* __restrict__ vh1,
  float* __restrict__ pm, float* __restrict__ pl, float* __restrict__ po)
{
  __shared__ u16 VT[32][72];
  __shared__ u16 P[4][32][72];
  const int bh = blockIdx.x / NCH, ch = blockIdx.x - bh*NCH;
  const int tid = threadIdx.x, w = tid>>6, lane = tid&63, l15=lane&15, hi=lane>>4;
  const int h = bh & 3;
  const int k0 = ch*CHK;
  const int nk = min(CHK, N_ - k0);
  const u16* Kb = kh1 + ((size_t)bh*N_ + k0)*32;
  const u16* Vb = vh1 + ((size_t)bh*N_ + k0)*32;
  s8 aq[2];
  #pragma unroll
  for (int qt=0;qt<2;qt++)
    aq[qt] = *(const s8*)(qh1 + ((size_t)h*T_ + w*32 + qt*16 + l15)*32 + hi*8);
  const float scale = 0.17677669529663687f;
  float m_reg[2][4], l_reg[2][4];
  f4 acc[2][2];
  #pragma unroll
  for (int qt=0;qt<2;qt++){
    #pragma unroll
    for (int r=0;r<4;r++){ m_reg[qt][r]=-1e30f; l_reg[qt][r]=0.f; }
    #pragma unroll
    for (int dt=0;dt<2;dt++) acc[qt][dt]=(f4){0.f,0.f,0.f,0.f};
  }
  const int ntile = (nk+63)>>6;
  for (int kt=0; kt<ntile; kt++){
    {
      int key = tid>>2, dseg = tid&3;
      int kg = kt*64 + key;
      uint4 v = (kg<nk)? *(const uint4*)(Vb + (size_t)kg*32 + dseg*8) : (uint4){0,0,0,0};
      const u16* vv = (const u16*)&v;
      #pragma unroll
      for (int i=0;i<8;i++) VT[dseg*8+i][key] = vv[i];
    }
    __syncthreads();
    f4 sa[2][4];
    #pragma unroll
    for (int kt4=0;kt4<4;kt4++){
      int key = kt*64 + kt4*16 + l15;
      int keyc = min(key, nk-1);
      s8 bk = *(const s8*)(Kb + (size_t)keyc*32 + hi*8);
      #pragma unroll
      for (int qt=0;qt<2;qt++)
        sa[qt][kt4] = mfma16(aq[qt], bk, (f4){0.f,0.f,0.f,0.f});
    }
    #pragma unroll
    for (int qt=0;qt<2;qt++){
      #pragma unroll
      for (int r=0;r<4;r++){
        float s[4];
        float mx = -1e30f;
        #pragma unroll
        for (int kt4=0;kt4<4;kt4++){
          int key = kt*64 + kt4*16 + l15;
          s[kt4] = (key<nk)? sa[qt][kt4][r]*scale : -1e30f;
          mx = fmaxf(mx, s[kt4]);
        }
        mx=fmaxf(mx,__shfl_xor(mx,1)); mx=fmaxf(mx,__shfl_xor(mx,2));
        mx=fmaxf(mx,__shfl_xor(mx,4)); mx=fmaxf(mx,__shfl_xor(mx,8));
        float mn = fmaxf(m_reg[qt][r], mx);
        float corr = __expf(m_reg[qt][r]-mn);
        float ps=0.f;
        #pragma unroll
        for (int kt4=0;kt4<4;kt4++){
          float p = __expf(s[kt4]-mn);
          ps += p;
          P[w][qt*16+hi*4+r][kt4*16+l15] = f2b(p);
        }
        ps = rsum16(ps);
        l_reg[qt][r] = l_reg[qt][r]*corr + ps;
        m_reg[qt][r] = mn;
        #pragma unroll
        for (int dt=0;dt<2;dt++) acc[qt][dt][r] *= corr;
      }
    }
    __syncthreads();
    #pragma unroll
    for (int ks=0;ks<2;ks++){
      s8 bv[2];
      #pragma unroll
      for (int dt=0;dt<2;dt++)
        bv[dt] = *(const s8*)&VT[dt*16+l15][ks*32+hi*8];
      #pragma unroll
      for (int qt=0;qt<2;qt++){
        s8 pa = *(const s8*)&P[w][qt*16+l15][ks*32+hi*8];
        #pragma unroll
        for (int dt=0;dt<2;dt++)
          acc[qt][dt]=mfma16(pa,bv[dt],acc[qt][dt]);
      }
    }
    __syncthreads();
  }
  const size_t pbase = ((size_t)bh*NCH + ch)*128;
  #pragma unroll
  for (int qt=0;qt<2;qt++)
    #pragma unroll
    for (int r=0;r<4;r++){
      int row = w*32 + qt*16 + hi*4 + r;
      if (l15==0){ pm[pbase+row]=m_reg[qt][r]; pl[pbase+row]=l_reg[qt][r]; }
      #pragma unroll
      for (int dt=0;dt<2;dt++)
        po[(pbase+row)*32 + dt*16 + l15] = acc[qt][dt][r];
    }
}

__global__ __launch_bounds__(256) void k_mha1c(
  const float* __restrict__ pm, const float* __restrict__ pl, const float* __restrict__ po,
  float* __restrict__ o1)
{
  int gid = blockIdx.x*256 + threadIdx.x;
  int row = gid >> 5, dim = gid & 31;
  int bh = row >> 7, q = row & 127;
  int b = bh >> 2, h = bh & 3;
  float M = -1e30f;
  #pragma unroll
  for (int ch=0; ch<NCH; ch++) M = fmaxf(M, pm[((size_t)bh*NCH+ch)*128 + q]);
  float L=0.f, O=0.f;
  for (int ch=0; ch<NCH; ch++){
    size_t pb = ((size_t)bh*NCH+ch)*128 + q;
    float e = __expf(pm[pb]-M);
    L += pl[pb]*e;
    O += po[pb*32+dim]*e;
  }
  o1[((size_t)b*T_+q)*D_ + h*32 + dim] = O / L;
}

// ---------------------------------------------------------------------------
// scalar online-softmax core (mha2: 128 keys)
// ---------------------------------------------------------------------------
DEVI void mha_core(const float* qv, const u16* Kb, const u16* Vb, int nk,
                   int lane, float* outp)
{
  const float scale = 0.17677669529663687f;
  float m=-1e30f, ssum=0.f, o[32];
  #pragma unroll
  for (int i=0;i<32;i++) o[i]=0.f;
  for (int c0=0;c0<nk;c0+=64){
    int key=c0+lane, keyc = key<nk? key: nk-1;
    const uint4* kp=(const uint4*)(Kb+(size_t)keyc*32);
    float sa=0.f;
    #pragma unroll
    for (int i=0;i<4;i++){ uint4 u=kp[i];
      sa += qv[i*8+0]*lo2f(u.x)+qv[i*8+1]*hi2f(u.x)+qv[i*8+2]*lo2f(u.y)+qv[i*8+3]*hi2f(u.y)
          + qv[i*8+4]*lo2f(u.z)+qv[i*8+5]*hi2f(u.z)+qv[i*8+6]*lo2f(u.w)+qv[i*8+7]*hi2f(u.w);
    }
    float s=sa*scale;
    float mn=fmaxf(m,s);
    float corr=__expf(m-mn);
    float p=(key<nk)?__expf(s-mn):0.f;
    ssum=ssum*corr+p;
    const uint4* vp=(const uint4*)(Vb+(size_t)keyc*32);
    #pragma unroll
    for (int i=0;i<4;i++){ uint4 u=vp[i];
      o[i*8+0]=o[i*8+0]*corr+p*lo2f(u.x); o[i*8+1]=o[i*8+1]*corr+p*hi2f(u.x);
      o[i*8+2]=o[i*8+2]*corr+p*lo2f(u.y); o[i*8+3]=o[i*8+3]*corr+p*hi2f(u.y);
      o[i*8+4]=o[i*8+4]*corr+p*lo2f(u.z); o[i*8+5]=o[i*8+5]*corr+p*hi2f(u.z);
      o[i*8+6]=o[i*8+6]*corr+p*lo2f(u.w); o[i*8+7]=o[i*8+7]*corr+p*hi2f(u.w);
    }
    m=mn;
  }
  float M=m;
  #pragma unroll
  for (int d=32;d>=1;d>>=1) M=fmaxf(M,__shfl_xor(M,d));
  float sc=__expf(m-M);
  float sm=ssum*sc;
  #pragma unroll
  for (int d=32;d>=1;d>>=1) sm+=__shfl_xor(sm,d);
  float inv=1.f/sm;
  #pragma unroll
  for (int i=0;i<32;i++){
    float v=o[i]*sc;
    #pragma unroll
    for (int d=32;d>=1;d>>=1) v+=__shfl_xor(v,d);
    if (lane==0) outp[i]=v*inv;
  }
}

__global__ __launch_bounds__(256) void k_mha2(
  const u16* __restrict__ qh2, const u16* __restrict__ kh2, const u16* __restrict__ vh2,
  float* __restrict__ o2)
{
  const int blk=blockIdx.x, bh=blk>>5, b=bh>>2, h=bh&3;
  const int w=threadIdx.x>>6, lane=threadIdx.x&63;
  const int q=(blk&31)*4+w;
  float qv[32];
  const uint4* qp=(const uint4*)(qh2 + ((size_t)bh*T_+q)*32);
  #pragma unroll
  for (int i=0;i<4;i++){ uint4 u=qp[i];
    qv[i*8+0]=lo2f(u.x); qv[i*8+1]=hi2f(u.x); qv[i*8+2]=lo2f(u.y); qv[i*8+3]=hi2f(u.y);
    qv[i*8+4]=lo2f(u.z); qv[i*8+5]=hi2f(u.z); qv[i*8+6]=lo2f(u.w); qv[i*8+7]=hi2f(u.w); }
  mha_core(qv, kh2+(size_t)bh*T_*32, vh2+(size_t)bh*T_*32, T_, lane,
           o2+((size_t)b*T_+q)*D_+h*32);
}

// ---------------------------------------------------------------------------
// K5a: W1 = o1@wo1^T+bo1; {q,k,v}h2 = W1@wqkv2^T+bqkv2
// ---------------------------------------------------------------------------
__global__ __launch_bounds__(256) void k_att12(
  const float* __restrict__ o1, const float* __restrict__ wo, const float* __restrict__ bo,
  const float* __restrict__ wqkv, const float* __restrict__ bqkv,
  u16* __restrict__ qh2, u16* __restrict__ kh2, u16* __restrict__ vh2)
{
  __shared__ u16 X[64][136];
  __shared__ u16 Y[64][392];
  const int tid=threadIdx.x, nl=tid>>2, part=tid&3;
  const int row = blockIdx.x*64 + nl;
  #pragma unroll
  for (int j=0;j<8;j++){
    int c = part*32 + j*4;
    f4 mv = *(const f4*)(o1 + (size_t)row*D_ + c);
    u16 ov[4];
    #pragma unroll
    for (int i=0;i<4;i++) ov[i]=f2b(nn(mv[i],2e4f));
    uint2 pk; __builtin_memcpy(&pk, ov, 8);
    *(uint2*)&X[nl][c]=pk;
  }
  __syncthreads();
  const int lane=tid&63, w=tid>>6, l15=lane&15, hi=lane>>4, rw=w*16;
  {
    f4 acc[8];
    #pragma unroll
    for (int t=0;t<8;t++){ float bb=bo[l15+16*t]; acc[t]=(f4){bb,bb,bb,bb}; }
    #pragma unroll
    for (int kk=0;kk<4;kk++){
      s8 a = *(const s8*)&X[rw+l15][kk*32+hi*8];
      #pragma unroll
      for (int t=0;t<8;t++){
        s8 bf = ldw8f(wo + (size_t)(t*16+l15)*D_ + kk*32+hi*8);
        acc[t]=mfma16(a,bf,acc[t]);
      }
    }
    #pragma unroll
    for (int t=0;t<8;t++){
      #pragma unroll
      for (int r=0;r<4;r++) Y[rw+hi*4+r][l15+16*t]=f2b(acc[t][r]);
    }
  }
  __syncthreads();
  f4 a2[24];
  #pragma unroll
  for (int t=0;t<24;t++){ float bb=bqkv[l15+16*t]; a2[t]=(f4){bb,bb,bb,bb}; }
  #pragma unroll
  for (int kk=0;kk<4;kk++){
    s8 a = *(const s8*)&Y[rw+l15][kk*32+hi*8];
    #pragma unroll
    for (int t=0;t<24;t++){
      s8 bf = ldw8f(wqkv + (size_t)(t*16+l15)*D_ + kk*32+hi*8);
      a2[t]=mfma16(a,bf,a2[t]);
    }
  }
  __syncthreads();
  #pragma unroll
  for (int t=0;t<24;t++){
    #pragma unroll
    for (int r=0;r<4;r++) Y[rw+hi*4+r][l15+16*t]=f2b(a2[t][r]);
  }
  __syncthreads();
  const int b=row>>7, q=row&127;
  #pragma unroll
  for (int j=0;j<12;j++){
    int u=part+4*j, col0=u*8;
    int sel=col0>>7, c2=col0&127, h=c2>>5, d=c2&31;
    u16* base = sel==0? qh2 : (sel==1? kh2 : vh2);
    *(uint4*)(base + ((size_t)(b*H_+h)*T_ + q)*32 + d) = *(const uint4*)&Y[nl][col0];
  }
}

// ---------------------------------------------------------------------------
// K5c: W2 = o2@wo2^T+bo2; kh3, vh3T
// ---------------------------------------------------------------------------
__global__ __launch_bounds__(256) void k_att23(
  const float* __restrict__ o2, const float* __restrict__ wo, const float* __restrict__ bo,
  const float* __restrict__ wqkv3, const float* __restrict__ bqkv3,
  u16* __restrict__ kh3, u16* __restrict__ vh3T)
{
  __shared__ u16 X[64][136];
  __shared__ u16 Y[64][264];
  const int tid=threadIdx.x, nl=tid>>2, part=tid&3;
  const int row = blockIdx.x*64 + nl;
  #pragma unroll
  for (int j=0;j<8;j++){
    int c = part*32 + j*4;
    f4 mv = *(const f4*)(o2 + (size_t)row*D_ + c);
    u16 ov[4];
    #pragma unroll
    for (int i=0;i<4;i++) ov[i]=f2b(nn(mv[i],3e4f));
    uint2 pk; __builtin_memcpy(&pk, ov, 8);
    *(uint2*)&X[nl][c]=pk;
  }
  __syncthreads();
  const int lane=tid&63, w=tid>>6, l15=lane&15, hi=lane>>4, rw=w*16;
  {
    f4 acc[8];
    #pragma unroll
    for (int t=0;t<8;t++){ float bb=bo[l15+16*t]; acc[t]=(f4){bb,bb,bb,bb}; }
    #pragma unroll
    for (int kk=0;kk<4;kk++){
      s8 a = *(const s8*)&X[rw+l15][kk*32+hi*8];
      #pragma unroll
      for (int t=0;t<8;t++){
        s8 bf = ldw8f(wo + (size_t)(t*16+l15)*D_ + kk*32+hi*8);
        acc[t]=mfma16(a,bf,acc[t]);
      }
    }
    #pragma unroll
    for (int t=0;t<8;t++){
      #pragma unroll
      for (int r=0;r<4;r++) Y[rw+hi*4+r][l15+16*t]=f2b(acc[t][r]);
    }
  }
  __syncthreads();
  f4 a2[16];
  #pragma unroll
  for (int t=0;t<16;t++){ float bb=bqkv3[128 + l15+16*t]; a2[t]=(f4){bb,bb,bb,bb}; }
  #pragma unroll
  for (int kk=0;kk<4;kk++){
    s8 a = *(const s8*)&Y[rw+l15][kk*32+hi*8];
    #pragma unroll
    for (int t=0;t<16;t++){
      s8 bf = ldw8f(wqkv3 + (size_t)(128 + t*16+l15)*D_ + kk*32+hi*8);
      a2[t]=mfma16(a,bf,a2[t]);
    }
  }
  __syncthreads();
  #pragma unroll
  for (int t=0;t<16;t++){
    #pragma unroll
    for (int r=0;r<4;r++) Y[rw+hi*4+r][l15+16*t]=f2b(a2[t][r]);
  }
  __syncthreads();
  const int b=row>>7, q=row&127;
  #pragma unroll
  for (int j=0;j<4;j++){
    int u=part+4*j, col0=u*8, h=col0>>5, d=col0&31;
    *(uint4*)(kh3 + ((size_t)(b*H_+h)*T_ + q)*32 + d) = *(const uint4*)&Y[nl][col0];
  }
  #pragma unroll
  for (int cc=0;cc<32;cc++){
    int c2 = part*32 + cc;
    int h=c2>>5, d=c2&31;
    vh3T[((size_t)(b*H_+h)*32 + d)*T_ + q] = Y[nl][128+c2];
  }
}

// ---------------------------------------------------------------------------
// K6: mha3 + wo3 + residual -> V2, LN2 -> XLN, FUSED FFN -> V3 (f32)
// ---------------------------------------------------------------------------
__global__ __launch_bounds__(256,2) void k_mha3f(
  const u16* __restrict__ W0, const u16* __restrict__ V1,
  const u16* __restrict__ wq3b, const float* __restrict__ bqkv3,
  const u16* __restrict__ kh3, const u16* __restrict__ vh3T,
  const u16* __restrict__ wo3b, const float* __restrict__ bo3,
  const float* __restrict__ l2g, const float* __restrict__ l2b,
  const u16* __restrict__ fw1b, const float* __restrict__ fb1,
  const u16* __restrict__ fw2b, const float* __restrict__ fb2,
  float* __restrict__ V3)
{
  __shared__ u16 Wt[64][136];   // W0 tile -> XLN
  __shared__ u16 Q3[64][136];   // q3 -> attn-out -> FFN hidden (Hs)
  __shared__ u16 P3[64][136];   // softmax P -> V2
  __shared__ float rsA[64][4], rsB[64][4];
  const int tid=threadIdx.x, nl=tid>>2, part=tid&3;
  const int b = blockIdx.x/157, tb = blockIdx.x - b*157;
  const int n0 = tb*64;
  {
    const int ns = min(n0+nl, N_-1);
    const u16* src = W0 + ((size_t)b*N_+ns)*D_;
    #pragma unroll
    for (int j=0;j<4;j++){ int u=part+4*j; *(uint4*)&Wt[nl][u*8] = *(const uint4*)(src+u*8); }
  }
  __syncthreads();
  const int lane=tid&63, w=tid>>6, l15=lane&15, hi=lane>>4;
  const int rw=w*16, colb=w*32;
  {
    f4 acc[4][2];
    #pragma unroll
    for (int m=0;m<4;m++)
      #pragma unroll
      for (int tl=0;tl<2;tl++){ float bb=bqkv3[colb+tl*16+l15]; acc[m][tl]=(f4){bb,bb,bb,bb}; }
    #pragma unroll
    for (int kk=0;kk<4;kk++){
      s8 bfr[2];
      #pragma unroll
      for (int tl=0;tl<2;tl++)
        bfr[tl] = *(const s8*)(wq3b + (size_t)(colb+tl*16+l15)*D_ + kk*32+hi*8);
      #pragma unroll
      for (int m=0;m<4;m++){
        s8 a = *(const s8*)&Wt[m*16+l15][kk*32+hi*8];
        #pragma unroll
        for (int tl=0;tl<2;tl++) acc[m][tl]=mfma16(a,bfr[tl],acc[m][tl]);
      }
    }
    #pragma unroll
    for (int m=0;m<4;m++)
      #pragma unroll
      for (int tl=0;tl<2;tl++)
        #pragma unroll
        for (int r=0;r<4;r++)
          Q3[m*16+hi*4+r][colb+tl*16+l15]=f2b(acc[m][tl][r]);
  }
  __syncthreads();
  const float scale=0.17677669529663687f;
  f4 oacc[8];
  #pragma unroll
  for (int t=0;t<8;t++) oacc[t]=(f4){0.f,0.f,0.f,0.f};
  #pragma unroll
  for (int h=0;h<H_;h++){
    f4 sa[8];
    #pragma unroll
    for (int t=0;t<8;t++) sa[t]=(f4){0.f,0.f,0.f,0.f};
    s8 aq = *(const s8*)&Q3[rw+l15][h*32+hi*8];
    #pragma unroll
    for (int t=0;t<8;t++){
      s8 bf = *(const s8*)(kh3 + ((size_t)(b*H_+h)*T_ + t*16+l15)*32 + hi*8);
      sa[t]=mfma16(aq,bf,sa[t]);
    }
    #pragma unroll
    for (int r=0;r<4;r++){
      const int row=rw+hi*4+r;
      float mx=-1e30f;
      float sv[8];
      #pragma unroll
      for (int t=0;t<8;t++){ sv[t]=sa[t][r]*scale; mx=fmaxf(mx,sv[t]); }
      mx=fmaxf(mx,__shfl_xor(mx,1)); mx=fmaxf(mx,__shfl_xor(mx,2));
      mx=fmaxf(mx,__shfl_xor(mx,4)); mx=fmaxf(mx,__shfl_xor(mx,8));
      float se=0.f; float pv[8];
      #pragma unroll
      for (int t=0;t<8;t++){ pv[t]=__expf(sv[t]-mx); se+=pv[t]; }
      se=rsum16(se);
      float inv=1.f/se;
      #pragma unroll
      for (int t=0;t<8;t++) P3[row][l15+16*t]=f2b(pv[t]*inv);
    }
    __syncthreads();
    #pragma unroll
    for (int kk=0;kk<4;kk++){
      s8 ap = *(const s8*)&P3[rw+l15][kk*32+hi*8];
      #pragma unroll
      for (int t2=0;t2<2;t2++){
        s8 bf = *(const s8*)(vh3T + ((size_t)(b*H_+h)*32 + t2*16+l15)*T_ + kk*32+hi*8);
        oacc[h*2+t2]=mfma16(ap,bf,oacc[h*2+t2]);
      }
    }
    __syncthreads();
  }
  #pragma unroll
  for (int t=0;t<8;t++){
    #pragma unroll
    for (int r=0;r<4;r++) Q3[rw+hi*4+r][l15+16*t]=f2b(oacc[t][r]);
  }
  __syncthreads();
  // wo3 col-split + residual + LN2
  f4 a2[4][2];
  #pragma unroll
  for (int m=0;m<4;m++)
    #pragma unroll
    for (int tl=0;tl<2;tl++){ float bb=bo3[colb+tl*16+l15]; a2[m][tl]=(f4){bb,bb,bb,bb}; }
  #pragma unroll
  for (int kk=0;kk<4;kk++){
    s8 bfr[2];
    #pragma unroll
    for (int tl=0;tl<2;tl++)
      bfr[tl] = *(const s8*)(wo3b + (size_t)(colb+tl*16+l15)*D_ + kk*32+hi*8);
    #pragma unroll
    for (int m=0;m<4;m++){
      s8 a = *(const s8*)&Q3[m*16+l15][kk*32+hi*8];
      #pragma unroll
      for (int tl=0;tl<2;tl++) a2[m][tl]=mfma16(a,bfr[tl],a2[m][tl]);
    }
  }
  #pragma unroll
  for (int m=0;m<4;m++)
    #pragma unroll
    for (int r=0;r<4;r++){
      const int row=m*16+hi*4+r;
      const int nr = min(n0+row, N_-1);
      const size_t gr=(size_t)b*N_+nr;
      float ps=0.f, pq=0.f;
      #pragma unroll
      for (int tl=0;tl<2;tl++){
        float tmp = b2f(V1[gr*D_ + colb+tl*16+l15]) + a2[m][tl][r];
        a2[m][tl][r]=tmp; ps+=tmp; pq+=tmp*tmp;
      }
      ps=rsum16(ps); pq=rsum16(pq);
      if (l15==0){ rsA[row][w]=ps; rsB[row][w]=pq; }
    }
  __syncthreads();
  float g2v[2],b2v[2];
  #pragma unroll
  for (int tl=0;tl<2;tl++){ g2v[tl]=l2g[colb+tl*16+l15]; b2v[tl]=l2b[colb+tl*16+l15]; }
  #pragma unroll
  for (int m=0;m<4;m++)
    #pragma unroll
    for (int r=0;r<4;r++){
      const int row=m*16+hi*4+r;
      float s  = rsA[row][0]+rsA[row][1]+rsA[row][2]+rsA[row][3];
      float s2 = rsB[row][0]+rsB[row][1]+rsB[row][2]+rsB[row][3];
      float mean=s*(1.f/128.f);
      float rstd=rsqrtf(s2*(1.f/128.f)-mean*mean+1e-5f);
      #pragma unroll
      for (int tl=0;tl<2;tl++){
        int col=colb+tl*16+l15;
        float tmp=a2[m][tl][r];
        P3[row][col]=f2b(tmp);                                 // V2
        Wt[row][col]=f2b((tmp-mean)*rstd*g2v[tl]+b2v[tl]);     // XLN
      }
    }
  __syncthreads();
  // ---- fused FFN: V3 = V2 + fw2(silu(fw1(XLN))) ----
  f4 accf[4][2];
  #pragma unroll
  for (int m=0;m<4;m++)
    #pragma unroll
    for (int tl=0;tl<2;tl++){ float bb=fb2[colb+tl*16+l15]; accf[m][tl]=(f4){bb,bb,bb,bb}; }
  for (int half=0;half<2;half++){
    f4 ah[4][2];
    #pragma unroll
    for (int m=0;m<4;m++)
      #pragma unroll
      for (int tl=0;tl<2;tl++){ float bb=fb1[half*128+colb+tl*16+l15]; ah[m][tl]=(f4){bb,bb,bb,bb}; }
    #pragma unroll
    for (int kk=0;kk<4;kk++){
      s8 bfr[2];
      #pragma unroll
      for (int tl=0;tl<2;tl++)
        bfr[tl] = *(const s8*)(fw1b + (size_t)(half*128+colb+tl*16+l15)*D_ + kk*32+hi*8);
      #pragma unroll
      for (int m=0;m<4;m++){
        s8 a = *(const s8*)&Wt[m*16+l15][kk*32+hi*8];
        #pragma unroll
        for (int tl=0;tl<2;tl++) ah[m][tl]=mfma16(a,bfr[tl],ah[m][tl]);
      }
    }
    __syncthreads();   // prior Q3 (Hs) readers done before overwrite
    #pragma unroll
    for (int m=0;m<4;m++)
      #pragma unroll
      for (int tl=0;tl<2;tl++)
        #pragma unroll
        for (int r=0;r<4;r++)
          Q3[m*16+hi*4+r][colb+tl*16+l15]=f2b(silu_f(ah[m][tl][r]));
    __syncthreads();
    #pragma unroll
    for (int kk=0;kk<4;kk++){
      s8 bfr[2];
      #pragma unroll
      for (int tl=0;tl<2;tl++)
        bfr[tl] = *(const s8*)(fw2b + (size_t)(colb+tl*16+l15)*256 + half*128 + kk*32+hi*8);
      #pragma unroll
      for (int m=0;m<4;m++){
        s8 a = *(const s8*)&Q3[m*16+l15][kk*32+hi*8];
        #pragma unroll
        for (int tl=0;tl<2;tl++) accf[m][tl]=mfma16(a,bfr[tl],accf[m][tl]);
      }
    }
  }
  #pragma unroll
  for (int m=0;m<4;m++)
    #pragma unroll
    for (int r=0;r<4;r++){
      const int row=m*16+hi*4+r;
      if (n0+row < N_){
        const size_t gr=(size_t)b*N_+n0+row;
        #pragma unroll
        for (int tl=0;tl<2;tl++){
          int col=colb+tl*16+l15;
          V3[gr*D_+col] = b2f(P3[row][col]) + accf[m][tl][r];
        }
      }
    }
}

// ---------------------------------------------------------------------------
extern "C" void kernel_launch(void* const* d_in, const int* in_sizes, int n_in,
                              void* d_out, int out_size, void* d_ws, size_t ws_size,
                              hipStream_t stream)
{
  const float* V     = (const float*)d_in[0];
  const float* E     = (const float*)d_in[1];
  const int* edges   = (const int*)d_in[2];
  const float* senc  = (const float*)d_in[3];
  const float* fe_w1=(const float*)d_in[4];  const float* fe_b1=(const float*)d_in[5];
  const float* fe_w2=(const float*)d_in[6];  const float* fe_b2=(const float*)d_in[7];
  const float* fe_g =(const float*)d_in[8];  const float* fe_be=(const float*)d_in[9];
  const float* fn_w1=(const float*)d_in[10]; const float* fn_b1=(const float*)d_in[11];
  const float* fn_w2=(const float*)d_in[12]; const float* fn_b2=(const float*)d_in[13];
  const float* fn_g =(const float*)d_in[14]; const float* fn_be=(const float*)d_in[15];
  const float* ln1_g=(const float*)d_in[16]; const float* ln1_b=(const float*)d_in[17];
  const float* ln2_g=(const float*)d_in[18]; const float* ln2_b=(const float*)d_in[19];
  const float* Q    =(const float*)d_in[20];
  const float* a1_wqkv=(const float*)d_in[21]; const float* a1_bqkv=(const float*)d_in[22];
  const float* a1_wo=(const float*)d_in[23];   const float* a1_bo=(const float*)d_in[24];
  const float* a2_wqkv=(const float*)d_in[25]; const float* a2_bqkv=(const float*)d_in[26];
  const float* a2_wo=(const float*)d_in[27];   const float* a2_bo=(const float*)d_in[28];
  const float* a3_wqkv=(const float*)d_in[29]; const float* a3_bqkv=(const float*)d_in[30];
  const float* a3_wo=(const float*)d_in[31];   const float* a3_bo=(const float*)d_in[32];
  const float* ffn_w1=(const float*)d_in[33];  const float* ffn_b1=(const float*)d_in[34];
  const float* ffn_w2=(const float*)d_in[35];  const float* ffn_b2=(const float*)d_in[36];

  char* ws = (char*)d_ws;
  size_t off = 0;
  auto alloc = [&](size_t bytes)->void*{ void* p = ws + off; off += (bytes + 255) & ~(size_t)255; return p; };
  float* m0s = (float*)alloc((size_t)B_*N_*64*4);
  float* m1s = (float*)alloc((size_t)B_*N_*64*4);
  float* c0s = (float*)alloc((size_t)B_*N_*4);
  float* c1s = (float*)alloc((size_t)B_*N_*4);
  const size_t zero_bytes = off;
  u16* wcat = (u16*)alloc((size_t)WTOT*2);
  u16* V1  = (u16*)alloc((size_t)B_*N_*D_*2);
  u16* W0  = (u16*)alloc((size_t)B_*N_*D_*2);
  u16* kh1 = (u16*)alloc((size_t)B_*H_*N_*32*2);
  u16* vh1 = (u16*)alloc((size_t)B_*H_*N_*32*2);
  u16* qh1 = (u16*)alloc((size_t)H_*T_*32*2);
  float* o1 = (float*)alloc((size_t)B_*T_*D_*4);
  u16* qh2 = (u16*)alloc((size_t)B_*H_*T_*32*2);
  u16* kh2 = (u16*)alloc((size_t)B_*H_*T_*32*2);
  u16* vh2 = (u16*)alloc((size_t)B_*H_*T_*32*2);
  float* o2 = (float*)alloc((size_t)B_*T_*D_*4);
  u16* kh3 = (u16*)alloc((size_t)B_*H_*T_*32*2);
  u16* vh3T= (u16*)alloc((size_t)B_*H_*32*T_*2);
  float* pmw = (float*)alloc((size_t)B_*H_*NCH*128*4);
  float* plw = (float*)alloc((size_t)B_*H_*NCH*128*4);
  float* pow_ = (float*)alloc((size_t)B_*H_*NCH*128*32*4);
  if (ws_size < off) return;

  u16* w_fe1 = wcat + WO_FE1;
  u16* w_fe2 = wcat + WO_FE2;
  u16* w_fn1 = wcat + WO_FN1;
  u16* w_fn2 = wcat + WO_FN2;
  u16* w_a1  = wcat + WO_A1;
  u16* w_a3  = wcat + WO_A3;
  u16* w_a3o = wcat + WO_A3O;
  u16* w_ff1 = wcat + WO_FF1;
  u16* w_ff2 = wcat + WO_FF2;

  float* outp = (float*)d_out;
  float* V3out = outp;
  float* Eout  = outp + (size_t)B_*N_*D_;

  hipMemsetAsync(d_ws, 0, zero_bytes, stream);
  k_cvtw<<<(WTOT/8+255)/256,256,0,stream>>>(fe_w1,fe_w2,fn_w1,fn_w2,a1_wqkv,a3_wqkv,a3_wo,
                                            ffn_w1,ffn_w2, wcat);
  k_edge<<<(B_*NE_)/64,512,0,stream>>>(V,E,edges,senc, w_fe1,fe_b1, w_fe2,fe_b2, fe_g,fe_be,
                                       m0s,m1s,c0s,c1s, Eout);
  k_nodekv<<<(B_*N_)/64,256,0,stream>>>(V,senc,m0s,m1s,c0s,c1s, w_fn1,fn_b1, w_fn2,fn_b2,
                                        fn_g,fn_be, ln1_g,ln1_b, w_a1,a1_bqkv,
                                        V1,W0, kh1,vh1);
  k_qh1<<<T_/64,256,0,stream>>>(Q, a1_wqkv, a1_bqkv, qh1);
  k_mha1p<<<B_*H_*NCH,256,0,stream>>>(qh1,kh1,vh1, pmw,plw,pow_);
  k_mha1c<<<(B_*H_*T_*32)/256,256,0,stream>>>(pmw,plw,pow_, o1);
  k_att12<<<(B_*T_)/64,256,0,stream>>>(o1, a1_wo, a1_bo, a2_wqkv, a2_bqkv, qh2,kh2,vh2);
  k_mha2<<<(B_*H_*T_)/4,256,0,stream>>>(qh2,kh2,vh2,o2);
  k_att23<<<(B_*T_)/64,256,0,stream>>>(o2, a2_wo, a2_bo, a3_wqkv, a3_bqkv, kh3, vh3T);
  k_mha3f<<<B_*157,256,0,stream>>>(W0,V1, w_a3,a3_bqkv, kh3,vh3T, w_a3o,a3_bo,
                                   ln2_g,ln2_b, w_ff1,ffn_b1, w_ff2,ffn_b2, V3out);
}